// Round 1
// baseline (1083.543 us; speedup 1.0000x reference)
//
#include <hip/hip_runtime.h>
#include <math.h>

// ---------------------------------------------------------------------------
// MultiModalGraphSAGE — R7: LDS-staged async GEMM pipeline.
// R6 post-mortem: enc GEMM at 1.18 TB/s (14.7% HBM), all pipes idle,
// VGPR_Count=68 proves the compiler collapsed the register A-window into a
// serial load->use chain (latency-bound, ~1.7 KB in flight/CU). R7: one
// bf16 GEMM template staging A through LDS via global_load_lds (width 16,
// VGPR-free deep queue), double-buffered (T3 2-phase), XOR-swizzled
// source+read (rule #21) to kill the 128B-stride bank conflict. fp32 enc
// inputs get a streaming concat->bf16 pre-pass; its scratch aliases the
// later st/h1b buffers, so workspace size is unchanged.
// ---------------------------------------------------------------------------

#define EPS 1e-5f

typedef __attribute__((ext_vector_type(8))) short bf16x8;
typedef __attribute__((ext_vector_type(4))) float f32x4;
typedef unsigned int u32;

__device__ inline unsigned short f2bf(float x) {
    unsigned u = __float_as_uint(x);
    u += 0x7fff + ((u >> 16) & 1);          // RNE to bf16
    return (unsigned short)(u >> 16);
}
__device__ inline float bf2f(unsigned short h) {
    return __uint_as_float(((unsigned)h) << 16);
}
__device__ inline unsigned packbf(float x, float y) {
    return (unsigned)f2bf(x) | ((unsigned)f2bf(y) << 16);
}

__device__ inline void gload_lds16(const void* g, void* l) {
    __builtin_amdgcn_global_load_lds(
        (__attribute__((address_space(1))) void*)g,
        (__attribute__((address_space(3))) void*)l, 16, 0, 0);
}

// ---------------- CSR build ----------------

__global__ void zero_int(int* __restrict__ p, int n) {
    int i = blockIdx.x * 256 + threadIdx.x;
    if (i < n) p[i] = 0;
}

__global__ void count_deg(const int* __restrict__ dst, int* __restrict__ deg, int e) {
    int i = blockIdx.x * 256 + threadIdx.x;
    if (i < e) atomicAdd(&deg[dst[i]], 1);
}

__global__ __launch_bounds__(1024)
void scan_block(const int* __restrict__ deg, int* __restrict__ rowptr,
                int* __restrict__ part, int n) {
    __shared__ int buf[1024];
    const int tid = threadIdx.x;
    const int i = blockIdx.x * 1024 + tid;
    const int v = (i < n) ? deg[i] : 0;
    buf[tid] = v;
    __syncthreads();
    #pragma unroll 1
    for (int off = 1; off < 1024; off <<= 1) {
        int t = (tid >= off) ? buf[tid - off] : 0;
        __syncthreads();
        buf[tid] += t;
        __syncthreads();
    }
    if (i < n) rowptr[i] = buf[tid] - v;          // local exclusive
    if (tid == 1023) part[blockIdx.x] = buf[1023];
}

__global__ __launch_bounds__(1024)
void scan_part(int* __restrict__ part, int nb) {
    __shared__ int buf[1024];
    const int tid = threadIdx.x;
    const int v = (tid < nb) ? part[tid] : 0;
    buf[tid] = v;
    __syncthreads();
    #pragma unroll 1
    for (int off = 1; off < 1024; off <<= 1) {
        int t = (tid >= off) ? buf[tid - off] : 0;
        __syncthreads();
        buf[tid] += t;
        __syncthreads();
    }
    if (tid < nb) part[tid] = buf[tid] - v;       // exclusive
    if (tid == 1023) part[nb] = buf[1023];        // grand total
}

__global__ void scan_add(const int* __restrict__ part, int* __restrict__ rowptr,
                         int* __restrict__ cursor, int n, int nb) {
    int i = blockIdx.x * 256 + threadIdx.x;
    if (i < n) {
        int v = rowptr[i] + part[i >> 10];
        rowptr[i] = v;
        cursor[i] = v;
    }
    if (i == 0) rowptr[n] = part[nb];
}

__global__ void fill_edges(const int* __restrict__ src, const int* __restrict__ dst,
                           int* __restrict__ cursor, int* __restrict__ eidx, int e) {
    int i = blockIdx.x * 256 + threadIdx.x;
    if (i < e) {
        int pos = atomicAdd(&cursor[dst[i]], 1);
        eidx[pos] = src[i];
    }
}

// ---------------- weight prep: W[K][N] fp32 -> Wt hi/lo [N][ldt] bf16 -------

__global__ void prep_w(const float* __restrict__ W, int K, int N,
                       short* __restrict__ hi, short* __restrict__ lo,
                       int ldt, int koff) {
    int i = blockIdx.x * 256 + threadIdx.x;
    if (i >= K * N) return;
    int k = i / N, n = i - k * N;
    float x = W[i];
    unsigned short h = f2bf(x);
    unsigned short l = f2bf(x - bf2f(h));
    size_t o = (size_t)n * ldt + koff + k;
    hi[o] = (short)h;
    lo[o] = (short)l;
}

// ---------------- concat(sf,mf) fp32 -> xb bf16 [nn,512] (streaming) --------

__global__ __launch_bounds__(256)
void concat_bf16(const float* __restrict__ sf, const float* __restrict__ mf,
                 short* __restrict__ xb, int nn) {
    const int total = nn * 64;                    // 16B units
    for (int g = blockIdx.x * 256 + threadIdx.x; g < total; g += gridDim.x * 256) {
        const int n = g >> 6, u = g & 63;
        const float* p = (u < 16) ? (sf + (size_t)n * 128 + (size_t)u * 8)
                                  : (mf + (size_t)n * 384 + (size_t)(u - 16) * 8);
        const float4 f0 = ((const float4*)p)[0];
        const float4 f1 = ((const float4*)p)[1];
        uint4 o;
        o.x = packbf(f0.x, f0.y); o.y = packbf(f0.z, f0.w);
        o.z = packbf(f1.x, f1.y); o.w = packbf(f1.z, f1.w);
        *(uint4*)(xb + (size_t)g * 8) = o;
    }
}

// ---------------- mean aggregation (bf16 in, bf16 out), one wave per node ---

__global__ __launch_bounds__(256)
void agg_mean_bb(const short* __restrict__ featb,
                 const int* __restrict__ rowptr, const int* __restrict__ eidx,
                 short* __restrict__ outb, int n) {
    const int node = blockIdx.x * 4 + (threadIdx.x >> 6);
    if (node >= n) return;
    const int lane = threadIdx.x & 63;
    const int beg = rowptr[node], end = rowptr[node + 1];
    float sx = 0.f, sy = 0.f;
    for (int e = beg; e < end; ++e) {
        const unsigned v =
            ((const unsigned*)(featb + (size_t)eidx[e] * 128))[lane];
        sx += __uint_as_float(v << 16);
        sy += __uint_as_float(v & 0xffff0000u);
    }
    const float inv = 1.0f / fmaxf((float)(end - beg), 1.0f);
    ((unsigned*)(outb + (size_t)node * 128))[lane] = packbf(sx * inv, sy * inv);
}

// sage1 combine: h2 = relu(bn1(s1 + mean_neigh(t1) + b1)), bf16 out
__global__ __launch_bounds__(256)
void agg_combine_bb(const short* __restrict__ featb,
                    const int* __restrict__ rowptr, const int* __restrict__ eidx,
                    const float* __restrict__ s1,          // [n,128] fp32
                    const float* __restrict__ bias,
                    const float* __restrict__ bng, const float* __restrict__ bnb,
                    const float* __restrict__ bnm, const float* __restrict__ bnv,
                    short* __restrict__ outb, int n) {
    const int node = blockIdx.x * 4 + (threadIdx.x >> 6);
    if (node >= n) return;
    const int lane = threadIdx.x & 63;
    const int beg = rowptr[node], end = rowptr[node + 1];
    float sx = 0.f, sy = 0.f;
    for (int e = beg; e < end; ++e) {
        const unsigned v =
            ((const unsigned*)(featb + (size_t)eidx[e] * 128))[lane];
        sx += __uint_as_float(v << 16);
        sy += __uint_as_float(v & 0xffff0000u);
    }
    const float inv = 1.0f / fmaxf((float)(end - beg), 1.0f);
    sx *= inv; sy *= inv;
    const int c = lane * 2;
    const float2 s = ((const float2*)(s1 + (size_t)node * 128))[lane];
    float v0 = s.x + sx + bias[c];
    float v1 = s.y + sy + bias[c + 1];
    v0 = (v0 - bnm[c])     * (bng[c]     / sqrtf(bnv[c]     + EPS)) + bnb[c];
    v1 = (v1 - bnm[c + 1]) * (bng[c + 1] / sqrtf(bnv[c + 1] + EPS)) + bnb[c + 1];
    ((unsigned*)(outb + (size_t)node * 128))[lane] =
        packbf(fmaxf(v0, 0.f), fmaxf(v1, 0.f));
}

// ---------------- LDS-staged MFMA GEMM: bf16 A, split-bf16 W ---------------
// Block: 256 thr = 4 waves. Tile 128 rows x NT*16 cols, BK=64.
// A staged via global_load_lds (async, VGPR-free): LDS dest linear, global
// source XOR-pre-swizzled (16B unit u ^= row&7) so the swizzled ds_read_b128
// is ~2-way-conflict (free). T3 2-phase: stage(next); compute(cur); barrier.
// B (tiny, L2-hot) read per sub-chunk into registers. 2 MFMAs/tile (hi+lo).
template<int NT, int K1, int K2>
__global__ __launch_bounds__(256)
void gemm_lds(const short* __restrict__ A1, int lda1,
              const short* __restrict__ A2, int lda2,
              const short* __restrict__ Wt_hi, const short* __restrict__ Wt_lo,
              const float* __restrict__ bias,
              const float* __restrict__ bng, const float* __restrict__ bnb,
              const float* __restrict__ bnm, const float* __restrict__ bnv,
              int relu,
              float* __restrict__ Cf, int fpN, int ldc,
              short* __restrict__ Cb, int bfcol0, int ldcb,
              int M) {
    constexpr int K = K1 + K2;
    constexpr int NBK = K / 64;
    static_assert(K % 64 == 0, "K multiple of 64");
    static_assert(K2 == 0 || K1 % 64 == 0, "concat boundary on BK");
    __shared__ short lds[2][128 * 64];            // 2 x 16 KB double buffer

    const int tid  = threadIdx.x;
    const int lane = tid & 63;
    const int wv   = tid >> 6;
    const int bm   = blockIdx.y * 128;
    const int col0 = blockIdx.x * (NT * 16);
    const int lrow = lane & 15;
    const int quad = lane >> 4;

    // ---- staging source addresses ----
    // physical LDS unit e = j*256+tid  ->  row = j*32 + (tid>>3), unit tid&7.
    // physical (row,u) holds global unit u^(row&7)  (XOR involution).
    const int su = (tid & 7) ^ ((tid >> 3) & 7);
    const short* gs1[4];
    const short* gs2[4];
    #pragma unroll
    for (int j = 0; j < 4; ++j) {
        const int rg = min(bm + j * 32 + (tid >> 3), M - 1);
        gs1[j] = A1 + (size_t)rg * lda1 + su * 8;
        if constexpr (K2 > 0) gs2[j] = A2 + (size_t)rg * lda2 + su * 8;
        else gs2[j] = nullptr;
    }

    auto stage = [&](int b, int c) {
        const int k = c * 64;
        #pragma unroll
        for (int j = 0; j < 4; ++j) {
            const short* p;
            if constexpr (K2 > 0)
                p = (k < K1) ? (gs1[j] + k) : (gs2[j] + (k - K1));
            else
                p = gs1[j] + k;
            gload_lds16(p, &lds[b][(j * 256 + tid) * 8]);
        }
    };

    // ---- B pointers (register fragments from L2) ----
    const short* pBh[NT];
    const short* pBl[NT];
    #pragma unroll
    for (int nt = 0; nt < NT; ++nt) {
        const size_t wo = (size_t)(col0 + nt * 16 + lrow) * K + quad * 8;
        pBh[nt] = Wt_hi + wo;
        pBl[nt] = Wt_lo + wo;
    }

    // ---- A-fragment swizzled LDS offsets (shorts), per (m, kk) ----
    // row = wv*32 + m*16 + lrow ; logical unit u = kk*4+quad ; phys u^=(row&7)
    int aoff[2][2];
    #pragma unroll
    for (int m = 0; m < 2; ++m)
        #pragma unroll
        for (int kk = 0; kk < 2; ++kk)
            aoff[m][kk] = (wv * 32 + m * 16 + lrow) * 64 +
                          (((kk * 4 + quad) ^ (lrow & 7)) * 8);

    f32x4 acc[2][NT];
    #pragma unroll
    for (int m = 0; m < 2; ++m)
        #pragma unroll
        for (int nt = 0; nt < NT; ++nt)
            acc[m][nt] = (f32x4){0.f, 0.f, 0.f, 0.f};

    stage(0, 0);
    __syncthreads();                              // vmcnt(0) drain: buf0 ready

    for (int c = 0; c < NBK; ++c) {
        const int b = c & 1;
        if (c + 1 < NBK) stage(b ^ 1, c + 1);     // async prefetch next K-step
        const int kbase = c * 64;
        #pragma unroll
        for (int kk = 0; kk < 2; ++kk) {
            const bf16x8 a0 = *(const bf16x8*)&lds[b][aoff[0][kk]];
            const bf16x8 a1 = *(const bf16x8*)&lds[b][aoff[1][kk]];
            const int kof = kbase + kk * 32;
            #pragma unroll
            for (int nt = 0; nt < NT; ++nt) {
                const bf16x8 bh = *(const bf16x8*)(pBh[nt] + kof);
                const bf16x8 bl = *(const bf16x8*)(pBl[nt] + kof);
                acc[0][nt] = __builtin_amdgcn_mfma_f32_16x16x32_bf16(a0, bh, acc[0][nt], 0, 0, 0);
                acc[0][nt] = __builtin_amdgcn_mfma_f32_16x16x32_bf16(a0, bl, acc[0][nt], 0, 0, 0);
                acc[1][nt] = __builtin_amdgcn_mfma_f32_16x16x32_bf16(a1, bh, acc[1][nt], 0, 0, 0);
                acc[1][nt] = __builtin_amdgcn_mfma_f32_16x16x32_bf16(a1, bl, acc[1][nt], 0, 0, 0);
            }
        }
        __syncthreads();          // all waves done with buf b; next buf landed
    }

    // epilogue: C/D layout col=lane&15, row=quad*4+reg
    #pragma unroll
    for (int nt = 0; nt < NT; ++nt) {
        const int gcol = col0 + nt * 16 + lrow;
        const float bsc = bias ? bias[gcol] : 0.f;
        float g = 1.f, bb = 0.f, mm = 0.f;
        if (bng) { g = bng[gcol] / sqrtf(bnv[gcol] + EPS); bb = bnb[gcol]; mm = bnm[gcol]; }
        #pragma unroll
        for (int m = 0; m < 2; ++m) {
            const int rbase = bm + wv * 32 + m * 16 + quad * 4;
            #pragma unroll
            for (int r = 0; r < 4; ++r) {
                const int grow = rbase + r;
                if (grow >= M) continue;
                float x = acc[m][nt][r] + bsc;
                if (bng) x = (x - mm) * g + bb;
                if (relu) x = fmaxf(x, 0.f);
                if (gcol < fpN) Cf[(size_t)grow * ldc + gcol] = x;
                if (Cb && gcol >= bfcol0)
                    Cb[(size_t)grow * ldcb + (gcol - bfcol0)] = (short)f2bf(x);
            }
        }
    }
}

// ---------------------------------------------------------------------------

extern "C" void kernel_launch(void* const* d_in, const int* in_sizes, int n_in,
                              void* d_out, int out_size, void* d_ws, size_t ws_size,
                              hipStream_t stream) {
    const float* sf    = (const float*)d_in[0];
    const float* mf    = (const float*)d_in[1];
    const int*   src   = (const int*)d_in[2];
    const int*   dst   = (const int*)d_in[3];
    const float* enc_w = (const float*)d_in[4];
    const float* enc_b = (const float*)d_in[5];
    const float* s0_ws = (const float*)d_in[6];
    const float* s0_wn = (const float*)d_in[7];
    const float* s0_b  = (const float*)d_in[8];
    const float* bn0_g = (const float*)d_in[9];
    const float* bn0_b = (const float*)d_in[10];
    const float* bn0_m = (const float*)d_in[11];
    const float* bn0_v = (const float*)d_in[12];
    const float* s1_ws = (const float*)d_in[13];
    const float* s1_wn = (const float*)d_in[14];
    const float* s1_b  = (const float*)d_in[15];
    const float* bn1_g = (const float*)d_in[16];
    const float* bn1_b = (const float*)d_in[17];
    const float* bn1_m = (const float*)d_in[18];
    const float* bn1_v = (const float*)d_in[19];
    const float* rel_w = (const float*)d_in[20];
    const float* rel_b = (const float*)d_in[21];
    const float* cw1   = (const float*)d_in[22];
    const float* cb1   = (const float*)d_in[23];
    const float* cw2   = (const float*)d_in[24];
    const float* cb2   = (const float*)d_in[25];
    float* out = (float*)d_out;

    const int nn = in_sizes[0] / 128;   // 100000
    const int ne = in_sizes[2];         // 800000
    const int nb = (nn + 1023) / 1024;  // scan blocks (98)

    // workspace layout. xb [nn,512] bf16 is dead after the enc GEMM, so the
    // later st (fp32 [nn,128]) + h1b (bf16 [nn,256]) alias its footprint
    // (51.2 MB + 51.2 MB = 102.4 MB exactly).
    short* h0b   = (short*)d_ws;                       // [nn,128] bf16
    short* xb    = h0b + (size_t)nn * 128;             // [nn,512] bf16 (enc A)
    float* st    = (float*)xb;                         // s1 fp32 [nn,128]
    short* h1b   = (short*)(st + (size_t)nn * 128);    // [nn,256] bf16
    short* agg0b = xb + (size_t)nn * 512;              // [nn,128]; reused as o1b
    short* t1b   = agg0b + (size_t)nn * 128;           // [nn,128]; reused as rb
    short* h2b   = t1b + (size_t)nn * 128;             // [nn,128]
    short* o1b   = agg0b;                              // [nn,64] (agg0b dead)
    short* rb    = t1b;                                // [nn,128] (t1b dead)
    int* deg    = (int*)(h2b + (size_t)nn * 128);
    int* rowptr = deg + nn;
    int* cursor = rowptr + nn + 1;
    int* part   = cursor + nn;                         // [nb+1]
    int* eidx   = part + nb + 1;
    // bf16 weight planes (hi, lo) — transposed [N][K]
    short* wts = (short*)(eidx + ne);
    short* wt_enc_h = wts;                 short* wt_enc_l = wt_enc_h + 65536;   // [128][512]
    short* wt_s0_h  = wt_enc_l + 65536;    short* wt_s0_l  = wt_s0_h  + 65536;   // [256][256]
    short* wt_st_h  = wt_s0_l  + 65536;    short* wt_st_l  = wt_st_h  + 65536;   // [256][256]
    short* wt_rel_h = wt_st_l  + 65536;    short* wt_rel_l = wt_rel_h + 32768;   // [128][256]
    short* wt_c1_h  = wt_rel_l + 32768;    short* wt_c1_l  = wt_c1_h  + 8192;    // [64][128]
    short* wt_c2_h  = wt_c1_l  + 8192;     short* wt_c2_l  = wt_c2_h  + 2048;    // [32][64]

    const dim3 blk(256);
    const int gM = (nn + 127) / 128;    // 782 row-blocks

    // --- CSR build (parallel scan) ---
    zero_int  <<<dim3((nn + 255) / 256), blk, 0, stream>>>(deg, nn);
    count_deg <<<dim3((ne + 255) / 256), blk, 0, stream>>>(dst, deg, ne);
    scan_block<<<dim3(nb), dim3(1024), 0, stream>>>(deg, rowptr, part, nn);
    scan_part <<<dim3(1),  dim3(1024), 0, stream>>>(part, nb);
    scan_add  <<<dim3((nn + 255) / 256), blk, 0, stream>>>(part, rowptr, cursor, nn, nb);
    fill_edges<<<dim3((ne + 255) / 256), blk, 0, stream>>>(src, dst, cursor, eidx, ne);

    // --- weight prep (tiny) ---
    prep_w<<<dim3(256), blk, 0, stream>>>(enc_w, 512, 128, wt_enc_h, wt_enc_l, 512, 0);
    prep_w<<<dim3(128), blk, 0, stream>>>(s0_ws, 128, 256, wt_s0_h, wt_s0_l, 256, 0);
    prep_w<<<dim3(128), blk, 0, stream>>>(s0_wn, 128, 256, wt_s0_h, wt_s0_l, 256, 128);
    prep_w<<<dim3(128), blk, 0, stream>>>(s1_ws, 256, 128, wt_st_h, wt_st_l, 256, 0);
    prep_w<<<dim3(128), blk, 0, stream>>>(s1_wn, 256, 128, wt_st_h + (size_t)128 * 256,
                                          wt_st_l + (size_t)128 * 256, 256, 0);
    prep_w<<<dim3(128), blk, 0, stream>>>(rel_w, 256, 128, wt_rel_h, wt_rel_l, 256, 0);
    prep_w<<<dim3(32),  blk, 0, stream>>>(cw1, 128, 64, wt_c1_h, wt_c1_l, 128, 0);
    prep_w<<<dim3(8),   blk, 0, stream>>>(cw2, 64, 32, wt_c2_h, wt_c2_l, 64, 0);

    // --- xb = bf16(concat(sf, mf)) : streaming convert ---
    concat_bf16<<<dim3(2048), blk, 0, stream>>>(sf, mf, xb, nn);

    // --- h0 = relu(xb @ enc_w + enc_b) -> h0b bf16 ---
    gemm_lds<4, 512, 0><<<dim3(2, gM), blk, 0, stream>>>(
        xb, 512, nullptr, 0, wt_enc_h, wt_enc_l, enc_b,
        nullptr, nullptr, nullptr, nullptr, 1,
        nullptr, 0, 0, h0b, 0, 128, nn);

    // --- agg0 = mean_neigh(h0b) -> agg0b bf16 ---
    agg_mean_bb<<<dim3((nn + 3) / 4), blk, 0, stream>>>(
        h0b, rowptr, eidx, agg0b, nn);

    // --- h1 = relu(bn0(h0@ws0 + agg0@wn0 + b0)) -> h1b bf16 ---
    gemm_lds<4, 128, 128><<<dim3(4, gM), blk, 0, stream>>>(
        h0b, 128, agg0b, 128, wt_s0_h, wt_s0_l, s0_b,
        bn0_g, bn0_b, bn0_m, bn0_v, 1,
        nullptr, 0, 0, h1b, 0, 256, nn);

    // --- [s1 | t1] = h1 @ [ws1 | wn1]; s1 fp32 -> st, t1 bf16 -> t1b ---
    gemm_lds<4, 256, 0><<<dim3(4, gM), blk, 0, stream>>>(
        h1b, 256, nullptr, 0, wt_st_h, wt_st_l, nullptr,
        nullptr, nullptr, nullptr, nullptr, 0,
        st, 128, 128, t1b, 128, 128, nn);

    // --- h2 = relu(bn1(s1 + mean_neigh(t1) + b1)) -> h2b bf16 ---
    agg_combine_bb<<<dim3((nn + 3) / 4), blk, 0, stream>>>(
        t1b, rowptr, eidx, st, s1_b,
        bn1_g, bn1_b, bn1_m, bn1_v, h2b, nn);

    // --- r = relu(h0@rel_w[:128] + h2@rel_w[128:] + rel_b) -> rb bf16 ---
    gemm_lds<4, 128, 128><<<dim3(2, gM), blk, 0, stream>>>(
        h0b, 128, h2b, 128, wt_rel_h, wt_rel_l, rel_b,
        nullptr, nullptr, nullptr, nullptr, 1,
        nullptr, 0, 0, rb, 0, 128, nn);

    // --- o1 = relu(r@cls_w1 + cb1) -> o1b bf16 [nn,64] ---
    gemm_lds<4, 128, 0><<<dim3(1, gM), blk, 0, stream>>>(
        rb, 128, nullptr, 0, wt_c1_h, wt_c1_l, cb1,
        nullptr, nullptr, nullptr, nullptr, 1,
        nullptr, 0, 0, o1b, 0, 64, nn);

    // --- out = o1@cls_w2 + cb2 -> d_out fp32 [nn,32] ---
    gemm_lds<2, 64, 0><<<dim3(1, gM), blk, 0, stream>>>(
        o1b, 64, nullptr, 0, wt_c2_h, wt_c2_l, cb2,
        nullptr, nullptr, nullptr, nullptr, 0,
        out, 32, 32, nullptr, 0, 0, nn);
}

// Round 2
// 718.787 us; speedup vs baseline: 1.5075x; 1.5075x over previous
//
#include <hip/hip_runtime.h>
#include <math.h>

// ---------------------------------------------------------------------------
// MultiModalGraphSAGE — R8: all-LDS GEMM pipeline with counted vmcnt.
// R7 post-mortem: (1) B loaded from global per K-step = 64KB/block/K-step
// through the CU L1/TA port (~64B/cy) -> L1-throughput-bound; (2) in-order
// vmcnt: MFMA waits on B register loads drained the freshly issued A stage
// -> no async overlap. R8: A AND B staged via global_load_lds (XOR-swizzled
// source, linear LDS dest, swizzled ds_read). K-loop has ZERO register VMEM:
// stage(c+1) -> s_waitcnt vmcnt(4+NT) -> s_barrier -> ds_read+MFMA ->
// s_barrier (m201/m218 pattern; never drain to 0 mid-loop). Epilogue bounces
// through LDS so all stores are coalesced 16B (R7 WRITE_SIZE was 2.6x
// useful bytes). Aggregation: 4 edges in flight (16 lanes x uint4 per row)
// + shfl_xor group reduce.
// ---------------------------------------------------------------------------

#define EPS 1e-5f

typedef __attribute__((ext_vector_type(8))) short bf16x8;
typedef __attribute__((ext_vector_type(4))) float f32x4;

__device__ inline unsigned short f2bf(float x) {
    unsigned u = __float_as_uint(x);
    u += 0x7fff + ((u >> 16) & 1);          // RNE to bf16
    return (unsigned short)(u >> 16);
}
__device__ inline float bf2f(unsigned short h) {
    return __uint_as_float(((unsigned)h) << 16);
}
__device__ inline unsigned packbf(float x, float y) {
    return (unsigned)f2bf(x) | ((unsigned)f2bf(y) << 16);
}

__device__ inline void gload_lds16(const void* g, void* l) {
    __builtin_amdgcn_global_load_lds(
        (__attribute__((address_space(1))) void*)g,
        (__attribute__((address_space(3))) void*)l, 16, 0, 0);
}

// ---------------- CSR build ----------------

__global__ void zero_int(int* __restrict__ p, int n) {
    int i = blockIdx.x * 256 + threadIdx.x;
    if (i < n) p[i] = 0;
}

__global__ void count_deg(const int* __restrict__ dst, int* __restrict__ deg, int e) {
    int i = blockIdx.x * 256 + threadIdx.x;
    if (i < e) atomicAdd(&deg[dst[i]], 1);
}

__global__ __launch_bounds__(1024)
void scan_block(const int* __restrict__ deg, int* __restrict__ rowptr,
                int* __restrict__ part, int n) {
    __shared__ int buf[1024];
    const int tid = threadIdx.x;
    const int i = blockIdx.x * 1024 + tid;
    const int v = (i < n) ? deg[i] : 0;
    buf[tid] = v;
    __syncthreads();
    #pragma unroll 1
    for (int off = 1; off < 1024; off <<= 1) {
        int t = (tid >= off) ? buf[tid - off] : 0;
        __syncthreads();
        buf[tid] += t;
        __syncthreads();
    }
    if (i < n) rowptr[i] = buf[tid] - v;          // local exclusive
    if (tid == 1023) part[blockIdx.x] = buf[1023];
}

__global__ __launch_bounds__(1024)
void scan_part(int* __restrict__ part, int nb) {
    __shared__ int buf[1024];
    const int tid = threadIdx.x;
    const int v = (tid < nb) ? part[tid] : 0;
    buf[tid] = v;
    __syncthreads();
    #pragma unroll 1
    for (int off = 1; off < 1024; off <<= 1) {
        int t = (tid >= off) ? buf[tid - off] : 0;
        __syncthreads();
        buf[tid] += t;
        __syncthreads();
    }
    if (tid < nb) part[tid] = buf[tid] - v;       // exclusive
    if (tid == 1023) part[nb] = buf[1023];        // grand total
}

__global__ void scan_add(const int* __restrict__ part, int* __restrict__ rowptr,
                         int* __restrict__ cursor, int n, int nb) {
    int i = blockIdx.x * 256 + threadIdx.x;
    if (i < n) {
        int v = rowptr[i] + part[i >> 10];
        rowptr[i] = v;
        cursor[i] = v;
    }
    if (i == 0) rowptr[n] = part[nb];
}

__global__ void fill_edges(const int* __restrict__ src, const int* __restrict__ dst,
                           int* __restrict__ cursor, int* __restrict__ eidx, int e) {
    int i = blockIdx.x * 256 + threadIdx.x;
    if (i < e) {
        int pos = atomicAdd(&cursor[dst[i]], 1);
        eidx[pos] = src[i];
    }
}

// ---------------- weight prep: W[K][N] fp32 -> Wt hi/lo [N][ldt] bf16 -------

__global__ void prep_w(const float* __restrict__ W, int K, int N,
                       short* __restrict__ hi, short* __restrict__ lo,
                       int ldt, int koff) {
    int i = blockIdx.x * 256 + threadIdx.x;
    if (i >= K * N) return;
    int k = i / N, n = i - k * N;
    float x = W[i];
    unsigned short h = f2bf(x);
    unsigned short l = f2bf(x - bf2f(h));
    size_t o = (size_t)n * ldt + koff + k;
    hi[o] = (short)h;
    lo[o] = (short)l;
}

// ---------------- concat(sf,mf) fp32 -> xb bf16 [nn,512] (streaming) --------

__global__ __launch_bounds__(256)
void concat_bf16(const float* __restrict__ sf, const float* __restrict__ mf,
                 short* __restrict__ xb, int nn) {
    const int total = nn * 64;                    // 16B units
    for (int g = blockIdx.x * 256 + threadIdx.x; g < total; g += gridDim.x * 256) {
        const int n = g >> 6, u = g & 63;
        const float* p = (u < 16) ? (sf + (size_t)n * 128 + (size_t)u * 8)
                                  : (mf + (size_t)n * 384 + (size_t)(u - 16) * 8);
        const float4 f0 = ((const float4*)p)[0];
        const float4 f1 = ((const float4*)p)[1];
        uint4 o;
        o.x = packbf(f0.x, f0.y); o.y = packbf(f0.z, f0.w);
        o.z = packbf(f1.x, f1.y); o.w = packbf(f1.z, f1.w);
        *(uint4*)(xb + (size_t)g * 8) = o;
    }
}

// ---------------- mean aggregation: 4 edges in flight, 16 lanes/row ---------
// wave = 4 groups x 16 lanes; group g handles edges beg+g, beg+g+4, ...
// lane j of a group loads uint4 (cols j*8..j*8+7) of the neighbor row.
// Group partial sums combined by shfl_xor(32), shfl_xor(16).

__global__ __launch_bounds__(256)
void agg_mean_bb(const short* __restrict__ featb,
                 const int* __restrict__ rowptr, const int* __restrict__ eidx,
                 short* __restrict__ outb, int n) {
    const int node = blockIdx.x * 4 + (threadIdx.x >> 6);
    if (node >= n) return;
    const int lane = threadIdx.x & 63;
    const int g = lane >> 4, j = lane & 15;
    const int beg = rowptr[node], end = rowptr[node + 1];
    float s[8];
    #pragma unroll
    for (int i = 0; i < 8; ++i) s[i] = 0.f;
    for (int e = beg + g; e < end; e += 4) {
        const uint4 v = *(const uint4*)(featb + (size_t)eidx[e] * 128 + j * 8);
        s[0] += __uint_as_float(v.x << 16); s[1] += __uint_as_float(v.x & 0xffff0000u);
        s[2] += __uint_as_float(v.y << 16); s[3] += __uint_as_float(v.y & 0xffff0000u);
        s[4] += __uint_as_float(v.z << 16); s[5] += __uint_as_float(v.z & 0xffff0000u);
        s[6] += __uint_as_float(v.w << 16); s[7] += __uint_as_float(v.w & 0xffff0000u);
    }
    #pragma unroll
    for (int i = 0; i < 8; ++i) {
        s[i] += __shfl_xor(s[i], 32);
        s[i] += __shfl_xor(s[i], 16);
    }
    if (g == 0) {
        const float inv = 1.0f / fmaxf((float)(end - beg), 1.0f);
        uint4 o;
        o.x = packbf(s[0] * inv, s[1] * inv);
        o.y = packbf(s[2] * inv, s[3] * inv);
        o.z = packbf(s[4] * inv, s[5] * inv);
        o.w = packbf(s[6] * inv, s[7] * inv);
        *(uint4*)(outb + (size_t)node * 128 + j * 8) = o;
    }
}

// sage1 combine: h2 = relu(bn1(s1 + mean_neigh(t1) + b1)), bf16 out
__global__ __launch_bounds__(256)
void agg_combine_bb(const short* __restrict__ featb,
                    const int* __restrict__ rowptr, const int* __restrict__ eidx,
                    const float* __restrict__ s1,          // [n,128] fp32
                    const float* __restrict__ bias,
                    const float* __restrict__ bng, const float* __restrict__ bnb,
                    const float* __restrict__ bnm, const float* __restrict__ bnv,
                    short* __restrict__ outb, int n) {
    const int node = blockIdx.x * 4 + (threadIdx.x >> 6);
    if (node >= n) return;
    const int lane = threadIdx.x & 63;
    const int g = lane >> 4, j = lane & 15;
    const int beg = rowptr[node], end = rowptr[node + 1];
    float s[8];
    #pragma unroll
    for (int i = 0; i < 8; ++i) s[i] = 0.f;
    for (int e = beg + g; e < end; e += 4) {
        const uint4 v = *(const uint4*)(featb + (size_t)eidx[e] * 128 + j * 8);
        s[0] += __uint_as_float(v.x << 16); s[1] += __uint_as_float(v.x & 0xffff0000u);
        s[2] += __uint_as_float(v.y << 16); s[3] += __uint_as_float(v.y & 0xffff0000u);
        s[4] += __uint_as_float(v.z << 16); s[5] += __uint_as_float(v.z & 0xffff0000u);
        s[6] += __uint_as_float(v.w << 16); s[7] += __uint_as_float(v.w & 0xffff0000u);
    }
    #pragma unroll
    for (int i = 0; i < 8; ++i) {
        s[i] += __shfl_xor(s[i], 32);
        s[i] += __shfl_xor(s[i], 16);
    }
    if (g == 0) {
        const float inv = 1.0f / fmaxf((float)(end - beg), 1.0f);
        const int c0 = j * 8;
        const float4 a0 = *(const float4*)(s1 + (size_t)node * 128 + c0);
        const float4 a1 = *(const float4*)(s1 + (size_t)node * 128 + c0 + 4);
        const float sf[8] = {a0.x, a0.y, a0.z, a0.w, a1.x, a1.y, a1.z, a1.w};
        float r[8];
        #pragma unroll
        for (int i = 0; i < 8; ++i) {
            const int c = c0 + i;
            float v = sf[i] + s[i] * inv + bias[c];
            v = (v - bnm[c]) * (bng[c] / sqrtf(bnv[c] + EPS)) + bnb[c];
            r[i] = fmaxf(v, 0.f);
        }
        uint4 o;
        o.x = packbf(r[0], r[1]); o.y = packbf(r[2], r[3]);
        o.z = packbf(r[4], r[5]); o.w = packbf(r[6], r[7]);
        *(uint4*)(outb + (size_t)node * 128 + j * 8) = o;
    }
}

// ---------------- all-LDS MFMA GEMM: bf16 A, split-bf16 W ------------------
// Block: 256 thr = 4 waves. Tile 128 rows x NT*16 cols, BK=64, 2 LDS buffers.
// Per buffer: A [128 rows][64 k] 16KB + B [2*NT*16 colrows][64 k] (hi cols
// then lo cols). Both staged by gload_lds16: LDS linear, global source
// pre-XOR-swizzled (16B unit u ^= row&7), ds_read applies the same XOR.
// K-loop: stage(c+1) -> vmcnt(4+NT) -> s_barrier -> ds_read+MFMA -> s_barrier.
// Epilogue: acc -> LDS fp32 -> coalesced float4/uint4 stores.
template<int NT, int K1, int K2>
__global__ __launch_bounds__(256)
void gemm_dp(const short* __restrict__ A1, int lda1,
             const short* __restrict__ A2, int lda2,
             const short* __restrict__ Wt_hi, const short* __restrict__ Wt_lo,
             const float* __restrict__ bias,
             const float* __restrict__ bng, const float* __restrict__ bnb,
             const float* __restrict__ bnm, const float* __restrict__ bnv,
             int relu,
             float* __restrict__ Cf, int fpN, int ldc,
             short* __restrict__ Cb, int bfcol0, int ldcb,
             int M) {
    constexpr int K   = K1 + K2;
    constexpr int NBK = K / 64;
    static_assert(K % 64 == 0, "K multiple of 64");
    static_assert(K2 == 0 || K1 % 64 == 0, "concat boundary on BK");
    constexpr int ASZ = 128 * 64;                 // shorts (16KB)
    constexpr int BSZ = 2 * NT * 16 * 64;         // shorts (hi+lo planes)
    constexpr int BUF = ASZ + BSZ;
    __shared__ short lds[2 * BUF];

    const int tid  = threadIdx.x;
    const int lane = tid & 63;
    const int wv   = tid >> 6;
    const int bm   = blockIdx.y * 128;
    const int col0 = blockIdx.x * (NT * 16);
    const int lrow = lane & 15;
    const int quad = lane >> 4;

    // ---- staging sources: phys (row,u) holds global unit u^(row&7) ----
    const int su = (tid & 7) ^ ((tid >> 3) & 7);
    const short* gsA1[4];
    const short* gsA2[4];
    #pragma unroll
    for (int jj = 0; jj < 4; ++jj) {
        const int rg = min(bm + jj * 32 + (tid >> 3), M - 1);
        gsA1[jj] = A1 + (size_t)rg * lda1 + su * 8;
        if constexpr (K2 > 0) gsA2[jj] = A2 + (size_t)rg * lda2 + su * 8;
        else gsA2[jj] = nullptr;
    }
    const short* gsB[NT];                         // B "rows": hi cols, then lo
    #pragma unroll
    for (int jj = 0; jj < NT; ++jj) {
        const int colIdx = jj * 32 + (tid >> 3);  // 0..2*NT*16-1
        const bool ishi = colIdx < NT * 16;
        const int cp = ishi ? colIdx : colIdx - NT * 16;
        gsB[jj] = (ishi ? Wt_hi : Wt_lo) + (size_t)(col0 + cp) * K + su * 8;
    }

    auto stage = [&](int b, int c) {
        const int k = c * 64;
        #pragma unroll
        for (int jj = 0; jj < 4; ++jj) {
            const short* p;
            if constexpr (K2 > 0)
                p = (k < K1) ? (gsA1[jj] + k) : (gsA2[jj] + (k - K1));
            else
                p = gsA1[jj] + k;
            gload_lds16(p, &lds[b * BUF + (jj * 256 + tid) * 8]);
        }
        #pragma unroll
        for (int jj = 0; jj < NT; ++jj)
            gload_lds16(gsB[jj] + k, &lds[b * BUF + ASZ + (jj * 256 + tid) * 8]);
    };

    // ---- swizzled LDS read offsets (shorts) ----
    int aoff[2][2];
    #pragma unroll
    for (int m = 0; m < 2; ++m)
        #pragma unroll
        for (int kk = 0; kk < 2; ++kk)
            aoff[m][kk] = (wv * 32 + m * 16 + lrow) * 64 +
                          (((kk * 4 + quad) ^ (lrow & 7)) * 8);
    int boff[NT][2];
    #pragma unroll
    for (int nt = 0; nt < NT; ++nt)
        #pragma unroll
        for (int kk = 0; kk < 2; ++kk)
            boff[nt][kk] = (nt * 16 + lrow) * 64 +
                           (((kk * 4 + quad) ^ (lrow & 7)) * 8);

    f32x4 acc[2][NT];
    #pragma unroll
    for (int m = 0; m < 2; ++m)
        #pragma unroll
        for (int nt = 0; nt < NT; ++nt)
            acc[m][nt] = (f32x4){0.f, 0.f, 0.f, 0.f};

    stage(0, 0);

    for (int c = 0; c < NBK; ++c) {
        const int b = c & 1;
        if (c + 1 < NBK) {
            stage(b ^ 1, c + 1);
            // keep stage(c+1)'s 4+NT loads in flight; drain stage(c)
            if constexpr (NT == 4) asm volatile("s_waitcnt vmcnt(8)" ::: "memory");
            else                   asm volatile("s_waitcnt vmcnt(6)" ::: "memory");
        } else {
            asm volatile("s_waitcnt vmcnt(0)" ::: "memory");
        }
        __builtin_amdgcn_s_barrier();             // buf b fully staged

        const short* La = &lds[b * BUF];
        const short* Lb = &lds[b * BUF + ASZ];
        #pragma unroll
        for (int kk = 0; kk < 2; ++kk) {
            const bf16x8 a0 = *(const bf16x8*)(La + aoff[0][kk]);
            const bf16x8 a1 = *(const bf16x8*)(La + aoff[1][kk]);
            #pragma unroll
            for (int nt = 0; nt < NT; ++nt) {
                const bf16x8 vbh = *(const bf16x8*)(Lb + boff[nt][kk]);
                const bf16x8 vbl = *(const bf16x8*)(Lb + boff[nt][kk] + NT * 16 * 64);
                acc[0][nt] = __builtin_amdgcn_mfma_f32_16x16x32_bf16(a0, vbh, acc[0][nt], 0, 0, 0);
                acc[0][nt] = __builtin_amdgcn_mfma_f32_16x16x32_bf16(a0, vbl, acc[0][nt], 0, 0, 0);
                acc[1][nt] = __builtin_amdgcn_mfma_f32_16x16x32_bf16(a1, vbh, acc[1][nt], 0, 0, 0);
                acc[1][nt] = __builtin_amdgcn_mfma_f32_16x16x32_bf16(a1, vbl, acc[1][nt], 0, 0, 0);
            }
        }
        asm volatile("" ::: "memory");
        __builtin_amdgcn_s_barrier();             // all waves done with buf b
    }

    // ---- epilogue via LDS: coalesced stores ----
    constexpr int EW = NT * 16 + 4;               // fp32 row stride (16B-aligned)
    float* ep = (float*)lds;                      // 128*EW*4 <= 34.8KB < 64KB

    #pragma unroll
    for (int nt = 0; nt < NT; ++nt) {
        const int gcol = col0 + nt * 16 + lrow;
        const float bsc = bias ? bias[gcol] : 0.f;
        float gg = 1.f, bb = 0.f, mm = 0.f;
        if (bng) { gg = bng[gcol] / sqrtf(bnv[gcol] + EPS); bb = bnb[gcol]; mm = bnm[gcol]; }
        #pragma unroll
        for (int m = 0; m < 2; ++m) {
            #pragma unroll
            for (int r = 0; r < 4; ++r) {
                float x = acc[m][nt][r] + bsc;
                if (bng) x = (x - mm) * gg + bb;
                if (relu) x = fmaxf(x, 0.f);
                ep[(wv * 32 + m * 16 + quad * 4 + r) * EW + nt * 16 + lrow] = x;
            }
        }
    }
    __syncthreads();

    if (col0 < fpN) {                             // fp32-target block
        for (int g = tid; g < 128 * NT * 4; g += 256) {
            const int row = g / (NT * 4), u = g - row * (NT * 4);
            const int grow = bm + row;
            if (grow < M)
                *(float4*)(Cf + (size_t)grow * ldc + col0 + u * 4) =
                    *(const float4*)(ep + row * EW + u * 4);
        }
    } else {                                      // bf16-target block
        for (int g = tid; g < 128 * NT * 2; g += 256) {
            const int row = g / (NT * 2), u = g - row * (NT * 2);
            const int grow = bm + row;
            const float4 f0 = *(const float4*)(ep + row * EW + u * 8);
            const float4 f1 = *(const float4*)(ep + row * EW + u * 8 + 4);
            uint4 o;
            o.x = packbf(f0.x, f0.y); o.y = packbf(f0.z, f0.w);
            o.z = packbf(f1.x, f1.y); o.w = packbf(f1.z, f1.w);
            if (grow < M)
                *(uint4*)(Cb + (size_t)grow * ldcb + (col0 - bfcol0) + u * 8) = o;
        }
    }
}

// ---------------------------------------------------------------------------

extern "C" void kernel_launch(void* const* d_in, const int* in_sizes, int n_in,
                              void* d_out, int out_size, void* d_ws, size_t ws_size,
                              hipStream_t stream) {
    const float* sf    = (const float*)d_in[0];
    const float* mf    = (const float*)d_in[1];
    const int*   src   = (const int*)d_in[2];
    const int*   dst   = (const int*)d_in[3];
    const float* enc_w = (const float*)d_in[4];
    const float* enc_b = (const float*)d_in[5];
    const float* s0_ws = (const float*)d_in[6];
    const float* s0_wn = (const float*)d_in[7];
    const float* s0_b  = (const float*)d_in[8];
    const float* bn0_g = (const float*)d_in[9];
    const float* bn0_b = (const float*)d_in[10];
    const float* bn0_m = (const float*)d_in[11];
    const float* bn0_v = (const float*)d_in[12];
    const float* s1_ws = (const float*)d_in[13];
    const float* s1_wn = (const float*)d_in[14];
    const float* s1_b  = (const float*)d_in[15];
    const float* bn1_g = (const float*)d_in[16];
    const float* bn1_b = (const float*)d_in[17];
    const float* bn1_m = (const float*)d_in[18];
    const float* bn1_v = (const float*)d_in[19];
    const float* rel_w = (const float*)d_in[20];
    const float* rel_b = (const float*)d_in[21];
    const float* cw1   = (const float*)d_in[22];
    const float* cb1   = (const float*)d_in[23];
    const float* cw2   = (const float*)d_in[24];
    const float* cb2   = (const float*)d_in[25];
    float* out = (float*)d_out;

    const int nn = in_sizes[0] / 128;   // 100000
    const int ne = in_sizes[2];         // 800000
    const int nb = (nn + 1023) / 1024;  // scan blocks (98)

    // workspace layout. xb [nn,512] bf16 is dead after the enc GEMM, so the
    // later st (fp32 [nn,128]) + h1b (bf16 [nn,256]) alias its footprint.
    short* h0b   = (short*)d_ws;                       // [nn,128] bf16
    short* xb    = h0b + (size_t)nn * 128;             // [nn,512] bf16 (enc A)
    float* st    = (float*)xb;                         // s1 fp32 [nn,128]
    short* h1b   = (short*)(st + (size_t)nn * 128);    // [nn,256] bf16
    short* agg0b = xb + (size_t)nn * 512;              // [nn,128]; reused as o1b
    short* t1b   = agg0b + (size_t)nn * 128;           // [nn,128]; reused as rb
    short* h2b   = t1b + (size_t)nn * 128;             // [nn,128]
    short* o1b   = agg0b;                              // [nn,64] (agg0b dead)
    short* rb    = t1b;                                // [nn,128] (t1b dead)
    int* deg    = (int*)(h2b + (size_t)nn * 128);
    int* rowptr = deg + nn;
    int* cursor = rowptr + nn + 1;
    int* part   = cursor + nn;                         // [nb+1]
    int* eidx   = part + nb + 1;
    // bf16 weight planes (hi, lo) — transposed [N][K]
    short* wts = (short*)(eidx + ne);
    short* wt_enc_h = wts;                 short* wt_enc_l = wt_enc_h + 65536;   // [128][512]
    short* wt_s0_h  = wt_enc_l + 65536;    short* wt_s0_l  = wt_s0_h  + 65536;   // [256][256]
    short* wt_st_h  = wt_s0_l  + 65536;    short* wt_st_l  = wt_st_h  + 65536;   // [256][256]
    short* wt_rel_h = wt_st_l  + 65536;    short* wt_rel_l = wt_rel_h + 32768;   // [128][256]
    short* wt_c1_h  = wt_rel_l + 32768;    short* wt_c1_l  = wt_c1_h  + 8192;    // [64][128]
    short* wt_c2_h  = wt_c1_l  + 8192;     short* wt_c2_l  = wt_c2_h  + 2048;    // [32][64]

    const dim3 blk(256);
    const int gM = (nn + 127) / 128;    // 782 row-blocks

    // --- CSR build (parallel scan) ---
    zero_int  <<<dim3((nn + 255) / 256), blk, 0, stream>>>(deg, nn);
    count_deg <<<dim3((ne + 255) / 256), blk, 0, stream>>>(dst, deg, ne);
    scan_block<<<dim3(nb), dim3(1024), 0, stream>>>(deg, rowptr, part, nn);
    scan_part <<<dim3(1),  dim3(1024), 0, stream>>>(part, nb);
    scan_add  <<<dim3((nn + 255) / 256), blk, 0, stream>>>(part, rowptr, cursor, nn, nb);
    fill_edges<<<dim3((ne + 255) / 256), blk, 0, stream>>>(src, dst, cursor, eidx, ne);

    // --- weight prep (tiny) ---
    prep_w<<<dim3(256), blk, 0, stream>>>(enc_w, 512, 128, wt_enc_h, wt_enc_l, 512, 0);
    prep_w<<<dim3(128), blk, 0, stream>>>(s0_ws, 128, 256, wt_s0_h, wt_s0_l, 256, 0);
    prep_w<<<dim3(128), blk, 0, stream>>>(s0_wn, 128, 256, wt_s0_h, wt_s0_l, 256, 128);
    prep_w<<<dim3(128), blk, 0, stream>>>(s1_ws, 256, 128, wt_st_h, wt_st_l, 256, 0);
    prep_w<<<dim3(128), blk, 0, stream>>>(s1_wn, 256, 128, wt_st_h + (size_t)128 * 256,
                                          wt_st_l + (size_t)128 * 256, 256, 0);
    prep_w<<<dim3(128), blk, 0, stream>>>(rel_w, 256, 128, wt_rel_h, wt_rel_l, 256, 0);
    prep_w<<<dim3(32),  blk, 0, stream>>>(cw1, 128, 64, wt_c1_h, wt_c1_l, 128, 0);
    prep_w<<<dim3(8),   blk, 0, stream>>>(cw2, 64, 32, wt_c2_h, wt_c2_l, 64, 0);

    // --- xb = bf16(concat(sf, mf)) : streaming convert ---
    concat_bf16<<<dim3(2048), blk, 0, stream>>>(sf, mf, xb, nn);

    // --- h0 = relu(xb @ enc_w + enc_b) -> h0b bf16 ---
    gemm_dp<4, 512, 0><<<dim3(2, gM), blk, 0, stream>>>(
        xb, 512, nullptr, 0, wt_enc_h, wt_enc_l, enc_b,
        nullptr, nullptr, nullptr, nullptr, 1,
        nullptr, 0, 0, h0b, 0, 128, nn);

    // --- agg0 = mean_neigh(h0b) -> agg0b bf16 ---
    agg_mean_bb<<<dim3((nn + 3) / 4), blk, 0, stream>>>(
        h0b, rowptr, eidx, agg0b, nn);

    // --- h1 = relu(bn0(h0@ws0 + agg0@wn0 + b0)) -> h1b bf16 ---
    gemm_dp<4, 128, 128><<<dim3(4, gM), blk, 0, stream>>>(
        h0b, 128, agg0b, 128, wt_s0_h, wt_s0_l, s0_b,
        bn0_g, bn0_b, bn0_m, bn0_v, 1,
        nullptr, 0, 0, h1b, 0, 256, nn);

    // --- [s1 | t1] = h1 @ [ws1 | wn1]; s1 fp32 -> st, t1 bf16 -> t1b ---
    gemm_dp<4, 256, 0><<<dim3(4, gM), blk, 0, stream>>>(
        h1b, 256, nullptr, 0, wt_st_h, wt_st_l, nullptr,
        nullptr, nullptr, nullptr, nullptr, 0,
        st, 128, 128, t1b, 128, 128, nn);

    // --- h2 = relu(bn1(s1 + mean_neigh(t1) + b1)) -> h2b bf16 ---
    agg_combine_bb<<<dim3((nn + 3) / 4), blk, 0, stream>>>(
        t1b, rowptr, eidx, st, s1_b,
        bn1_g, bn1_b, bn1_m, bn1_v, h2b, nn);

    // --- r = relu(h0@rel_w[:128] + h2@rel_w[128:] + rel_b) -> rb bf16 ---
    gemm_dp<4, 128, 128><<<dim3(2, gM), blk, 0, stream>>>(
        h0b, 128, h2b, 128, wt_rel_h, wt_rel_l, rel_b,
        nullptr, nullptr, nullptr, nullptr, 1,
        nullptr, 0, 0, rb, 0, 128, nn);

    // --- o1 = relu(r@cls_w1 + cb1) -> o1b bf16 [nn,64] ---
    gemm_dp<4, 128, 0><<<dim3(1, gM), blk, 0, stream>>>(
        rb, 128, nullptr, 0, wt_c1_h, wt_c1_l, cb1,
        nullptr, nullptr, nullptr, nullptr, 1,
        nullptr, 0, 0, o1b, 0, 64, nn);

    // --- out = o1@cls_w2 + cb2 -> d_out fp32 [nn,32] ---
    gemm_dp<2, 64, 0><<<dim3(1, gM), blk, 0, stream>>>(
        o1b, 64, nullptr, 0, wt_c2_h, wt_c2_l, cb2,
        nullptr, nullptr, nullptr, nullptr, 0,
        out, 32, 32, nullptr, 0, 0, nn);
}

// Round 3
// 699.199 us; speedup vs baseline: 1.5497x; 1.0280x over previous
//
#include <hip/hip_runtime.h>
#include <math.h>

// ---------------------------------------------------------------------------
// MultiModalGraphSAGE — R9.
// R8 post-mortem: GEMM fix confirmed (719 us, GEMMs < 96 us). New top:
// concat_bf16 96 us @ 2.1 TB/s — latency-bound (32 B/lane in flight).
// R9: (1) concat does 4 units/thread with all 8 float4 loads issued before
// any convert (128 B/lane in flight); (2) GEMM wave layout 4m x 1n ->
// 2m x 2n (wave = 64 rows x 32 cols): per-K-step LDS reads 80 -> 64 KB
// (B-tile no longer read by all 4 waves); (3) 8 prep_w launches fused into
// one prep_all, zero_int replaced by hipMemsetAsync.
// ---------------------------------------------------------------------------

#define EPS 1e-5f

typedef __attribute__((ext_vector_type(8))) short bf16x8;
typedef __attribute__((ext_vector_type(4))) float f32x4;

__device__ inline unsigned short f2bf(float x) {
    unsigned u = __float_as_uint(x);
    u += 0x7fff + ((u >> 16) & 1);          // RNE to bf16
    return (unsigned short)(u >> 16);
}
__device__ inline float bf2f(unsigned short h) {
    return __uint_as_float(((unsigned)h) << 16);
}
__device__ inline unsigned packbf(float x, float y) {
    return (unsigned)f2bf(x) | ((unsigned)f2bf(y) << 16);
}

__device__ inline void gload_lds16(const void* g, void* l) {
    __builtin_amdgcn_global_load_lds(
        (__attribute__((address_space(1))) void*)g,
        (__attribute__((address_space(3))) void*)l, 16, 0, 0);
}

// ---------------- CSR build ----------------

__global__ void count_deg(const int* __restrict__ dst, int* __restrict__ deg, int e) {
    int i = blockIdx.x * 256 + threadIdx.x;
    if (i < e) atomicAdd(&deg[dst[i]], 1);
}

__global__ __launch_bounds__(1024)
void scan_block(const int* __restrict__ deg, int* __restrict__ rowptr,
                int* __restrict__ part, int n) {
    __shared__ int buf[1024];
    const int tid = threadIdx.x;
    const int i = blockIdx.x * 1024 + tid;
    const int v = (i < n) ? deg[i] : 0;
    buf[tid] = v;
    __syncthreads();
    #pragma unroll 1
    for (int off = 1; off < 1024; off <<= 1) {
        int t = (tid >= off) ? buf[tid - off] : 0;
        __syncthreads();
        buf[tid] += t;
        __syncthreads();
    }
    if (i < n) rowptr[i] = buf[tid] - v;          // local exclusive
    if (tid == 1023) part[blockIdx.x] = buf[1023];
}

__global__ __launch_bounds__(1024)
void scan_part(int* __restrict__ part, int nb) {
    __shared__ int buf[1024];
    const int tid = threadIdx.x;
    const int v = (tid < nb) ? part[tid] : 0;
    buf[tid] = v;
    __syncthreads();
    #pragma unroll 1
    for (int off = 1; off < 1024; off <<= 1) {
        int t = (tid >= off) ? buf[tid - off] : 0;
        __syncthreads();
        buf[tid] += t;
        __syncthreads();
    }
    if (tid < nb) part[tid] = buf[tid] - v;       // exclusive
    if (tid == 1023) part[nb] = buf[1023];        // grand total
}

__global__ void scan_add(const int* __restrict__ part, int* __restrict__ rowptr,
                         int* __restrict__ cursor, int n, int nb) {
    int i = blockIdx.x * 256 + threadIdx.x;
    if (i < n) {
        int v = rowptr[i] + part[i >> 10];
        rowptr[i] = v;
        cursor[i] = v;
    }
    if (i == 0) rowptr[n] = part[nb];
}

__global__ void fill_edges(const int* __restrict__ src, const int* __restrict__ dst,
                           int* __restrict__ cursor, int* __restrict__ eidx, int e) {
    int i = blockIdx.x * 256 + threadIdx.x;
    if (i < e) {
        int pos = atomicAdd(&cursor[dst[i]], 1);
        eidx[pos] = src[i];
    }
}

// ---------------- fused weight prep: all W[K][N] fp32 -> hi/lo [N][ldt] ----

__global__ __launch_bounds__(256)
void prep_all(const float* __restrict__ enc_w, const float* __restrict__ s0_ws,
              const float* __restrict__ s0_wn, const float* __restrict__ s1_ws,
              const float* __restrict__ s1_wn, const float* __restrict__ rel_w,
              const float* __restrict__ cw1, const float* __restrict__ cw2,
              short* wt_enc_h, short* wt_enc_l, short* wt_s0_h, short* wt_s0_l,
              short* wt_st_h, short* wt_st_l, short* wt_rel_h, short* wt_rel_l,
              short* wt_c1_h, short* wt_c1_l, short* wt_c2_h, short* wt_c2_l) {
    int e = blockIdx.x * 256 + threadIdx.x;
    const float* W; short* hi; short* lo; int Nd, ldt, koff;
    if (e < 65536)       { W = enc_w; hi = wt_enc_h; lo = wt_enc_l; Nd = 128; ldt = 512; koff = 0; }
    else if (e < 98304)  { e -= 65536;  W = s0_ws; hi = wt_s0_h; lo = wt_s0_l; Nd = 256; ldt = 256; koff = 0; }
    else if (e < 131072) { e -= 98304;  W = s0_wn; hi = wt_s0_h; lo = wt_s0_l; Nd = 256; ldt = 256; koff = 128; }
    else if (e < 163840) { e -= 131072; W = s1_ws; hi = wt_st_h; lo = wt_st_l; Nd = 128; ldt = 256; koff = 0; }
    else if (e < 196608) { e -= 163840; W = s1_wn; hi = wt_st_h + 32768; lo = wt_st_l + 32768; Nd = 128; ldt = 256; koff = 0; }
    else if (e < 229376) { e -= 196608; W = rel_w; hi = wt_rel_h; lo = wt_rel_l; Nd = 128; ldt = 256; koff = 0; }
    else if (e < 237568) { e -= 229376; W = cw1; hi = wt_c1_h; lo = wt_c1_l; Nd = 64; ldt = 128; koff = 0; }
    else if (e < 239616) { e -= 237568; W = cw2; hi = wt_c2_h; lo = wt_c2_l; Nd = 32; ldt = 64; koff = 0; }
    else return;
    const int k = e / Nd, n = e - k * Nd;
    const float x = W[e];
    const unsigned short h = f2bf(x);
    const unsigned short l = f2bf(x - bf2f(h));
    const size_t o = (size_t)n * ldt + koff + k;
    hi[o] = (short)h;
    lo[o] = (short)l;
}

// ---------------- concat(sf,mf) fp32 -> xb bf16 [nn,512] --------------------
// 4 units (16B out each) per thread at stride S; all 8 float4 loads issued
// before any convert -> 128 B/lane in flight (latency-bound fix).

__global__ __launch_bounds__(256)
void concat_bf16(const float* __restrict__ sf, const float* __restrict__ mf,
                 short* __restrict__ xb, int nn) {
    const int S = nn * 16;                        // units per slice (64 | S)
    const int g = blockIdx.x * 256 + threadIdx.x;
    if (g >= S) return;
    const int q = g & 63;                         // same for all 4 slices
    float4 f[4][2];
    #pragma unroll
    for (int j = 0; j < 4; ++j) {
        const int n = (g + j * S) >> 6;
        const float* p = (q < 16) ? (sf + (size_t)n * 128 + (size_t)q * 8)
                                  : (mf + (size_t)n * 384 + (size_t)(q - 16) * 8);
        f[j][0] = ((const float4*)p)[0];
        f[j][1] = ((const float4*)p)[1];
    }
    #pragma unroll
    for (int j = 0; j < 4; ++j) {
        uint4 o;
        o.x = packbf(f[j][0].x, f[j][0].y); o.y = packbf(f[j][0].z, f[j][0].w);
        o.z = packbf(f[j][1].x, f[j][1].y); o.w = packbf(f[j][1].z, f[j][1].w);
        *(uint4*)(xb + (size_t)(g + j * S) * 8) = o;
    }
}

// ---------------- mean aggregation: 4 edges in flight, 16 lanes/row ---------

__global__ __launch_bounds__(256)
void agg_mean_bb(const short* __restrict__ featb,
                 const int* __restrict__ rowptr, const int* __restrict__ eidx,
                 short* __restrict__ outb, int n) {
    const int node = blockIdx.x * 4 + (threadIdx.x >> 6);
    if (node >= n) return;
    const int lane = threadIdx.x & 63;
    const int g = lane >> 4, j = lane & 15;
    const int beg = rowptr[node], end = rowptr[node + 1];
    float s[8];
    #pragma unroll
    for (int i = 0; i < 8; ++i) s[i] = 0.f;
    for (int e = beg + g; e < end; e += 4) {
        const uint4 v = *(const uint4*)(featb + (size_t)eidx[e] * 128 + j * 8);
        s[0] += __uint_as_float(v.x << 16); s[1] += __uint_as_float(v.x & 0xffff0000u);
        s[2] += __uint_as_float(v.y << 16); s[3] += __uint_as_float(v.y & 0xffff0000u);
        s[4] += __uint_as_float(v.z << 16); s[5] += __uint_as_float(v.z & 0xffff0000u);
        s[6] += __uint_as_float(v.w << 16); s[7] += __uint_as_float(v.w & 0xffff0000u);
    }
    #pragma unroll
    for (int i = 0; i < 8; ++i) {
        s[i] += __shfl_xor(s[i], 32);
        s[i] += __shfl_xor(s[i], 16);
    }
    if (g == 0) {
        const float inv = 1.0f / fmaxf((float)(end - beg), 1.0f);
        uint4 o;
        o.x = packbf(s[0] * inv, s[1] * inv);
        o.y = packbf(s[2] * inv, s[3] * inv);
        o.z = packbf(s[4] * inv, s[5] * inv);
        o.w = packbf(s[6] * inv, s[7] * inv);
        *(uint4*)(outb + (size_t)node * 128 + j * 8) = o;
    }
}

// sage1 combine: h2 = relu(bn1(s1 + mean_neigh(t1) + b1)), bf16 out
__global__ __launch_bounds__(256)
void agg_combine_bb(const short* __restrict__ featb,
                    const int* __restrict__ rowptr, const int* __restrict__ eidx,
                    const float* __restrict__ s1,          // [n,128] fp32
                    const float* __restrict__ bias,
                    const float* __restrict__ bng, const float* __restrict__ bnb,
                    const float* __restrict__ bnm, const float* __restrict__ bnv,
                    short* __restrict__ outb, int n) {
    const int node = blockIdx.x * 4 + (threadIdx.x >> 6);
    if (node >= n) return;
    const int lane = threadIdx.x & 63;
    const int g = lane >> 4, j = lane & 15;
    const int beg = rowptr[node], end = rowptr[node + 1];
    float s[8];
    #pragma unroll
    for (int i = 0; i < 8; ++i) s[i] = 0.f;
    for (int e = beg + g; e < end; e += 4) {
        const uint4 v = *(const uint4*)(featb + (size_t)eidx[e] * 128 + j * 8);
        s[0] += __uint_as_float(v.x << 16); s[1] += __uint_as_float(v.x & 0xffff0000u);
        s[2] += __uint_as_float(v.y << 16); s[3] += __uint_as_float(v.y & 0xffff0000u);
        s[4] += __uint_as_float(v.z << 16); s[5] += __uint_as_float(v.z & 0xffff0000u);
        s[6] += __uint_as_float(v.w << 16); s[7] += __uint_as_float(v.w & 0xffff0000u);
    }
    #pragma unroll
    for (int i = 0; i < 8; ++i) {
        s[i] += __shfl_xor(s[i], 32);
        s[i] += __shfl_xor(s[i], 16);
    }
    if (g == 0) {
        const float inv = 1.0f / fmaxf((float)(end - beg), 1.0f);
        const int c0 = j * 8;
        const float4 a0 = *(const float4*)(s1 + (size_t)node * 128 + c0);
        const float4 a1 = *(const float4*)(s1 + (size_t)node * 128 + c0 + 4);
        const float sf[8] = {a0.x, a0.y, a0.z, a0.w, a1.x, a1.y, a1.z, a1.w};
        float r[8];
        #pragma unroll
        for (int i = 0; i < 8; ++i) {
            const int c = c0 + i;
            float v = sf[i] + s[i] * inv + bias[c];
            v = (v - bnm[c]) * (bng[c] / sqrtf(bnv[c] + EPS)) + bnb[c];
            r[i] = fmaxf(v, 0.f);
        }
        uint4 o;
        o.x = packbf(r[0], r[1]); o.y = packbf(r[2], r[3]);
        o.z = packbf(r[4], r[5]); o.w = packbf(r[6], r[7]);
        *(uint4*)(outb + (size_t)node * 128 + j * 8) = o;
    }
}

// ---------------- all-LDS MFMA GEMM: bf16 A, split-bf16 W ------------------
// Block: 256 thr = 4 waves arranged 2m x 2n (wave = 64 rows x NT/2*16 cols).
// Tile 128 rows x NT*16 cols, BK=64, double-buffered. A+B staged by
// gload_lds16 (source pre-XOR-swizzled on 16B units, linear LDS, swizzled
// ds_read). K-loop: stage(c+1) -> vmcnt(4+NT) -> s_barrier -> ds_read+MFMA
// -> s_barrier. Per-K-step LDS reads 64 KB (was 80 with 4m x 1n).
// Epilogue: acc -> LDS fp32 -> coalesced float4/uint4 stores.
template<int NT, int K1, int K2>
__global__ __launch_bounds__(256)
void gemm_dp(const short* __restrict__ A1, int lda1,
             const short* __restrict__ A2, int lda2,
             const short* __restrict__ Wt_hi, const short* __restrict__ Wt_lo,
             const float* __restrict__ bias,
             const float* __restrict__ bng, const float* __restrict__ bnb,
             const float* __restrict__ bnm, const float* __restrict__ bnv,
             int relu,
             float* __restrict__ Cf, int fpN, int ldc,
             short* __restrict__ Cb, int bfcol0, int ldcb,
             int M) {
    constexpr int K   = K1 + K2;
    constexpr int NBK = K / 64;
    constexpr int NTW = NT / 2;
    static_assert(K % 64 == 0, "K multiple of 64");
    static_assert(NT % 2 == 0, "NT even");
    static_assert(K2 == 0 || K1 % 64 == 0, "concat boundary on BK");
    constexpr int ASZ = 128 * 64;                 // shorts (16KB)
    constexpr int BSZ = 2 * NT * 16 * 64;         // shorts (hi+lo planes)
    constexpr int BUF = ASZ + BSZ;
    __shared__ short lds[2 * BUF];

    const int tid  = threadIdx.x;
    const int lane = tid & 63;
    const int wv   = tid >> 6;
    const int wm   = wv >> 1;                     // 0..1 (row half)
    const int wn   = wv & 1;                      // 0..1 (col half)
    const int bm   = blockIdx.y * 128;
    const int col0 = blockIdx.x * (NT * 16);
    const int lrow = lane & 15;
    const int quad = lane >> 4;

    // ---- staging sources: phys (row,u) holds global unit u^(row&7) ----
    const int su = (tid & 7) ^ ((tid >> 3) & 7);
    const short* gsA1[4];
    const short* gsA2[4];
    #pragma unroll
    for (int jj = 0; jj < 4; ++jj) {
        const int rg = min(bm + jj * 32 + (tid >> 3), M - 1);
        gsA1[jj] = A1 + (size_t)rg * lda1 + su * 8;
        if constexpr (K2 > 0) gsA2[jj] = A2 + (size_t)rg * lda2 + su * 8;
        else gsA2[jj] = nullptr;
    }
    const short* gsB[NT];                         // B "rows": hi cols, then lo
    #pragma unroll
    for (int jj = 0; jj < NT; ++jj) {
        const int colIdx = jj * 32 + (tid >> 3);  // 0..2*NT*16-1
        const bool ishi = colIdx < NT * 16;
        const int cp = ishi ? colIdx : colIdx - NT * 16;
        gsB[jj] = (ishi ? Wt_hi : Wt_lo) + (size_t)(col0 + cp) * K + su * 8;
    }

    auto stage = [&](int b, int c) {
        const int k = c * 64;
        #pragma unroll
        for (int jj = 0; jj < 4; ++jj) {
            const short* p;
            if constexpr (K2 > 0)
                p = (k < K1) ? (gsA1[jj] + k) : (gsA2[jj] + (k - K1));
            else
                p = gsA1[jj] + k;
            gload_lds16(p, &lds[b * BUF + (jj * 256 + tid) * 8]);
        }
        #pragma unroll
        for (int jj = 0; jj < NT; ++jj)
            gload_lds16(gsB[jj] + k, &lds[b * BUF + ASZ + (jj * 256 + tid) * 8]);
    };

    // ---- swizzled LDS read offsets (shorts) ----
    int aoff[4][2];
    #pragma unroll
    for (int m = 0; m < 4; ++m)
        #pragma unroll
        for (int kk = 0; kk < 2; ++kk)
            aoff[m][kk] = (wm * 64 + m * 16 + lrow) * 64 +
                          (((kk * 4 + quad) ^ (lrow & 7)) * 8);
    int boff[NTW][2];
    #pragma unroll
    for (int nt = 0; nt < NTW; ++nt)
        #pragma unroll
        for (int kk = 0; kk < 2; ++kk)
            boff[nt][kk] = (wn * NTW * 16 + nt * 16 + lrow) * 64 +
                           (((kk * 4 + quad) ^ (lrow & 7)) * 8);

    f32x4 acc[4][NTW];
    #pragma unroll
    for (int m = 0; m < 4; ++m)
        #pragma unroll
        for (int nt = 0; nt < NTW; ++nt)
            acc[m][nt] = (f32x4){0.f, 0.f, 0.f, 0.f};

    stage(0, 0);

    for (int c = 0; c < NBK; ++c) {
        const int b = c & 1;
        if (c + 1 < NBK) {
            stage(b ^ 1, c + 1);
            // keep stage(c+1)'s 4+NT loads in flight; drain stage(c)
            if constexpr (NT == 4) asm volatile("s_waitcnt vmcnt(8)" ::: "memory");
            else                   asm volatile("s_waitcnt vmcnt(6)" ::: "memory");
        } else {
            asm volatile("s_waitcnt vmcnt(0)" ::: "memory");
        }
        __builtin_amdgcn_s_barrier();             // buf b fully staged

        const short* La = &lds[b * BUF];
        const short* Lb = &lds[b * BUF + ASZ];
        #pragma unroll
        for (int kk = 0; kk < 2; ++kk) {
            bf16x8 a[4];
            #pragma unroll
            for (int m = 0; m < 4; ++m)
                a[m] = *(const bf16x8*)(La + aoff[m][kk]);
            #pragma unroll
            for (int nt = 0; nt < NTW; ++nt) {
                const bf16x8 vbh = *(const bf16x8*)(Lb + boff[nt][kk]);
                const bf16x8 vbl = *(const bf16x8*)(Lb + boff[nt][kk] + NT * 16 * 64);
                #pragma unroll
                for (int m = 0; m < 4; ++m) {
                    acc[m][nt] = __builtin_amdgcn_mfma_f32_16x16x32_bf16(a[m], vbh, acc[m][nt], 0, 0, 0);
                    acc[m][nt] = __builtin_amdgcn_mfma_f32_16x16x32_bf16(a[m], vbl, acc[m][nt], 0, 0, 0);
                }
            }
        }
        asm volatile("" ::: "memory");
        __builtin_amdgcn_s_barrier();             // all waves done with buf b
    }

    // ---- epilogue via LDS: coalesced stores ----
    constexpr int EW = NT * 16 + 4;               // fp32 row stride (16B-aligned)
    float* ep = (float*)lds;

    #pragma unroll
    for (int nt = 0; nt < NTW; ++nt) {
        const int lcol = wn * NTW * 16 + nt * 16 + lrow;
        const int gcol = col0 + lcol;
        const float bsc = bias ? bias[gcol] : 0.f;
        float gg = 1.f, bb = 0.f, mm = 0.f;
        if (bng) { gg = bng[gcol] / sqrtf(bnv[gcol] + EPS); bb = bnb[gcol]; mm = bnm[gcol]; }
        #pragma unroll
        for (int m = 0; m < 4; ++m) {
            #pragma unroll
            for (int r = 0; r < 4; ++r) {
                float x = acc[m][nt][r] + bsc;
                if (bng) x = (x - mm) * gg + bb;
                if (relu) x = fmaxf(x, 0.f);
                ep[(wm * 64 + m * 16 + quad * 4 + r) * EW + lcol] = x;
            }
        }
    }
    __syncthreads();

    if (col0 < fpN) {                             // fp32-target block
        for (int g = tid; g < 128 * NT * 4; g += 256) {
            const int row = g / (NT * 4), u = g - row * (NT * 4);
            const int grow = bm + row;
            if (grow < M)
                *(float4*)(Cf + (size_t)grow * ldc + col0 + u * 4) =
                    *(const float4*)(ep + row * EW + u * 4);
        }
    } else {                                      // bf16-target block
        for (int g = tid; g < 128 * NT * 2; g += 256) {
            const int row = g / (NT * 2), u = g - row * (NT * 2);
            const int grow = bm + row;
            const float4 f0 = *(const float4*)(ep + row * EW + u * 8);
            const float4 f1 = *(const float4*)(ep + row * EW + u * 8 + 4);
            uint4 o;
            o.x = packbf(f0.x, f0.y); o.y = packbf(f0.z, f0.w);
            o.z = packbf(f1.x, f1.y); o.w = packbf(f1.z, f1.w);
            if (grow < M)
                *(uint4*)(Cb + (size_t)grow * ldcb + (col0 - bfcol0) + u * 8) = o;
        }
    }
}

// ---------------------------------------------------------------------------

extern "C" void kernel_launch(void* const* d_in, const int* in_sizes, int n_in,
                              void* d_out, int out_size, void* d_ws, size_t ws_size,
                              hipStream_t stream) {
    const float* sf    = (const float*)d_in[0];
    const float* mf    = (const float*)d_in[1];
    const int*   src   = (const int*)d_in[2];
    const int*   dst   = (const int*)d_in[3];
    const float* enc_w = (const float*)d_in[4];
    const float* enc_b = (const float*)d_in[5];
    const float* s0_ws = (const float*)d_in[6];
    const float* s0_wn = (const float*)d_in[7];
    const float* s0_b  = (const float*)d_in[8];
    const float* bn0_g = (const float*)d_in[9];
    const float* bn0_b = (const float*)d_in[10];
    const float* bn0_m = (const float*)d_in[11];
    const float* bn0_v = (const float*)d_in[12];
    const float* s1_ws = (const float*)d_in[13];
    const float* s1_wn = (const float*)d_in[14];
    const float* s1_b  = (const float*)d_in[15];
    const float* bn1_g = (const float*)d_in[16];
    const float* bn1_b = (const float*)d_in[17];
    const float* bn1_m = (const float*)d_in[18];
    const float* bn1_v = (const float*)d_in[19];
    const float* rel_w = (const float*)d_in[20];
    const float* rel_b = (const float*)d_in[21];
    const float* cw1   = (const float*)d_in[22];
    const float* cb1   = (const float*)d_in[23];
    const float* cw2   = (const float*)d_in[24];
    const float* cb2   = (const float*)d_in[25];
    float* out = (float*)d_out;

    const int nn = in_sizes[0] / 128;   // 100000
    const int ne = in_sizes[2];         // 800000
    const int nb = (nn + 1023) / 1024;  // scan blocks (98)

    // workspace layout. xb [nn,512] bf16 is dead after the enc GEMM, so the
    // later st (fp32 [nn,128]) + h1b (bf16 [nn,256]) alias its footprint.
    short* h0b   = (short*)d_ws;                       // [nn,128] bf16
    short* xb    = h0b + (size_t)nn * 128;             // [nn,512] bf16 (enc A)
    float* st    = (float*)xb;                         // s1 fp32 [nn,128]
    short* h1b   = (short*)(st + (size_t)nn * 128);    // [nn,256] bf16
    short* agg0b = xb + (size_t)nn * 512;              // [nn,128]; reused as o1b
    short* t1b   = agg0b + (size_t)nn * 128;           // [nn,128]; reused as rb
    short* h2b   = t1b + (size_t)nn * 128;             // [nn,128]
    short* o1b   = agg0b;                              // [nn,64] (agg0b dead)
    short* rb    = t1b;                                // [nn,128] (t1b dead)
    int* deg    = (int*)(h2b + (size_t)nn * 128);
    int* rowptr = deg + nn;
    int* cursor = rowptr + nn + 1;
    int* part   = cursor + nn;                         // [nb+1]
    int* eidx   = part + nb + 1;
    // bf16 weight planes (hi, lo) — transposed [N][K]
    short* wts = (short*)(eidx + ne);
    short* wt_enc_h = wts;                 short* wt_enc_l = wt_enc_h + 65536;   // [128][512]
    short* wt_s0_h  = wt_enc_l + 65536;    short* wt_s0_l  = wt_s0_h  + 65536;   // [256][256]
    short* wt_st_h  = wt_s0_l  + 65536;    short* wt_st_l  = wt_st_h  + 65536;   // [256][256]
    short* wt_rel_h = wt_st_l  + 65536;    short* wt_rel_l = wt_rel_h + 32768;   // [128][256]
    short* wt_c1_h  = wt_rel_l + 32768;    short* wt_c1_l  = wt_c1_h  + 8192;    // [64][128]
    short* wt_c2_h  = wt_c1_l  + 8192;     short* wt_c2_l  = wt_c2_h  + 2048;    // [32][64]

    const dim3 blk(256);
    const int gM = (nn + 127) / 128;    // 782 row-blocks

    // --- CSR build (parallel scan) ---
    hipMemsetAsync(deg, 0, (size_t)nn * 4, stream);
    count_deg <<<dim3((ne + 255) / 256), blk, 0, stream>>>(dst, deg, ne);
    scan_block<<<dim3(nb), dim3(1024), 0, stream>>>(deg, rowptr, part, nn);
    scan_part <<<dim3(1),  dim3(1024), 0, stream>>>(part, nb);
    scan_add  <<<dim3((nn + 255) / 256), blk, 0, stream>>>(part, rowptr, cursor, nn, nb);
    fill_edges<<<dim3((ne + 255) / 256), blk, 0, stream>>>(src, dst, cursor, eidx, ne);

    // --- weight prep (fused, 1 launch) ---
    prep_all<<<dim3(936), blk, 0, stream>>>(
        enc_w, s0_ws, s0_wn, s1_ws, s1_wn, rel_w, cw1, cw2,
        wt_enc_h, wt_enc_l, wt_s0_h, wt_s0_l, wt_st_h, wt_st_l,
        wt_rel_h, wt_rel_l, wt_c1_h, wt_c1_l, wt_c2_h, wt_c2_l);

    // --- xb = bf16(concat(sf, mf)) : streaming convert, 4 units/thread ---
    concat_bf16<<<dim3((nn * 16 + 255) / 256), blk, 0, stream>>>(sf, mf, xb, nn);

    // --- h0 = relu(xb @ enc_w + enc_b) -> h0b bf16 ---
    gemm_dp<4, 512, 0><<<dim3(2, gM), blk, 0, stream>>>(
        xb, 512, nullptr, 0, wt_enc_h, wt_enc_l, enc_b,
        nullptr, nullptr, nullptr, nullptr, 1,
        nullptr, 0, 0, h0b, 0, 128, nn);

    // --- agg0 = mean_neigh(h0b) -> agg0b bf16 ---
    agg_mean_bb<<<dim3((nn + 3) / 4), blk, 0, stream>>>(
        h0b, rowptr, eidx, agg0b, nn);

    // --- h1 = relu(bn0(h0@ws0 + agg0@wn0 + b0)) -> h1b bf16 ---
    gemm_dp<4, 128, 128><<<dim3(4, gM), blk, 0, stream>>>(
        h0b, 128, agg0b, 128, wt_s0_h, wt_s0_l, s0_b,
        bn0_g, bn0_b, bn0_m, bn0_v, 1,
        nullptr, 0, 0, h1b, 0, 256, nn);

    // --- [s1 | t1] = h1 @ [ws1 | wn1]; s1 fp32 -> st, t1 bf16 -> t1b ---
    gemm_dp<4, 256, 0><<<dim3(4, gM), blk, 0, stream>>>(
        h1b, 256, nullptr, 0, wt_st_h, wt_st_l, nullptr,
        nullptr, nullptr, nullptr, nullptr, 0,
        st, 128, 128, t1b, 128, 128, nn);

    // --- h2 = relu(bn1(s1 + mean_neigh(t1) + b1)) -> h2b bf16 ---
    agg_combine_bb<<<dim3((nn + 3) / 4), blk, 0, stream>>>(
        t1b, rowptr, eidx, st, s1_b,
        bn1_g, bn1_b, bn1_m, bn1_v, h2b, nn);

    // --- r = relu(h0@rel_w[:128] + h2@rel_w[128:] + rel_b) -> rb bf16 ---
    gemm_dp<4, 128, 128><<<dim3(2, gM), blk, 0, stream>>>(
        h0b, 128, h2b, 128, wt_rel_h, wt_rel_l, rel_b,
        nullptr, nullptr, nullptr, nullptr, 1,
        nullptr, 0, 0, rb, 0, 128, nn);

    // --- o1 = relu(r@cls_w1 + cb1) -> o1b bf16 [nn,64] ---
    gemm_dp<4, 128, 0><<<dim3(1, gM), blk, 0, stream>>>(
        rb, 128, nullptr, 0, wt_c1_h, wt_c1_l, cb1,
        nullptr, nullptr, nullptr, nullptr, 1,
        nullptr, 0, 0, o1b, 0, 64, nn);

    // --- out = o1@cls_w2 + cb2 -> d_out fp32 [nn,32] ---
    gemm_dp<2, 64, 0><<<dim3(1, gM), blk, 0, stream>>>(
        o1b, 64, nullptr, 0, wt_c2_h, wt_c2_l, cb2,
        nullptr, nullptr, nullptr, nullptr, 0,
        out, 32, 32, nullptr, 0, 0, nn);
}

// Round 4
// 691.847 us; speedup vs baseline: 1.5662x; 1.0106x over previous
//
#include <hip/hip_runtime.h>
#include <math.h>

// ---------------------------------------------------------------------------
// MultiModalGraphSAGE — R10.
// R9 post-mortem: concat stuck at 2.2 TB/s, VGPR=20 proves the compiler
// collapsed the 8-float4 register window again (same as R7 GEMM). R10:
// concat staged through LDS via global_load_lds (VGPR-free deep queue,
// counted vmcnt(2)) — the mechanism the compiler can't defeat. Also fuses
// cls1+cls2 into one kernel (phase1 K-loop -> fp32 ep in LDS -> phase2
// 16 MFMAs vs w2 -> out), numerics bit-identical to the o1b round trip.
// ---------------------------------------------------------------------------

#define EPS 1e-5f

typedef __attribute__((ext_vector_type(8))) short bf16x8;
typedef __attribute__((ext_vector_type(4))) float f32x4;

__device__ inline unsigned short f2bf(float x) {
    unsigned u = __float_as_uint(x);
    u += 0x7fff + ((u >> 16) & 1);          // RNE to bf16
    return (unsigned short)(u >> 16);
}
__device__ inline float bf2f(unsigned short h) {
    return __uint_as_float(((unsigned)h) << 16);
}
__device__ inline unsigned packbf(float x, float y) {
    return (unsigned)f2bf(x) | ((unsigned)f2bf(y) << 16);
}

__device__ inline void gload_lds16(const void* g, void* l) {
    __builtin_amdgcn_global_load_lds(
        (__attribute__((address_space(1))) void*)g,
        (__attribute__((address_space(3))) void*)l, 16, 0, 0);
}

// ---------------- CSR build ----------------

__global__ void count_deg(const int* __restrict__ dst, int* __restrict__ deg, int e) {
    int i = blockIdx.x * 256 + threadIdx.x;
    if (i < e) atomicAdd(&deg[dst[i]], 1);
}

__global__ __launch_bounds__(1024)
void scan_block(const int* __restrict__ deg, int* __restrict__ rowptr,
                int* __restrict__ part, int n) {
    __shared__ int buf[1024];
    const int tid = threadIdx.x;
    const int i = blockIdx.x * 1024 + tid;
    const int v = (i < n) ? deg[i] : 0;
    buf[tid] = v;
    __syncthreads();
    #pragma unroll 1
    for (int off = 1; off < 1024; off <<= 1) {
        int t = (tid >= off) ? buf[tid - off] : 0;
        __syncthreads();
        buf[tid] += t;
        __syncthreads();
    }
    if (i < n) rowptr[i] = buf[tid] - v;          // local exclusive
    if (tid == 1023) part[blockIdx.x] = buf[1023];
}

__global__ __launch_bounds__(1024)
void scan_part(int* __restrict__ part, int nb) {
    __shared__ int buf[1024];
    const int tid = threadIdx.x;
    const int v = (tid < nb) ? part[tid] : 0;
    buf[tid] = v;
    __syncthreads();
    #pragma unroll 1
    for (int off = 1; off < 1024; off <<= 1) {
        int t = (tid >= off) ? buf[tid - off] : 0;
        __syncthreads();
        buf[tid] += t;
        __syncthreads();
    }
    if (tid < nb) part[tid] = buf[tid] - v;       // exclusive
    if (tid == 1023) part[nb] = buf[1023];        // grand total
}

__global__ void scan_add(const int* __restrict__ part, int* __restrict__ rowptr,
                         int* __restrict__ cursor, int n, int nb) {
    int i = blockIdx.x * 256 + threadIdx.x;
    if (i < n) {
        int v = rowptr[i] + part[i >> 10];
        rowptr[i] = v;
        cursor[i] = v;
    }
    if (i == 0) rowptr[n] = part[nb];
}

__global__ void fill_edges(const int* __restrict__ src, const int* __restrict__ dst,
                           int* __restrict__ cursor, int* __restrict__ eidx, int e) {
    int i = blockIdx.x * 256 + threadIdx.x;
    if (i < e) {
        int pos = atomicAdd(&cursor[dst[i]], 1);
        eidx[pos] = src[i];
    }
}

// ---------------- fused weight prep: all W[K][N] fp32 -> hi/lo [N][ldt] ----

__global__ __launch_bounds__(256)
void prep_all(const float* __restrict__ enc_w, const float* __restrict__ s0_ws,
              const float* __restrict__ s0_wn, const float* __restrict__ s1_ws,
              const float* __restrict__ s1_wn, const float* __restrict__ rel_w,
              const float* __restrict__ cw1, const float* __restrict__ cw2,
              short* wt_enc_h, short* wt_enc_l, short* wt_s0_h, short* wt_s0_l,
              short* wt_st_h, short* wt_st_l, short* wt_rel_h, short* wt_rel_l,
              short* wt_c1_h, short* wt_c1_l, short* wt_c2_h, short* wt_c2_l) {
    int e = blockIdx.x * 256 + threadIdx.x;
    const float* W; short* hi; short* lo; int Nd, ldt, koff;
    if (e < 65536)       { W = enc_w; hi = wt_enc_h; lo = wt_enc_l; Nd = 128; ldt = 512; koff = 0; }
    else if (e < 98304)  { e -= 65536;  W = s0_ws; hi = wt_s0_h; lo = wt_s0_l; Nd = 256; ldt = 256; koff = 0; }
    else if (e < 131072) { e -= 98304;  W = s0_wn; hi = wt_s0_h; lo = wt_s0_l; Nd = 256; ldt = 256; koff = 128; }
    else if (e < 163840) { e -= 131072; W = s1_ws; hi = wt_st_h; lo = wt_st_l; Nd = 128; ldt = 256; koff = 0; }
    else if (e < 196608) { e -= 163840; W = s1_wn; hi = wt_st_h + 32768; lo = wt_st_l + 32768; Nd = 128; ldt = 256; koff = 0; }
    else if (e < 229376) { e -= 196608; W = rel_w; hi = wt_rel_h; lo = wt_rel_l; Nd = 128; ldt = 256; koff = 0; }
    else if (e < 237568) { e -= 229376; W = cw1; hi = wt_c1_h; lo = wt_c1_l; Nd = 64; ldt = 128; koff = 0; }
    else if (e < 239616) { e -= 237568; W = cw2; hi = wt_c2_h; lo = wt_c2_l; Nd = 32; ldt = 64; koff = 0; }
    else return;
    const int k = e / Nd, n = e - k * Nd;
    const float x = W[e];
    const unsigned short h = f2bf(x);
    const unsigned short l = f2bf(x - bf2f(h));
    const size_t o = (size_t)n * ldt + koff + k;
    hi[o] = (short)h;
    lo[o] = (short)l;
}

// ---------------- concat(sf,mf) fp32 -> xb bf16 [nn,512] --------------------
// LDS-staged streaming: per iter a block stages 4 input rows (sf 2KB + mf
// 6KB, linear) via global_load_lds, counted vmcnt(2) keeps next-iter stage
// in flight; convert phase reads LDS, one coalesced uint4 store/thread.

__global__ __launch_bounds__(256)
void concat_bf16(const float* __restrict__ sf, const float* __restrict__ mf,
                 short* __restrict__ xb, int nn) {
    __shared__ float lds[2 * 2048];               // 2 x 8 KB
    const int t = threadIdx.x;
    const int nIter = nn >> 2;                    // 4 rows / iter

    // staging sources (16B unit e: e<128 -> sf, else mf; dst = e*16 linear)
    const float* P1; size_t ld1;
    if (t < 128) { P1 = sf + (size_t)(t >> 5) * 128 + (t & 31) * 4; ld1 = 128; }
    else { const int em = t - 128;
           P1 = mf + (size_t)(em / 96) * 384 + (em % 96) * 4; ld1 = 384; }
    const int em2 = t + 128;                      // second unit: always mf
    const float* P2 = mf + (size_t)(em2 / 96) * 384 + (em2 % 96) * 4;

    // convert-phase LDS read address (floats within buffer)
    const int n = t >> 6, q = t & 63;
    const int raddr = (q < 16) ? (n * 128 + q * 8)
                               : (512 + n * 384 + (q - 16) * 8);

    int it = blockIdx.x;
    if (it >= nIter) return;
    {
        const size_t r0 = (size_t)it * 4;
        gload_lds16(P1 + r0 * ld1, (char*)lds + t * 16);
        gload_lds16(P2 + r0 * 384, (char*)lds + 4096 + t * 16);
    }
    int b = 0;
    for (; it < nIter; it += gridDim.x) {
        const int nx = it + gridDim.x;
        if (nx < nIter) {
            const size_t r0 = (size_t)nx * 4;
            gload_lds16(P1 + r0 * ld1, (char*)lds + (b ^ 1) * 8192 + t * 16);
            gload_lds16(P2 + r0 * 384, (char*)lds + (b ^ 1) * 8192 + 4096 + t * 16);
            // only the 2 next-iter stages may remain outstanding
            asm volatile("s_waitcnt vmcnt(2)" ::: "memory");
        } else {
            asm volatile("s_waitcnt vmcnt(0)" ::: "memory");
        }
        __builtin_amdgcn_s_barrier();
        const float* base = lds + b * 2048 + raddr;
        const float4 f0 = *(const float4*)base;
        const float4 f1 = *(const float4*)(base + 4);
        uint4 o;
        o.x = packbf(f0.x, f0.y); o.y = packbf(f0.z, f0.w);
        o.z = packbf(f1.x, f1.y); o.w = packbf(f1.z, f1.w);
        *(uint4*)(xb + ((size_t)it * 256 + t) * 8) = o;
        __builtin_amdgcn_s_barrier();             // all reads of buf b done
        b ^= 1;
    }
}

// ---------------- mean aggregation: 4 edges in flight, 16 lanes/row ---------

__global__ __launch_bounds__(256)
void agg_mean_bb(const short* __restrict__ featb,
                 const int* __restrict__ rowptr, const int* __restrict__ eidx,
                 short* __restrict__ outb, int n) {
    const int node = blockIdx.x * 4 + (threadIdx.x >> 6);
    if (node >= n) return;
    const int lane = threadIdx.x & 63;
    const int g = lane >> 4, j = lane & 15;
    const int beg = rowptr[node], end = rowptr[node + 1];
    float s[8];
    #pragma unroll
    for (int i = 0; i < 8; ++i) s[i] = 0.f;
    for (int e = beg + g; e < end; e += 4) {
        const uint4 v = *(const uint4*)(featb + (size_t)eidx[e] * 128 + j * 8);
        s[0] += __uint_as_float(v.x << 16); s[1] += __uint_as_float(v.x & 0xffff0000u);
        s[2] += __uint_as_float(v.y << 16); s[3] += __uint_as_float(v.y & 0xffff0000u);
        s[4] += __uint_as_float(v.z << 16); s[5] += __uint_as_float(v.z & 0xffff0000u);
        s[6] += __uint_as_float(v.w << 16); s[7] += __uint_as_float(v.w & 0xffff0000u);
    }
    #pragma unroll
    for (int i = 0; i < 8; ++i) {
        s[i] += __shfl_xor(s[i], 32);
        s[i] += __shfl_xor(s[i], 16);
    }
    if (g == 0) {
        const float inv = 1.0f / fmaxf((float)(end - beg), 1.0f);
        uint4 o;
        o.x = packbf(s[0] * inv, s[1] * inv);
        o.y = packbf(s[2] * inv, s[3] * inv);
        o.z = packbf(s[4] * inv, s[5] * inv);
        o.w = packbf(s[6] * inv, s[7] * inv);
        *(uint4*)(outb + (size_t)node * 128 + j * 8) = o;
    }
}

// sage1 combine: h2 = relu(bn1(s1 + mean_neigh(t1) + b1)), bf16 out
__global__ __launch_bounds__(256)
void agg_combine_bb(const short* __restrict__ featb,
                    const int* __restrict__ rowptr, const int* __restrict__ eidx,
                    const float* __restrict__ s1,          // [n,128] fp32
                    const float* __restrict__ bias,
                    const float* __restrict__ bng, const float* __restrict__ bnb,
                    const float* __restrict__ bnm, const float* __restrict__ bnv,
                    short* __restrict__ outb, int n) {
    const int node = blockIdx.x * 4 + (threadIdx.x >> 6);
    if (node >= n) return;
    const int lane = threadIdx.x & 63;
    const int g = lane >> 4, j = lane & 15;
    const int beg = rowptr[node], end = rowptr[node + 1];
    float s[8];
    #pragma unroll
    for (int i = 0; i < 8; ++i) s[i] = 0.f;
    for (int e = beg + g; e < end; e += 4) {
        const uint4 v = *(const uint4*)(featb + (size_t)eidx[e] * 128 + j * 8);
        s[0] += __uint_as_float(v.x << 16); s[1] += __uint_as_float(v.x & 0xffff0000u);
        s[2] += __uint_as_float(v.y << 16); s[3] += __uint_as_float(v.y & 0xffff0000u);
        s[4] += __uint_as_float(v.z << 16); s[5] += __uint_as_float(v.z & 0xffff0000u);
        s[6] += __uint_as_float(v.w << 16); s[7] += __uint_as_float(v.w & 0xffff0000u);
    }
    #pragma unroll
    for (int i = 0; i < 8; ++i) {
        s[i] += __shfl_xor(s[i], 32);
        s[i] += __shfl_xor(s[i], 16);
    }
    if (g == 0) {
        const float inv = 1.0f / fmaxf((float)(end - beg), 1.0f);
        const int c0 = j * 8;
        const float4 a0 = *(const float4*)(s1 + (size_t)node * 128 + c0);
        const float4 a1 = *(const float4*)(s1 + (size_t)node * 128 + c0 + 4);
        const float sf[8] = {a0.x, a0.y, a0.z, a0.w, a1.x, a1.y, a1.z, a1.w};
        float r[8];
        #pragma unroll
        for (int i = 0; i < 8; ++i) {
            const int c = c0 + i;
            float v = sf[i] + s[i] * inv + bias[c];
            v = (v - bnm[c]) * (bng[c] / sqrtf(bnv[c] + EPS)) + bnb[c];
            r[i] = fmaxf(v, 0.f);
        }
        uint4 o;
        o.x = packbf(r[0], r[1]); o.y = packbf(r[2], r[3]);
        o.z = packbf(r[4], r[5]); o.w = packbf(r[6], r[7]);
        *(uint4*)(outb + (size_t)node * 128 + j * 8) = o;
    }
}

// ---------------- all-LDS MFMA GEMM: bf16 A, split-bf16 W ------------------
// Block: 256 thr = 4 waves arranged 2m x 2n (wave = 64 rows x NT/2*16 cols).
// Tile 128 rows x NT*16 cols, BK=64, double-buffered. A+B staged by
// gload_lds16 (source pre-XOR-swizzled on 16B units, linear LDS, swizzled
// ds_read). K-loop: stage(c+1) -> vmcnt(4+NT) -> s_barrier -> ds_read+MFMA
// -> s_barrier. Epilogue: acc -> LDS fp32 -> coalesced float4/uint4 stores.
template<int NT, int K1, int K2>
__global__ __launch_bounds__(256)
void gemm_dp(const short* __restrict__ A1, int lda1,
             const short* __restrict__ A2, int lda2,
             const short* __restrict__ Wt_hi, const short* __restrict__ Wt_lo,
             const float* __restrict__ bias,
             const float* __restrict__ bng, const float* __restrict__ bnb,
             const float* __restrict__ bnm, const float* __restrict__ bnv,
             int relu,
             float* __restrict__ Cf, int fpN, int ldc,
             short* __restrict__ Cb, int bfcol0, int ldcb,
             int M) {
    constexpr int K   = K1 + K2;
    constexpr int NBK = K / 64;
    constexpr int NTW = NT / 2;
    static_assert(K % 64 == 0, "K multiple of 64");
    static_assert(NT % 2 == 0, "NT even");
    static_assert(K2 == 0 || K1 % 64 == 0, "concat boundary on BK");
    constexpr int ASZ = 128 * 64;                 // shorts (16KB)
    constexpr int BSZ = 2 * NT * 16 * 64;         // shorts (hi+lo planes)
    constexpr int BUF = ASZ + BSZ;
    __shared__ short lds[2 * BUF];

    const int tid  = threadIdx.x;
    const int lane = tid & 63;
    const int wv   = tid >> 6;
    const int wm   = wv >> 1;                     // 0..1 (row half)
    const int wn   = wv & 1;                      // 0..1 (col half)
    const int bm   = blockIdx.y * 128;
    const int col0 = blockIdx.x * (NT * 16);
    const int lrow = lane & 15;
    const int quad = lane >> 4;

    // ---- staging sources: phys (row,u) holds global unit u^(row&7) ----
    const int su = (tid & 7) ^ ((tid >> 3) & 7);
    const short* gsA1[4];
    const short* gsA2[4];
    #pragma unroll
    for (int jj = 0; jj < 4; ++jj) {
        const int rg = min(bm + jj * 32 + (tid >> 3), M - 1);
        gsA1[jj] = A1 + (size_t)rg * lda1 + su * 8;
        if constexpr (K2 > 0) gsA2[jj] = A2 + (size_t)rg * lda2 + su * 8;
        else gsA2[jj] = nullptr;
    }
    const short* gsB[NT];                         // B "rows": hi cols, then lo
    #pragma unroll
    for (int jj = 0; jj < NT; ++jj) {
        const int colIdx = jj * 32 + (tid >> 3);  // 0..2*NT*16-1
        const bool ishi = colIdx < NT * 16;
        const int cp = ishi ? colIdx : colIdx - NT * 16;
        gsB[jj] = (ishi ? Wt_hi : Wt_lo) + (size_t)(col0 + cp) * K + su * 8;
    }

    auto stage = [&](int b, int c) {
        const int k = c * 64;
        #pragma unroll
        for (int jj = 0; jj < 4; ++jj) {
            const short* p;
            if constexpr (K2 > 0)
                p = (k < K1) ? (gsA1[jj] + k) : (gsA2[jj] + (k - K1));
            else
                p = gsA1[jj] + k;
            gload_lds16(p, &lds[b * BUF + (jj * 256 + tid) * 8]);
        }
        #pragma unroll
        for (int jj = 0; jj < NT; ++jj)
            gload_lds16(gsB[jj] + k, &lds[b * BUF + ASZ + (jj * 256 + tid) * 8]);
    };

    // ---- swizzled LDS read offsets (shorts) ----
    int aoff[4][2];
    #pragma unroll
    for (int m = 0; m < 4; ++m)
        #pragma unroll
        for (int kk = 0; kk < 2; ++kk)
            aoff[m][kk] = (wm * 64 + m * 16 + lrow) * 64 +
                          (((kk * 4 + quad) ^ (lrow & 7)) * 8);
    int boff[NTW][2];
    #pragma unroll
    for (int nt = 0; nt < NTW; ++nt)
        #pragma unroll
        for (int kk = 0; kk < 2; ++kk)
            boff[nt][kk] = (wn * NTW * 16 + nt * 16 + lrow) * 64 +
                           (((kk * 4 + quad) ^ (lrow & 7)) * 8);

    f32x4 acc[4][NTW];
    #pragma unroll
    for (int m = 0; m < 4; ++m)
        #pragma unroll
        for (int nt = 0; nt < NTW; ++nt)
            acc[m][nt] = (f32x4){0.f, 0.f, 0.f, 0.f};

    stage(0, 0);

    for (int c = 0; c < NBK; ++c) {
        const int b = c & 1;
        if (c + 1 < NBK) {
            stage(b ^ 1, c + 1);
            // keep stage(c+1)'s 4+NT loads in flight; drain stage(c)
            if constexpr (NT == 4) asm volatile("s_waitcnt vmcnt(8)" ::: "memory");
            else                   asm volatile("s_waitcnt vmcnt(6)" ::: "memory");
        } else {
            asm volatile("s_waitcnt vmcnt(0)" ::: "memory");
        }
        __builtin_amdgcn_s_barrier();             // buf b fully staged

        const short* La = &lds[b * BUF];
        const short* Lb = &lds[b * BUF + ASZ];
        #pragma unroll
        for (int kk = 0; kk < 2; ++kk) {
            bf16x8 a[4];
            #pragma unroll
            for (int m = 0; m < 4; ++m)
                a[m] = *(const bf16x8*)(La + aoff[m][kk]);
            #pragma unroll
            for (int nt = 0; nt < NTW; ++nt) {
                const bf16x8 vbh = *(const bf16x8*)(Lb + boff[nt][kk]);
                const bf16x8 vbl = *(const bf16x8*)(Lb + boff[nt][kk] + NT * 16 * 64);
                #pragma unroll
                for (int m = 0; m < 4; ++m) {
                    acc[m][nt] = __builtin_amdgcn_mfma_f32_16x16x32_bf16(a[m], vbh, acc[m][nt], 0, 0, 0);
                    acc[m][nt] = __builtin_amdgcn_mfma_f32_16x16x32_bf16(a[m], vbl, acc[m][nt], 0, 0, 0);
                }
            }
        }
        asm volatile("" ::: "memory");
        __builtin_amdgcn_s_barrier();             // all waves done with buf b
    }

    // ---- epilogue via LDS: coalesced stores ----
    constexpr int EW = NT * 16 + 4;               // fp32 row stride (16B-aligned)
    float* ep = (float*)lds;

    #pragma unroll
    for (int nt = 0; nt < NTW; ++nt) {
        const int lcol = wn * NTW * 16 + nt * 16 + lrow;
        const int gcol = col0 + lcol;
        const float bsc = bias ? bias[gcol] : 0.f;
        float gg = 1.f, bb = 0.f, mm = 0.f;
        if (bng) { gg = bng[gcol] / sqrtf(bnv[gcol] + EPS); bb = bnb[gcol]; mm = bnm[gcol]; }
        #pragma unroll
        for (int m = 0; m < 4; ++m) {
            #pragma unroll
            for (int r = 0; r < 4; ++r) {
                float x = acc[m][nt][r] + bsc;
                if (bng) x = (x - mm) * gg + bb;
                if (relu) x = fmaxf(x, 0.f);
                ep[(wm * 64 + m * 16 + quad * 4 + r) * EW + lcol] = x;
            }
        }
    }
    __syncthreads();

    if (col0 < fpN) {                             // fp32-target block
        for (int g = tid; g < 128 * NT * 4; g += 256) {
            const int row = g / (NT * 4), u = g - row * (NT * 4);
            const int grow = bm + row;
            if (grow < M)
                *(float4*)(Cf + (size_t)grow * ldc + col0 + u * 4) =
                    *(const float4*)(ep + row * EW + u * 4);
        }
    } else {                                      // bf16-target block
        for (int g = tid; g < 128 * NT * 2; g += 256) {
            const int row = g / (NT * 2), u = g - row * (NT * 2);
            const int grow = bm + row;
            const float4 f0 = *(const float4*)(ep + row * EW + u * 8);
            const float4 f1 = *(const float4*)(ep + row * EW + u * 8 + 4);
            uint4 o;
            o.x = packbf(f0.x, f0.y); o.y = packbf(f0.z, f0.w);
            o.z = packbf(f1.x, f1.y); o.w = packbf(f1.z, f1.w);
            if (grow < M)
                *(uint4*)(Cb + (size_t)grow * ldcb + (col0 - bfcol0) + u * 8) = o;
        }
    }
}

// ---------------- fused classifier: out = relu(rb@w1+b1)@w2+b2 -------------
// Phase 1: standard K-loop (K=128, NT=4 -> 64 cols) -> relu -> ep fp32 LDS.
// Phase 2: A-frags packed from ep via f2bf (bit-identical to the old o1b
// round trip), B = w2 hi/lo from global (L2-hot), 16+16 MFMAs -> ep2 ->
// coalesced float4 stores of out [M,32].
__global__ __launch_bounds__(256)
void gemm_cls(const short* __restrict__ A1,            // rb [M,128]
              const short* __restrict__ W1h, const short* __restrict__ W1l,
              const float* __restrict__ cb1,
              const short* __restrict__ W2h, const short* __restrict__ W2l,
              const float* __restrict__ cb2,
              float* __restrict__ out, int M) {
    constexpr int NT = 4, NTW = 2, NBK = 2, K = 128;
    constexpr int ASZ = 128 * 64, BSZ = 2 * NT * 16 * 64, BUF = ASZ + BSZ;
    __shared__ short lds[2 * BUF];                // 64 KB

    const int tid  = threadIdx.x;
    const int lane = tid & 63;
    const int wv   = tid >> 6;
    const int wm   = wv >> 1;
    const int wn   = wv & 1;
    const int bm   = blockIdx.x * 128;
    const int lrow = lane & 15;
    const int quad = lane >> 4;

    const int su = (tid & 7) ^ ((tid >> 3) & 7);
    const short* gsA[4];
    #pragma unroll
    for (int jj = 0; jj < 4; ++jj) {
        const int rg = min(bm + jj * 32 + (tid >> 3), M - 1);
        gsA[jj] = A1 + (size_t)rg * 128 + su * 8;
    }
    const short* gsB[NT];
    #pragma unroll
    for (int jj = 0; jj < NT; ++jj) {
        const int colIdx = jj * 32 + (tid >> 3);
        const bool ishi = colIdx < NT * 16;
        const int cp = ishi ? colIdx : colIdx - NT * 16;
        gsB[jj] = (ishi ? W1h : W1l) + (size_t)cp * K + su * 8;
    }
    auto stage = [&](int b, int c) {
        const int k = c * 64;
        #pragma unroll
        for (int jj = 0; jj < 4; ++jj)
            gload_lds16(gsA[jj] + k, &lds[b * BUF + (jj * 256 + tid) * 8]);
        #pragma unroll
        for (int jj = 0; jj < NT; ++jj)
            gload_lds16(gsB[jj] + k, &lds[b * BUF + ASZ + (jj * 256 + tid) * 8]);
    };

    int aoff[4][2], boff[NTW][2];
    #pragma unroll
    for (int m = 0; m < 4; ++m)
        #pragma unroll
        for (int kk = 0; kk < 2; ++kk)
            aoff[m][kk] = (wm * 64 + m * 16 + lrow) * 64 +
                          (((kk * 4 + quad) ^ (lrow & 7)) * 8);
    #pragma unroll
    for (int nt = 0; nt < NTW; ++nt)
        #pragma unroll
        for (int kk = 0; kk < 2; ++kk)
            boff[nt][kk] = (wn * NTW * 16 + nt * 16 + lrow) * 64 +
                           (((kk * 4 + quad) ^ (lrow & 7)) * 8);

    f32x4 acc[4][NTW];
    #pragma unroll
    for (int m = 0; m < 4; ++m)
        #pragma unroll
        for (int nt = 0; nt < NTW; ++nt)
            acc[m][nt] = (f32x4){0.f, 0.f, 0.f, 0.f};

    stage(0, 0);
    for (int c = 0; c < NBK; ++c) {
        const int b = c & 1;
        if (c + 1 < NBK) {
            stage(b ^ 1, c + 1);
            asm volatile("s_waitcnt vmcnt(8)" ::: "memory");
        } else {
            asm volatile("s_waitcnt vmcnt(0)" ::: "memory");
        }
        __builtin_amdgcn_s_barrier();
        const short* La = &lds[b * BUF];
        const short* Lb = &lds[b * BUF + ASZ];
        #pragma unroll
        for (int kk = 0; kk < 2; ++kk) {
            bf16x8 a[4];
            #pragma unroll
            for (int m = 0; m < 4; ++m)
                a[m] = *(const bf16x8*)(La + aoff[m][kk]);
            #pragma unroll
            for (int nt = 0; nt < NTW; ++nt) {
                const bf16x8 vbh = *(const bf16x8*)(Lb + boff[nt][kk]);
                const bf16x8 vbl = *(const bf16x8*)(Lb + boff[nt][kk] + NT * 16 * 64);
                #pragma unroll
                for (int m = 0; m < 4; ++m) {
                    acc[m][nt] = __builtin_amdgcn_mfma_f32_16x16x32_bf16(a[m], vbh, acc[m][nt], 0, 0, 0);
                    acc[m][nt] = __builtin_amdgcn_mfma_f32_16x16x32_bf16(a[m], vbl, acc[m][nt], 0, 0, 0);
                }
            }
        }
        asm volatile("" ::: "memory");
        __builtin_amdgcn_s_barrier();
    }

    // ---- phase-1 epilogue -> ep (relu(o1)) ----
    constexpr int EW = 68;                        // 64 + 4 pad
    float* ep = (float*)lds;                      // [128][68] = 34.8 KB
    #pragma unroll
    for (int nt = 0; nt < NTW; ++nt) {
        const int lcol = wn * NTW * 16 + nt * 16 + lrow;
        const float bsc = cb1[lcol];
        #pragma unroll
        for (int m = 0; m < 4; ++m)
            #pragma unroll
            for (int r = 0; r < 4; ++r)
                ep[(wm * 64 + m * 16 + quad * 4 + r) * EW + lcol] =
                    fmaxf(acc[m][nt][r] + bsc, 0.f);
    }
    __syncthreads();

    // ---- phase 2: o1 (ep) @ w2 ----
    const short* pB2h = W2h + (size_t)(wn * 16 + lrow) * 64 + quad * 8;
    const short* pB2l = W2l + (size_t)(wn * 16 + lrow) * 64 + quad * 8;
    f32x4 acc2[4];
    #pragma unroll
    for (int m = 0; m < 4; ++m) acc2[m] = (f32x4){0.f, 0.f, 0.f, 0.f};
    #pragma unroll
    for (int kk = 0; kk < 2; ++kk) {
        const bf16x8 bh = *(const bf16x8*)(pB2h + kk * 32);
        const bf16x8 bl = *(const bf16x8*)(pB2l + kk * 32);
        #pragma unroll
        for (int m = 0; m < 4; ++m) {
            const float* pe = ep + (wm * 64 + m * 16 + lrow) * EW + kk * 32 + quad * 8;
            const float4 e0 = *(const float4*)pe;
            const float4 e1 = *(const float4*)(pe + 4);
            bf16x8 a;
            a[0] = (short)f2bf(e0.x); a[1] = (short)f2bf(e0.y);
            a[2] = (short)f2bf(e0.z); a[3] = (short)f2bf(e0.w);
            a[4] = (short)f2bf(e1.x); a[5] = (short)f2bf(e1.y);
            a[6] = (short)f2bf(e1.z); a[7] = (short)f2bf(e1.w);
            acc2[m] = __builtin_amdgcn_mfma_f32_16x16x32_bf16(a, bh, acc2[m], 0, 0, 0);
            acc2[m] = __builtin_amdgcn_mfma_f32_16x16x32_bf16(a, bl, acc2[m], 0, 0, 0);
        }
    }

    // ---- phase-2 epilogue -> ep2 (disjoint from ep) -> coalesced stores ----
    constexpr int EW2 = 36;                       // 32 + 4 pad (16B-aligned)
    float* ep2 = (float*)lds + 128 * EW;          // 18.4 KB, total 53.2 < 64
    {
        const int lcol = wn * 16 + lrow;
        const float bsc = cb2[lcol];
        #pragma unroll
        for (int m = 0; m < 4; ++m)
            #pragma unroll
            for (int r = 0; r < 4; ++r)
                ep2[(wm * 64 + m * 16 + quad * 4 + r) * EW2 + lcol] =
                    acc2[m][r] + bsc;
    }
    __syncthreads();
    #pragma unroll
    for (int j = 0; j < 4; ++j) {
        const int g = tid + j * 256;              // 16B units, 8 per row
        const int row = g >> 3, u = g & 7;
        const int grow = bm + row;
        if (grow < M)
            *(float4*)(out + (size_t)grow * 32 + u * 4) =
                *(const float4*)(ep2 + row * EW2 + u * 4);
    }
}

// ---------------------------------------------------------------------------

extern "C" void kernel_launch(void* const* d_in, const int* in_sizes, int n_in,
                              void* d_out, int out_size, void* d_ws, size_t ws_size,
                              hipStream_t stream) {
    const float* sf    = (const float*)d_in[0];
    const float* mf    = (const float*)d_in[1];
    const int*   src   = (const int*)d_in[2];
    const int*   dst   = (const int*)d_in[3];
    const float* enc_w = (const float*)d_in[4];
    const float* enc_b = (const float*)d_in[5];
    const float* s0_ws = (const float*)d_in[6];
    const float* s0_wn = (const float*)d_in[7];
    const float* s0_b  = (const float*)d_in[8];
    const float* bn0_g = (const float*)d_in[9];
    const float* bn0_b = (const float*)d_in[10];
    const float* bn0_m = (const float*)d_in[11];
    const float* bn0_v = (const float*)d_in[12];
    const float* s1_ws = (const float*)d_in[13];
    const float* s1_wn = (const float*)d_in[14];
    const float* s1_b  = (const float*)d_in[15];
    const float* bn1_g = (const float*)d_in[16];
    const float* bn1_b = (const float*)d_in[17];
    const float* bn1_m = (const float*)d_in[18];
    const float* bn1_v = (const float*)d_in[19];
    const float* rel_w = (const float*)d_in[20];
    const float* rel_b = (const float*)d_in[21];
    const float* cw1   = (const float*)d_in[22];
    const float* cb1   = (const float*)d_in[23];
    const float* cw2   = (const float*)d_in[24];
    const float* cb2   = (const float*)d_in[25];
    float* out = (float*)d_out;

    const int nn = in_sizes[0] / 128;   // 100000
    const int ne = in_sizes[2];         // 800000
    const int nb = (nn + 1023) / 1024;  // scan blocks (98)

    // workspace layout. xb [nn,512] bf16 is dead after the enc GEMM, so the
    // later st (fp32 [nn,128]) + h1b (bf16 [nn,256]) alias its footprint.
    short* h0b   = (short*)d_ws;                       // [nn,128] bf16
    short* xb    = h0b + (size_t)nn * 128;             // [nn,512] bf16 (enc A)
    float* st    = (float*)xb;                         // s1 fp32 [nn,128]
    short* h1b   = (short*)(st + (size_t)nn * 128);    // [nn,256] bf16
    short* agg0b = xb + (size_t)nn * 512;              // [nn,128]
    short* t1b   = agg0b + (size_t)nn * 128;           // [nn,128]; reused as rb
    short* h2b   = t1b + (size_t)nn * 128;             // [nn,128]
    short* rb    = t1b;                                // [nn,128] (t1b dead)
    int* deg    = (int*)(h2b + (size_t)nn * 128);
    int* rowptr = deg + nn;
    int* cursor = rowptr + nn + 1;
    int* part   = cursor + nn;                         // [nb+1]
    int* eidx   = part + nb + 1;
    // bf16 weight planes (hi, lo) — transposed [N][K]
    short* wts = (short*)(eidx + ne);
    short* wt_enc_h = wts;                 short* wt_enc_l = wt_enc_h + 65536;   // [128][512]
    short* wt_s0_h  = wt_enc_l + 65536;    short* wt_s0_l  = wt_s0_h  + 65536;   // [256][256]
    short* wt_st_h  = wt_s0_l  + 65536;    short* wt_st_l  = wt_st_h  + 65536;   // [256][256]
    short* wt_rel_h = wt_st_l  + 65536;    short* wt_rel_l = wt_rel_h + 32768;   // [128][256]
    short* wt_c1_h  = wt_rel_l + 32768;    short* wt_c1_l  = wt_c1_h  + 8192;    // [64][128]
    short* wt_c2_h  = wt_c1_l  + 8192;     short* wt_c2_l  = wt_c2_h  + 2048;    // [32][64]

    const dim3 blk(256);
    const int gM = (nn + 127) / 128;    // 782 row-blocks

    // --- CSR build (parallel scan) ---
    hipMemsetAsync(deg, 0, (size_t)nn * 4, stream);
    count_deg <<<dim3((ne + 255) / 256), blk, 0, stream>>>(dst, deg, ne);
    scan_block<<<dim3(nb), dim3(1024), 0, stream>>>(deg, rowptr, part, nn);
    scan_part <<<dim3(1),  dim3(1024), 0, stream>>>(part, nb);
    scan_add  <<<dim3((nn + 255) / 256), blk, 0, stream>>>(part, rowptr, cursor, nn, nb);
    fill_edges<<<dim3((ne + 255) / 256), blk, 0, stream>>>(src, dst, cursor, eidx, ne);

    // --- weight prep (fused, 1 launch) ---
    prep_all<<<dim3(936), blk, 0, stream>>>(
        enc_w, s0_ws, s0_wn, s1_ws, s1_wn, rel_w, cw1, cw2,
        wt_enc_h, wt_enc_l, wt_s0_h, wt_s0_l, wt_st_h, wt_st_l,
        wt_rel_h, wt_rel_l, wt_c1_h, wt_c1_l, wt_c2_h, wt_c2_l);

    // --- xb = bf16(concat(sf, mf)) : LDS-staged streaming ---
    concat_bf16<<<dim3(2048), blk, 0, stream>>>(sf, mf, xb, nn);

    // --- h0 = relu(xb @ enc_w + enc_b) -> h0b bf16 ---
    gemm_dp<4, 512, 0><<<dim3(2, gM), blk, 0, stream>>>(
        xb, 512, nullptr, 0, wt_enc_h, wt_enc_l, enc_b,
        nullptr, nullptr, nullptr, nullptr, 1,
        nullptr, 0, 0, h0b, 0, 128, nn);

    // --- agg0 = mean_neigh(h0b) -> agg0b bf16 ---
    agg_mean_bb<<<dim3((nn + 3) / 4), blk, 0, stream>>>(
        h0b, rowptr, eidx, agg0b, nn);

    // --- h1 = relu(bn0(h0@ws0 + agg0@wn0 + b0)) -> h1b bf16 ---
    gemm_dp<4, 128, 128><<<dim3(4, gM), blk, 0, stream>>>(
        h0b, 128, agg0b, 128, wt_s0_h, wt_s0_l, s0_b,
        bn0_g, bn0_b, bn0_m, bn0_v, 1,
        nullptr, 0, 0, h1b, 0, 256, nn);

    // --- [s1 | t1] = h1 @ [ws1 | wn1]; s1 fp32 -> st, t1 bf16 -> t1b ---
    gemm_dp<4, 256, 0><<<dim3(4, gM), blk, 0, stream>>>(
        h1b, 256, nullptr, 0, wt_st_h, wt_st_l, nullptr,
        nullptr, nullptr, nullptr, nullptr, 0,
        st, 128, 128, t1b, 128, 128, nn);

    // --- h2 = relu(bn1(s1 + mean_neigh(t1) + b1)) -> h2b bf16 ---
    agg_combine_bb<<<dim3((nn + 3) / 4), blk, 0, stream>>>(
        t1b, rowptr, eidx, st, s1_b,
        bn1_g, bn1_b, bn1_m, bn1_v, h2b, nn);

    // --- r = relu(h0@rel_w[:128] + h2@rel_w[128:] + rel_b) -> rb bf16 ---
    gemm_dp<4, 128, 128><<<dim3(2, gM), blk, 0, stream>>>(
        h0b, 128, h2b, 128, wt_rel_h, wt_rel_l, rel_b,
        nullptr, nullptr, nullptr, nullptr, 1,
        nullptr, 0, 0, rb, 0, 128, nn);

    // --- out = relu(rb@w1+b1)@w2+b2 (fused classifier) ---
    gemm_cls<<<dim3(gM), blk, 0, stream>>>(
        rb, wt_c1_h, wt_c1_l, cb1, wt_c2_h, wt_c2_l, cb2, out, nn);
}

// Round 5
// 685.142 us; speedup vs baseline: 1.5815x; 1.0098x over previous
//
#include <hip/hip_runtime.h>
#include <math.h>

// ---------------------------------------------------------------------------
// MultiModalGraphSAGE — R11.
// R10 post-mortem: LDS-staged concat unchanged (96 us) — depth-1 prefetch +
// 2 barriers/iter leaves every iteration stalled on ~900cy HBM latency.
// R11: concat = register window (8 float4 loads) with a HARD scheduling
// fence (__builtin_amdgcn_sched_barrier(0)) between loads and converts so
// the compiler cannot re-serialize (R9's failure: VGPR=20 proved collapse;
// now VGPR>=48 is the verification signal). 128 B/lane in flight.
// Aggregations: 2-edge-deep ILP per 16-lane group with the same fence
// (2 independent gather chains/group instead of 1).
// ---------------------------------------------------------------------------

#define EPS 1e-5f

typedef __attribute__((ext_vector_type(8))) short bf16x8;
typedef __attribute__((ext_vector_type(4))) float f32x4;

__device__ inline unsigned short f2bf(float x) {
    unsigned u = __float_as_uint(x);
    u += 0x7fff + ((u >> 16) & 1);          // RNE to bf16
    return (unsigned short)(u >> 16);
}
__device__ inline float bf2f(unsigned short h) {
    return __uint_as_float(((unsigned)h) << 16);
}
__device__ inline unsigned packbf(float x, float y) {
    return (unsigned)f2bf(x) | ((unsigned)f2bf(y) << 16);
}

__device__ inline void gload_lds16(const void* g, void* l) {
    __builtin_amdgcn_global_load_lds(
        (__attribute__((address_space(1))) void*)g,
        (__attribute__((address_space(3))) void*)l, 16, 0, 0);
}

// ---------------- CSR build ----------------

__global__ void count_deg(const int* __restrict__ dst, int* __restrict__ deg, int e) {
    int i = blockIdx.x * 256 + threadIdx.x;
    if (i < e) atomicAdd(&deg[dst[i]], 1);
}

__global__ __launch_bounds__(1024)
void scan_block(const int* __restrict__ deg, int* __restrict__ rowptr,
                int* __restrict__ part, int n) {
    __shared__ int buf[1024];
    const int tid = threadIdx.x;
    const int i = blockIdx.x * 1024 + tid;
    const int v = (i < n) ? deg[i] : 0;
    buf[tid] = v;
    __syncthreads();
    #pragma unroll 1
    for (int off = 1; off < 1024; off <<= 1) {
        int t = (tid >= off) ? buf[tid - off] : 0;
        __syncthreads();
        buf[tid] += t;
        __syncthreads();
    }
    if (i < n) rowptr[i] = buf[tid] - v;          // local exclusive
    if (tid == 1023) part[blockIdx.x] = buf[1023];
}

__global__ __launch_bounds__(1024)
void scan_part(int* __restrict__ part, int nb) {
    __shared__ int buf[1024];
    const int tid = threadIdx.x;
    const int v = (tid < nb) ? part[tid] : 0;
    buf[tid] = v;
    __syncthreads();
    #pragma unroll 1
    for (int off = 1; off < 1024; off <<= 1) {
        int t = (tid >= off) ? buf[tid - off] : 0;
        __syncthreads();
        buf[tid] += t;
        __syncthreads();
    }
    if (tid < nb) part[tid] = buf[tid] - v;       // exclusive
    if (tid == 1023) part[nb] = buf[1023];        // grand total
}

__global__ void scan_add(const int* __restrict__ part, int* __restrict__ rowptr,
                         int* __restrict__ cursor, int n, int nb) {
    int i = blockIdx.x * 256 + threadIdx.x;
    if (i < n) {
        int v = rowptr[i] + part[i >> 10];
        rowptr[i] = v;
        cursor[i] = v;
    }
    if (i == 0) rowptr[n] = part[nb];
}

__global__ void fill_edges(const int* __restrict__ src, const int* __restrict__ dst,
                           int* __restrict__ cursor, int* __restrict__ eidx, int e) {
    int i = blockIdx.x * 256 + threadIdx.x;
    if (i < e) {
        int pos = atomicAdd(&cursor[dst[i]], 1);
        eidx[pos] = src[i];
    }
}

// ---------------- fused weight prep: all W[K][N] fp32 -> hi/lo [N][ldt] ----

__global__ __launch_bounds__(256)
void prep_all(const float* __restrict__ enc_w, const float* __restrict__ s0_ws,
              const float* __restrict__ s0_wn, const float* __restrict__ s1_ws,
              const float* __restrict__ s1_wn, const float* __restrict__ rel_w,
              const float* __restrict__ cw1, const float* __restrict__ cw2,
              short* wt_enc_h, short* wt_enc_l, short* wt_s0_h, short* wt_s0_l,
              short* wt_st_h, short* wt_st_l, short* wt_rel_h, short* wt_rel_l,
              short* wt_c1_h, short* wt_c1_l, short* wt_c2_h, short* wt_c2_l) {
    int e = blockIdx.x * 256 + threadIdx.x;
    const float* W; short* hi; short* lo; int Nd, ldt, koff;
    if (e < 65536)       { W = enc_w; hi = wt_enc_h; lo = wt_enc_l; Nd = 128; ldt = 512; koff = 0; }
    else if (e < 98304)  { e -= 65536;  W = s0_ws; hi = wt_s0_h; lo = wt_s0_l; Nd = 256; ldt = 256; koff = 0; }
    else if (e < 131072) { e -= 98304;  W = s0_wn; hi = wt_s0_h; lo = wt_s0_l; Nd = 256; ldt = 256; koff = 128; }
    else if (e < 163840) { e -= 131072; W = s1_ws; hi = wt_st_h; lo = wt_st_l; Nd = 128; ldt = 256; koff = 0; }
    else if (e < 196608) { e -= 163840; W = s1_wn; hi = wt_st_h + 32768; lo = wt_st_l + 32768; Nd = 128; ldt = 256; koff = 0; }
    else if (e < 229376) { e -= 196608; W = rel_w; hi = wt_rel_h; lo = wt_rel_l; Nd = 128; ldt = 256; koff = 0; }
    else if (e < 237568) { e -= 229376; W = cw1; hi = wt_c1_h; lo = wt_c1_l; Nd = 64; ldt = 128; koff = 0; }
    else if (e < 239616) { e -= 237568; W = cw2; hi = wt_c2_h; lo = wt_c2_l; Nd = 32; ldt = 64; koff = 0; }
    else return;
    const int k = e / Nd, n = e - k * Nd;
    const float x = W[e];
    const unsigned short h = f2bf(x);
    const unsigned short l = f2bf(x - bf2f(h));
    const size_t o = (size_t)n * ldt + koff + k;
    hi[o] = (short)h;
    lo[o] = (short)l;
}

// ---------------- concat(sf,mf) fp32 -> xb bf16 [nn,512] --------------------
// Register window: 4 units/thread at stride S, ALL 8 float4 loads issued
// before any convert, pinned by sched_barrier(0) so the compiler cannot
// re-serialize (R9 collapse: VGPR=20). 128 B/lane in flight.

__global__ __launch_bounds__(256)
void concat_bf16(const float* __restrict__ sf, const float* __restrict__ mf,
                 short* __restrict__ xb, int nn) {
    const int S = nn * 16;                        // 16B units per slice
    const int g = blockIdx.x * 256 + threadIdx.x;
    if (g >= S) return;
    const int q = g & 63;                         // S % 64 == 0 -> same all j
    const float* p[4];
    #pragma unroll
    for (int j = 0; j < 4; ++j) {
        const int n = (g + j * S) >> 6;
        p[j] = (q < 16) ? (sf + (size_t)n * 128 + (size_t)q * 8)
                        : (mf + (size_t)n * 384 + (size_t)(q - 16) * 8);
    }
    float4 f0[4], f1[4];
    #pragma unroll
    for (int j = 0; j < 4; ++j) {
        f0[j] = ((const float4*)p[j])[0];
        f1[j] = ((const float4*)p[j])[1];
    }
    __builtin_amdgcn_sched_barrier(0);            // all loads issue first
    #pragma unroll
    for (int j = 0; j < 4; ++j) {
        uint4 o;
        o.x = packbf(f0[j].x, f0[j].y); o.y = packbf(f0[j].z, f0[j].w);
        o.z = packbf(f1[j].x, f1[j].y); o.w = packbf(f1[j].z, f1[j].w);
        *(uint4*)(xb + (size_t)(g + j * S) * 8) = o;
    }
}

// ---------------- mean aggregation: 2-edge ILP per 16-lane group ------------
// wave = 4 groups x 16 lanes; group g handles edges beg+g, beg+g+4, ...
// Unrolled by 2: both eidx and both feature-row gathers issue before any
// accumulate (sched_barrier fence) -> 2 independent chains per group.

__global__ __launch_bounds__(256)
void agg_mean_bb(const short* __restrict__ featb,
                 const int* __restrict__ rowptr, const int* __restrict__ eidx,
                 short* __restrict__ outb, int n) {
    const int node = blockIdx.x * 4 + (threadIdx.x >> 6);
    if (node >= n) return;
    const int lane = threadIdx.x & 63;
    const int g = lane >> 4, j = lane & 15;
    const int beg = rowptr[node], end = rowptr[node + 1];
    float s[8];
    #pragma unroll
    for (int i = 0; i < 8; ++i) s[i] = 0.f;
    for (int e = beg + g; e < end; e += 8) {
        const int e1 = e + 4;
        const bool has2 = e1 < end;
        const int i0 = eidx[e];
        const int i1 = has2 ? eidx[e1] : i0;
        const uint4 v0 = *(const uint4*)(featb + (size_t)i0 * 128 + j * 8);
        const uint4 v1 = *(const uint4*)(featb + (size_t)i1 * 128 + j * 8);
        __builtin_amdgcn_sched_barrier(0);
        s[0] += __uint_as_float(v0.x << 16); s[1] += __uint_as_float(v0.x & 0xffff0000u);
        s[2] += __uint_as_float(v0.y << 16); s[3] += __uint_as_float(v0.y & 0xffff0000u);
        s[4] += __uint_as_float(v0.z << 16); s[5] += __uint_as_float(v0.z & 0xffff0000u);
        s[6] += __uint_as_float(v0.w << 16); s[7] += __uint_as_float(v0.w & 0xffff0000u);
        if (has2) {
            s[0] += __uint_as_float(v1.x << 16); s[1] += __uint_as_float(v1.x & 0xffff0000u);
            s[2] += __uint_as_float(v1.y << 16); s[3] += __uint_as_float(v1.y & 0xffff0000u);
            s[4] += __uint_as_float(v1.z << 16); s[5] += __uint_as_float(v1.z & 0xffff0000u);
            s[6] += __uint_as_float(v1.w << 16); s[7] += __uint_as_float(v1.w & 0xffff0000u);
        }
    }
    #pragma unroll
    for (int i = 0; i < 8; ++i) {
        s[i] += __shfl_xor(s[i], 32);
        s[i] += __shfl_xor(s[i], 16);
    }
    if (g == 0) {
        const float inv = 1.0f / fmaxf((float)(end - beg), 1.0f);
        uint4 o;
        o.x = packbf(s[0] * inv, s[1] * inv);
        o.y = packbf(s[2] * inv, s[3] * inv);
        o.z = packbf(s[4] * inv, s[5] * inv);
        o.w = packbf(s[6] * inv, s[7] * inv);
        *(uint4*)(outb + (size_t)node * 128 + j * 8) = o;
    }
}

// sage1 combine: h2 = relu(bn1(s1 + mean_neigh(t1) + b1)), bf16 out
__global__ __launch_bounds__(256)
void agg_combine_bb(const short* __restrict__ featb,
                    const int* __restrict__ rowptr, const int* __restrict__ eidx,
                    const float* __restrict__ s1,          // [n,128] fp32
                    const float* __restrict__ bias,
                    const float* __restrict__ bng, const float* __restrict__ bnb,
                    const float* __restrict__ bnm, const float* __restrict__ bnv,
                    short* __restrict__ outb, int n) {
    const int node = blockIdx.x * 4 + (threadIdx.x >> 6);
    if (node >= n) return;
    const int lane = threadIdx.x & 63;
    const int g = lane >> 4, j = lane & 15;
    const int beg = rowptr[node], end = rowptr[node + 1];
    float s[8];
    #pragma unroll
    for (int i = 0; i < 8; ++i) s[i] = 0.f;
    for (int e = beg + g; e < end; e += 8) {
        const int e1 = e + 4;
        const bool has2 = e1 < end;
        const int i0 = eidx[e];
        const int i1 = has2 ? eidx[e1] : i0;
        const uint4 v0 = *(const uint4*)(featb + (size_t)i0 * 128 + j * 8);
        const uint4 v1 = *(const uint4*)(featb + (size_t)i1 * 128 + j * 8);
        __builtin_amdgcn_sched_barrier(0);
        s[0] += __uint_as_float(v0.x << 16); s[1] += __uint_as_float(v0.x & 0xffff0000u);
        s[2] += __uint_as_float(v0.y << 16); s[3] += __uint_as_float(v0.y & 0xffff0000u);
        s[4] += __uint_as_float(v0.z << 16); s[5] += __uint_as_float(v0.z & 0xffff0000u);
        s[6] += __uint_as_float(v0.w << 16); s[7] += __uint_as_float(v0.w & 0xffff0000u);
        if (has2) {
            s[0] += __uint_as_float(v1.x << 16); s[1] += __uint_as_float(v1.x & 0xffff0000u);
            s[2] += __uint_as_float(v1.y << 16); s[3] += __uint_as_float(v1.y & 0xffff0000u);
            s[4] += __uint_as_float(v1.z << 16); s[5] += __uint_as_float(v1.z & 0xffff0000u);
            s[6] += __uint_as_float(v1.w << 16); s[7] += __uint_as_float(v1.w & 0xffff0000u);
        }
    }
    #pragma unroll
    for (int i = 0; i < 8; ++i) {
        s[i] += __shfl_xor(s[i], 32);
        s[i] += __shfl_xor(s[i], 16);
    }
    if (g == 0) {
        const float inv = 1.0f / fmaxf((float)(end - beg), 1.0f);
        const int c0 = j * 8;
        const float4 a0 = *(const float4*)(s1 + (size_t)node * 128 + c0);
        const float4 a1 = *(const float4*)(s1 + (size_t)node * 128 + c0 + 4);
        const float sf[8] = {a0.x, a0.y, a0.z, a0.w, a1.x, a1.y, a1.z, a1.w};
        float r[8];
        #pragma unroll
        for (int i = 0; i < 8; ++i) {
            const int c = c0 + i;
            float v = sf[i] + s[i] * inv + bias[c];
            v = (v - bnm[c]) * (bng[c] / sqrtf(bnv[c] + EPS)) + bnb[c];
            r[i] = fmaxf(v, 0.f);
        }
        uint4 o;
        o.x = packbf(r[0], r[1]); o.y = packbf(r[2], r[3]);
        o.z = packbf(r[4], r[5]); o.w = packbf(r[6], r[7]);
        *(uint4*)(outb + (size_t)node * 128 + j * 8) = o;
    }
}

// ---------------- all-LDS MFMA GEMM: bf16 A, split-bf16 W ------------------
// Block: 256 thr = 4 waves arranged 2m x 2n (wave = 64 rows x NT/2*16 cols).
// Tile 128 rows x NT*16 cols, BK=64, double-buffered. A+B staged by
// gload_lds16 (source pre-XOR-swizzled on 16B units, linear LDS, swizzled
// ds_read). K-loop: stage(c+1) -> vmcnt(4+NT) -> s_barrier -> ds_read+MFMA
// -> s_barrier. Epilogue: acc -> LDS fp32 -> coalesced float4/uint4 stores.
template<int NT, int K1, int K2>
__global__ __launch_bounds__(256)
void gemm_dp(const short* __restrict__ A1, int lda1,
             const short* __restrict__ A2, int lda2,
             const short* __restrict__ Wt_hi, const short* __restrict__ Wt_lo,
             const float* __restrict__ bias,
             const float* __restrict__ bng, const float* __restrict__ bnb,
             const float* __restrict__ bnm, const float* __restrict__ bnv,
             int relu,
             float* __restrict__ Cf, int fpN, int ldc,
             short* __restrict__ Cb, int bfcol0, int ldcb,
             int M) {
    constexpr int K   = K1 + K2;
    constexpr int NBK = K / 64;
    constexpr int NTW = NT / 2;
    static_assert(K % 64 == 0, "K multiple of 64");
    static_assert(NT % 2 == 0, "NT even");
    static_assert(K2 == 0 || K1 % 64 == 0, "concat boundary on BK");
    constexpr int ASZ = 128 * 64;                 // shorts (16KB)
    constexpr int BSZ = 2 * NT * 16 * 64;         // shorts (hi+lo planes)
    constexpr int BUF = ASZ + BSZ;
    __shared__ short lds[2 * BUF];

    const int tid  = threadIdx.x;
    const int lane = tid & 63;
    const int wv   = tid >> 6;
    const int wm   = wv >> 1;                     // 0..1 (row half)
    const int wn   = wv & 1;                      // 0..1 (col half)
    const int bm   = blockIdx.y * 128;
    const int col0 = blockIdx.x * (NT * 16);
    const int lrow = lane & 15;
    const int quad = lane >> 4;

    // ---- staging sources: phys (row,u) holds global unit u^(row&7) ----
    const int su = (tid & 7) ^ ((tid >> 3) & 7);
    const short* gsA1[4];
    const short* gsA2[4];
    #pragma unroll
    for (int jj = 0; jj < 4; ++jj) {
        const int rg = min(bm + jj * 32 + (tid >> 3), M - 1);
        gsA1[jj] = A1 + (size_t)rg * lda1 + su * 8;
        if constexpr (K2 > 0) gsA2[jj] = A2 + (size_t)rg * lda2 + su * 8;
        else gsA2[jj] = nullptr;
    }
    const short* gsB[NT];                         // B "rows": hi cols, then lo
    #pragma unroll
    for (int jj = 0; jj < NT; ++jj) {
        const int colIdx = jj * 32 + (tid >> 3);  // 0..2*NT*16-1
        const bool ishi = colIdx < NT * 16;
        const int cp = ishi ? colIdx : colIdx - NT * 16;
        gsB[jj] = (ishi ? Wt_hi : Wt_lo) + (size_t)(col0 + cp) * K + su * 8;
    }

    auto stage = [&](int b, int c) {
        const int k = c * 64;
        #pragma unroll
        for (int jj = 0; jj < 4; ++jj) {
            const short* p;
            if constexpr (K2 > 0)
                p = (k < K1) ? (gsA1[jj] + k) : (gsA2[jj] + (k - K1));
            else
                p = gsA1[jj] + k;
            gload_lds16(p, &lds[b * BUF + (jj * 256 + tid) * 8]);
        }
        #pragma unroll
        for (int jj = 0; jj < NT; ++jj)
            gload_lds16(gsB[jj] + k, &lds[b * BUF + ASZ + (jj * 256 + tid) * 8]);
    };

    // ---- swizzled LDS read offsets (shorts) ----
    int aoff[4][2];
    #pragma unroll
    for (int m = 0; m < 4; ++m)
        #pragma unroll
        for (int kk = 0; kk < 2; ++kk)
            aoff[m][kk] = (wm * 64 + m * 16 + lrow) * 64 +
                          (((kk * 4 + quad) ^ (lrow & 7)) * 8);
    int boff[NTW][2];
    #pragma unroll
    for (int nt = 0; nt < NTW; ++nt)
        #pragma unroll
        for (int kk = 0; kk < 2; ++kk)
            boff[nt][kk] = (wn * NTW * 16 + nt * 16 + lrow) * 64 +
                           (((kk * 4 + quad) ^ (lrow & 7)) * 8);

    f32x4 acc[4][NTW];
    #pragma unroll
    for (int m = 0; m < 4; ++m)
        #pragma unroll
        for (int nt = 0; nt < NTW; ++nt)
            acc[m][nt] = (f32x4){0.f, 0.f, 0.f, 0.f};

    stage(0, 0);

    for (int c = 0; c < NBK; ++c) {
        const int b = c & 1;
        if (c + 1 < NBK) {
            stage(b ^ 1, c + 1);
            // keep stage(c+1)'s 4+NT loads in flight; drain stage(c)
            if constexpr (NT == 4) asm volatile("s_waitcnt vmcnt(8)" ::: "memory");
            else                   asm volatile("s_waitcnt vmcnt(6)" ::: "memory");
        } else {
            asm volatile("s_waitcnt vmcnt(0)" ::: "memory");
        }
        __builtin_amdgcn_s_barrier();             // buf b fully staged

        const short* La = &lds[b * BUF];
        const short* Lb = &lds[b * BUF + ASZ];
        #pragma unroll
        for (int kk = 0; kk < 2; ++kk) {
            bf16x8 a[4];
            #pragma unroll
            for (int m = 0; m < 4; ++m)
                a[m] = *(const bf16x8*)(La + aoff[m][kk]);
            #pragma unroll
            for (int nt = 0; nt < NTW; ++nt) {
                const bf16x8 vbh = *(const bf16x8*)(Lb + boff[nt][kk]);
                const bf16x8 vbl = *(const bf16x8*)(Lb + boff[nt][kk] + NT * 16 * 64);
                #pragma unroll
                for (int m = 0; m < 4; ++m) {
                    acc[m][nt] = __builtin_amdgcn_mfma_f32_16x16x32_bf16(a[m], vbh, acc[m][nt], 0, 0, 0);
                    acc[m][nt] = __builtin_amdgcn_mfma_f32_16x16x32_bf16(a[m], vbl, acc[m][nt], 0, 0, 0);
                }
            }
        }
        asm volatile("" ::: "memory");
        __builtin_amdgcn_s_barrier();             // all waves done with buf b
    }

    // ---- epilogue via LDS: coalesced stores ----
    constexpr int EW = NT * 16 + 4;               // fp32 row stride (16B-aligned)
    float* ep = (float*)lds;

    #pragma unroll
    for (int nt = 0; nt < NTW; ++nt) {
        const int lcol = wn * NTW * 16 + nt * 16 + lrow;
        const int gcol = col0 + lcol;
        const float bsc = bias ? bias[gcol] : 0.f;
        float gg = 1.f, bb = 0.f, mm = 0.f;
        if (bng) { gg = bng[gcol] / sqrtf(bnv[gcol] + EPS); bb = bnb[gcol]; mm = bnm[gcol]; }
        #pragma unroll
        for (int m = 0; m < 4; ++m) {
            #pragma unroll
            for (int r = 0; r < 4; ++r) {
                float x = acc[m][nt][r] + bsc;
                if (bng) x = (x - mm) * gg + bb;
                if (relu) x = fmaxf(x, 0.f);
                ep[(wm * 64 + m * 16 + quad * 4 + r) * EW + lcol] = x;
            }
        }
    }
    __syncthreads();

    if (col0 < fpN) {                             // fp32-target block
        for (int g = tid; g < 128 * NT * 4; g += 256) {
            const int row = g / (NT * 4), u = g - row * (NT * 4);
            const int grow = bm + row;
            if (grow < M)
                *(float4*)(Cf + (size_t)grow * ldc + col0 + u * 4) =
                    *(const float4*)(ep + row * EW + u * 4);
        }
    } else {                                      // bf16-target block
        for (int g = tid; g < 128 * NT * 2; g += 256) {
            const int row = g / (NT * 2), u = g - row * (NT * 2);
            const int grow = bm + row;
            const float4 f0 = *(const float4*)(ep + row * EW + u * 8);
            const float4 f1 = *(const float4*)(ep + row * EW + u * 8 + 4);
            uint4 o;
            o.x = packbf(f0.x, f0.y); o.y = packbf(f0.z, f0.w);
            o.z = packbf(f1.x, f1.y); o.w = packbf(f1.z, f1.w);
            if (grow < M)
                *(uint4*)(Cb + (size_t)grow * ldcb + (col0 - bfcol0) + u * 8) = o;
        }
    }
}

// ---------------- fused classifier: out = relu(rb@w1+b1)@w2+b2 -------------
__global__ __launch_bounds__(256)
void gemm_cls(const short* __restrict__ A1,            // rb [M,128]
              const short* __restrict__ W1h, const short* __restrict__ W1l,
              const float* __restrict__ cb1,
              const short* __restrict__ W2h, const short* __restrict__ W2l,
              const float* __restrict__ cb2,
              float* __restrict__ out, int M) {
    constexpr int NT = 4, NTW = 2, NBK = 2, K = 128;
    constexpr int ASZ = 128 * 64, BSZ = 2 * NT * 16 * 64, BUF = ASZ + BSZ;
    __shared__ short lds[2 * BUF];                // 64 KB

    const int tid  = threadIdx.x;
    const int lane = tid & 63;
    const int wv   = tid >> 6;
    const int wm   = wv >> 1;
    const int wn   = wv & 1;
    const int bm   = blockIdx.x * 128;
    const int lrow = lane & 15;
    const int quad = lane >> 4;

    const int su = (tid & 7) ^ ((tid >> 3) & 7);
    const short* gsA[4];
    #pragma unroll
    for (int jj = 0; jj < 4; ++jj) {
        const int rg = min(bm + jj * 32 + (tid >> 3), M - 1);
        gsA[jj] = A1 + (size_t)rg * 128 + su * 8;
    }
    const short* gsB[NT];
    #pragma unroll
    for (int jj = 0; jj < NT; ++jj) {
        const int colIdx = jj * 32 + (tid >> 3);
        const bool ishi = colIdx < NT * 16;
        const int cp = ishi ? colIdx : colIdx - NT * 16;
        gsB[jj] = (ishi ? W1h : W1l) + (size_t)cp * K + su * 8;
    }
    auto stage = [&](int b, int c) {
        const int k = c * 64;
        #pragma unroll
        for (int jj = 0; jj < 4; ++jj)
            gload_lds16(gsA[jj] + k, &lds[b * BUF + (jj * 256 + tid) * 8]);
        #pragma unroll
        for (int jj = 0; jj < NT; ++jj)
            gload_lds16(gsB[jj] + k, &lds[b * BUF + ASZ + (jj * 256 + tid) * 8]);
    };

    int aoff[4][2], boff[NTW][2];
    #pragma unroll
    for (int m = 0; m < 4; ++m)
        #pragma unroll
        for (int kk = 0; kk < 2; ++kk)
            aoff[m][kk] = (wm * 64 + m * 16 + lrow) * 64 +
                          (((kk * 4 + quad) ^ (lrow & 7)) * 8);
    #pragma unroll
    for (int nt = 0; nt < NTW; ++nt)
        #pragma unroll
        for (int kk = 0; kk < 2; ++kk)
            boff[nt][kk] = (wn * NTW * 16 + nt * 16 + lrow) * 64 +
                           (((kk * 4 + quad) ^ (lrow & 7)) * 8);

    f32x4 acc[4][NTW];
    #pragma unroll
    for (int m = 0; m < 4; ++m)
        #pragma unroll
        for (int nt = 0; nt < NTW; ++nt)
            acc[m][nt] = (f32x4){0.f, 0.f, 0.f, 0.f};

    stage(0, 0);
    for (int c = 0; c < NBK; ++c) {
        const int b = c & 1;
        if (c + 1 < NBK) {
            stage(b ^ 1, c + 1);
            asm volatile("s_waitcnt vmcnt(8)" ::: "memory");
        } else {
            asm volatile("s_waitcnt vmcnt(0)" ::: "memory");
        }
        __builtin_amdgcn_s_barrier();
        const short* La = &lds[b * BUF];
        const short* Lb = &lds[b * BUF + ASZ];
        #pragma unroll
        for (int kk = 0; kk < 2; ++kk) {
            bf16x8 a[4];
            #pragma unroll
            for (int m = 0; m < 4; ++m)
                a[m] = *(const bf16x8*)(La + aoff[m][kk]);
            #pragma unroll
            for (int nt = 0; nt < NTW; ++nt) {
                const bf16x8 vbh = *(const bf16x8*)(Lb + boff[nt][kk]);
                const bf16x8 vbl = *(const bf16x8*)(Lb + boff[nt][kk] + NT * 16 * 64);
                #pragma unroll
                for (int m = 0; m < 4; ++m) {
                    acc[m][nt] = __builtin_amdgcn_mfma_f32_16x16x32_bf16(a[m], vbh, acc[m][nt], 0, 0, 0);
                    acc[m][nt] = __builtin_amdgcn_mfma_f32_16x16x32_bf16(a[m], vbl, acc[m][nt], 0, 0, 0);
                }
            }
        }
        asm volatile("" ::: "memory");
        __builtin_amdgcn_s_barrier();
    }

    // ---- phase-1 epilogue -> ep (relu(o1)) ----
    constexpr int EW = 68;                        // 64 + 4 pad
    float* ep = (float*)lds;                      // [128][68] = 34.8 KB
    #pragma unroll
    for (int nt = 0; nt < NTW; ++nt) {
        const int lcol = wn * NTW * 16 + nt * 16 + lrow;
        const float bsc = cb1[lcol];
        #pragma unroll
        for (int m = 0; m < 4; ++m)
            #pragma unroll
            for (int r = 0; r < 4; ++r)
                ep[(wm * 64 + m * 16 + quad * 4 + r) * EW + lcol] =
                    fmaxf(acc[m][nt][r] + bsc, 0.f);
    }
    __syncthreads();

    // ---- phase 2: o1 (ep) @ w2 ----
    const short* pB2h = W2h + (size_t)(wn * 16 + lrow) * 64 + quad * 8;
    const short* pB2l = W2l + (size_t)(wn * 16 + lrow) * 64 + quad * 8;
    f32x4 acc2[4];
    #pragma unroll
    for (int m = 0; m < 4; ++m) acc2[m] = (f32x4){0.f, 0.f, 0.f, 0.f};
    #pragma unroll
    for (int kk = 0; kk < 2; ++kk) {
        const bf16x8 bh = *(const bf16x8*)(pB2h + kk * 32);
        const bf16x8 bl = *(const bf16x8*)(pB2l + kk * 32);
        #pragma unroll
        for (int m = 0; m < 4; ++m) {
            const float* pe = ep + (wm * 64 + m * 16 + lrow) * EW + kk * 32 + quad * 8;
            const float4 e0 = *(const float4*)pe;
            const float4 e1 = *(const float4*)(pe + 4);
            bf16x8 a;
            a[0] = (short)f2bf(e0.x); a[1] = (short)f2bf(e0.y);
            a[2] = (short)f2bf(e0.z); a[3] = (short)f2bf(e0.w);
            a[4] = (short)f2bf(e1.x); a[5] = (short)f2bf(e1.y);
            a[6] = (short)f2bf(e1.z); a[7] = (short)f2bf(e1.w);
            acc2[m] = __builtin_amdgcn_mfma_f32_16x16x32_bf16(a, bh, acc2[m], 0, 0, 0);
            acc2[m] = __builtin_amdgcn_mfma_f32_16x16x32_bf16(a, bl, acc2[m], 0, 0, 0);
        }
    }

    // ---- phase-2 epilogue -> ep2 (disjoint from ep) -> coalesced stores ----
    constexpr int EW2 = 36;                       // 32 + 4 pad (16B-aligned)
    float* ep2 = (float*)lds + 128 * EW;          // 18.4 KB, total 53.2 < 64
    {
        const int lcol = wn * 16 + lrow;
        const float bsc = cb2[lcol];
        #pragma unroll
        for (int m = 0; m < 4; ++m)
            #pragma unroll
            for (int r = 0; r < 4; ++r)
                ep2[(wm * 64 + m * 16 + quad * 4 + r) * EW2 + lcol] =
                    acc2[m][r] + bsc;
    }
    __syncthreads();
    #pragma unroll
    for (int j = 0; j < 4; ++j) {
        const int g = tid + j * 256;              // 16B units, 8 per row
        const int row = g >> 3, u = g & 7;
        const int grow = bm + row;
        if (grow < M)
            *(float4*)(out + (size_t)grow * 32 + u * 4) =
                *(const float4*)(ep2 + row * EW2 + u * 4);
    }
}

// ---------------------------------------------------------------------------

extern "C" void kernel_launch(void* const* d_in, const int* in_sizes, int n_in,
                              void* d_out, int out_size, void* d_ws, size_t ws_size,
                              hipStream_t stream) {
    const float* sf    = (const float*)d_in[0];
    const float* mf    = (const float*)d_in[1];
    const int*   src   = (const int*)d_in[2];
    const int*   dst   = (const int*)d_in[3];
    const float* enc_w = (const float*)d_in[4];
    const float* enc_b = (const float*)d_in[5];
    const float* s0_ws = (const float*)d_in[6];
    const float* s0_wn = (const float*)d_in[7];
    const float* s0_b  = (const float*)d_in[8];
    const float* bn0_g = (const float*)d_in[9];
    const float* bn0_b = (const float*)d_in[10];
    const float* bn0_m = (const float*)d_in[11];
    const float* bn0_v = (const float*)d_in[12];
    const float* s1_ws = (const float*)d_in[13];
    const float* s1_wn = (const float*)d_in[14];
    const float* s1_b  = (const float*)d_in[15];
    const float* bn1_g = (const float*)d_in[16];
    const float* bn1_b = (const float*)d_in[17];
    const float* bn1_m = (const float*)d_in[18];
    const float* bn1_v = (const float*)d_in[19];
    const float* rel_w = (const float*)d_in[20];
    const float* rel_b = (const float*)d_in[21];
    const float* cw1   = (const float*)d_in[22];
    const float* cb1   = (const float*)d_in[23];
    const float* cw2   = (const float*)d_in[24];
    const float* cb2   = (const float*)d_in[25];
    float* out = (float*)d_out;

    const int nn = in_sizes[0] / 128;   // 100000
    const int ne = in_sizes[2];         // 800000
    const int nb = (nn + 1023) / 1024;  // scan blocks (98)

    // workspace layout. xb [nn,512] bf16 is dead after the enc GEMM, so the
    // later st (fp32 [nn,128]) + h1b (bf16 [nn,256]) alias its footprint.
    short* h0b   = (short*)d_ws;                       // [nn,128] bf16
    short* xb    = h0b + (size_t)nn * 128;             // [nn,512] bf16 (enc A)
    float* st    = (float*)xb;                         // s1 fp32 [nn,128]
    short* h1b   = (short*)(st + (size_t)nn * 128);    // [nn,256] bf16
    short* agg0b = xb + (size_t)nn * 512;              // [nn,128]
    short* t1b   = agg0b + (size_t)nn * 128;           // [nn,128]; reused as rb
    short* h2b   = t1b + (size_t)nn * 128;             // [nn,128]
    short* rb    = t1b;                                // [nn,128] (t1b dead)
    int* deg    = (int*)(h2b + (size_t)nn * 128);
    int* rowptr = deg + nn;
    int* cursor = rowptr + nn + 1;
    int* part   = cursor + nn;                         // [nb+1]
    int* eidx   = part + nb + 1;
    // bf16 weight planes (hi, lo) — transposed [N][K]
    short* wts = (short*)(eidx + ne);
    short* wt_enc_h = wts;                 short* wt_enc_l = wt_enc_h + 65536;   // [128][512]
    short* wt_s0_h  = wt_enc_l + 65536;    short* wt_s0_l  = wt_s0_h  + 65536;   // [256][256]
    short* wt_st_h  = wt_s0_l  + 65536;    short* wt_st_l  = wt_st_h  + 65536;   // [256][256]
    short* wt_rel_h = wt_st_l  + 65536;    short* wt_rel_l = wt_rel_h + 32768;   // [128][256]
    short* wt_c1_h  = wt_rel_l + 32768;    short* wt_c1_l  = wt_c1_h  + 8192;    // [64][128]
    short* wt_c2_h  = wt_c1_l  + 8192;     short* wt_c2_l  = wt_c2_h  + 2048;    // [32][64]

    const dim3 blk(256);
    const int gM = (nn + 127) / 128;    // 782 row-blocks

    // --- CSR build (parallel scan) ---
    hipMemsetAsync(deg, 0, (size_t)nn * 4, stream);
    count_deg <<<dim3((ne + 255) / 256), blk, 0, stream>>>(dst, deg, ne);
    scan_block<<<dim3(nb), dim3(1024), 0, stream>>>(deg, rowptr, part, nn);
    scan_part <<<dim3(1),  dim3(1024), 0, stream>>>(part, nb);
    scan_add  <<<dim3((nn + 255) / 256), blk, 0, stream>>>(part, rowptr, cursor, nn, nb);
    fill_edges<<<dim3((ne + 255) / 256), blk, 0, stream>>>(src, dst, cursor, eidx, ne);

    // --- weight prep (fused, 1 launch) ---
    prep_all<<<dim3(936), blk, 0, stream>>>(
        enc_w, s0_ws, s0_wn, s1_ws, s1_wn, rel_w, cw1, cw2,
        wt_enc_h, wt_enc_l, wt_s0_h, wt_s0_l, wt_st_h, wt_st_l,
        wt_rel_h, wt_rel_l, wt_c1_h, wt_c1_l, wt_c2_h, wt_c2_l);

    // --- xb = bf16(concat(sf, mf)) : register-window + sched fence ---
    concat_bf16<<<dim3((nn * 16 + 255) / 256), blk, 0, stream>>>(sf, mf, xb, nn);

    // --- h0 = relu(xb @ enc_w + enc_b) -> h0b bf16 ---
    gemm_dp<4, 512, 0><<<dim3(2, gM), blk, 0, stream>>>(
        xb, 512, nullptr, 0, wt_enc_h, wt_enc_l, enc_b,
        nullptr, nullptr, nullptr, nullptr, 1,
        nullptr, 0, 0, h0b, 0, 128, nn);

    // --- agg0 = mean_neigh(h0b) -> agg0b bf16 ---
    agg_mean_bb<<<dim3((nn + 3) / 4), blk, 0, stream>>>(
        h0b, rowptr, eidx, agg0b, nn);

    // --- h1 = relu(bn0(h0@ws0 + agg0@wn0 + b0)) -> h1b bf16 ---
    gemm_dp<4, 128, 128><<<dim3(4, gM), blk, 0, stream>>>(
        h0b, 128, agg0b, 128, wt_s0_h, wt_s0_l, s0_b,
        bn0_g, bn0_b, bn0_m, bn0_v, 1,
        nullptr, 0, 0, h1b, 0, 256, nn);

    // --- [s1 | t1] = h1 @ [ws1 | wn1]; s1 fp32 -> st, t1 bf16 -> t1b ---
    gemm_dp<4, 256, 0><<<dim3(4, gM), blk, 0, stream>>>(
        h1b, 256, nullptr, 0, wt_st_h, wt_st_l, nullptr,
        nullptr, nullptr, nullptr, nullptr, 0,
        st, 128, 128, t1b, 128, 128, nn);

    // --- h2 = relu(bn1(s1 + mean_neigh(t1) + b1)) -> h2b bf16 ---
    agg_combine_bb<<<dim3((nn + 3) / 4), blk, 0, stream>>>(
        t1b, rowptr, eidx, st, s1_b,
        bn1_g, bn1_b, bn1_m, bn1_v, h2b, nn);

    // --- r = relu(h0@rel_w[:128] + h2@rel_w[128:] + rel_b) -> rb bf16 ---
    gemm_dp<4, 128, 128><<<dim3(2, gM), blk, 0, stream>>>(
        h0b, 128, h2b, 128, wt_rel_h, wt_rel_l, rel_b,
        nullptr, nullptr, nullptr, nullptr, 1,
        nullptr, 0, 0, rb, 0, 128, nn);

    // --- out = relu(rb@w1+b1)@w2+b2 (fused classifier) ---
    gemm_cls<<<dim3(gM), blk, 0, stream>>>(
        rb, wt_c1_h, wt_c1_l, cb1, wt_c2_h, wt_c2_l, cb2, out, nn);
}

// Round 6
// 661.266 us; speedup vs baseline: 1.6386x; 1.0361x over previous
//
#include <hip/hip_runtime.h>
#include <math.h>

// ---------------------------------------------------------------------------
// MultiModalGraphSAGE — R12.
// R11 post-mortem: concat stuck at ~96us across FOUR structurally different
// implementations (incl. forced 32-VGPR window, VGPR counter confirmed) —
// not latency-bound; externally limited ~3.2 TB/s for the r/convert/w mix.
// R12: DELETE the concat pass. The enc GEMM reads sf/mf fp32 directly and
// converts during staging (T14 issue-early/write-late): top of K-step c
// issues 8 float4 A(c+1) reg-loads + gload_lds B(c+1); compute(c) hides the
// latency; then f2bf convert + ds_write_b128 into the same bf16 LDS layout,
// vmcnt(0) for B, one barrier/step. Saves 200 MB of xb traffic + a kernel.
// Numerics bit-identical (same RNE f2bf). Everything else unchanged.
// ---------------------------------------------------------------------------

#define EPS 1e-5f

typedef __attribute__((ext_vector_type(8))) short bf16x8;
typedef __attribute__((ext_vector_type(4))) float f32x4;

__device__ inline unsigned short f2bf(float x) {
    unsigned u = __float_as_uint(x);
    u += 0x7fff + ((u >> 16) & 1);          // RNE to bf16
    return (unsigned short)(u >> 16);
}
__device__ inline float bf2f(unsigned short h) {
    return __uint_as_float(((unsigned)h) << 16);
}
__device__ inline unsigned packbf(float x, float y) {
    return (unsigned)f2bf(x) | ((unsigned)f2bf(y) << 16);
}

__device__ inline void gload_lds16(const void* g, void* l) {
    __builtin_amdgcn_global_load_lds(
        (__attribute__((address_space(1))) void*)g,
        (__attribute__((address_space(3))) void*)l, 16, 0, 0);
}

// ---------------- CSR build ----------------

__global__ void count_deg(const int* __restrict__ dst, int* __restrict__ deg, int e) {
    int i = blockIdx.x * 256 + threadIdx.x;
    if (i < e) atomicAdd(&deg[dst[i]], 1);
}

__global__ __launch_bounds__(1024)
void scan_block(const int* __restrict__ deg, int* __restrict__ rowptr,
                int* __restrict__ part, int n) {
    __shared__ int buf[1024];
    const int tid = threadIdx.x;
    const int i = blockIdx.x * 1024 + tid;
    const int v = (i < n) ? deg[i] : 0;
    buf[tid] = v;
    __syncthreads();
    #pragma unroll 1
    for (int off = 1; off < 1024; off <<= 1) {
        int t = (tid >= off) ? buf[tid - off] : 0;
        __syncthreads();
        buf[tid] += t;
        __syncthreads();
    }
    if (i < n) rowptr[i] = buf[tid] - v;          // local exclusive
    if (tid == 1023) part[blockIdx.x] = buf[1023];
}

__global__ __launch_bounds__(1024)
void scan_part(int* __restrict__ part, int nb) {
    __shared__ int buf[1024];
    const int tid = threadIdx.x;
    const int v = (tid < nb) ? part[tid] : 0;
    buf[tid] = v;
    __syncthreads();
    #pragma unroll 1
    for (int off = 1; off < 1024; off <<= 1) {
        int t = (tid >= off) ? buf[tid - off] : 0;
        __syncthreads();
        buf[tid] += t;
        __syncthreads();
    }
    if (tid < nb) part[tid] = buf[tid] - v;       // exclusive
    if (tid == 1023) part[nb] = buf[1023];        // grand total
}

__global__ void scan_add(const int* __restrict__ part, int* __restrict__ rowptr,
                         int* __restrict__ cursor, int n, int nb) {
    int i = blockIdx.x * 256 + threadIdx.x;
    if (i < n) {
        int v = rowptr[i] + part[i >> 10];
        rowptr[i] = v;
        cursor[i] = v;
    }
    if (i == 0) rowptr[n] = part[nb];
}

__global__ void fill_edges(const int* __restrict__ src, const int* __restrict__ dst,
                           int* __restrict__ cursor, int* __restrict__ eidx, int e) {
    int i = blockIdx.x * 256 + threadIdx.x;
    if (i < e) {
        int pos = atomicAdd(&cursor[dst[i]], 1);
        eidx[pos] = src[i];
    }
}

// ---------------- fused weight prep: all W[K][N] fp32 -> hi/lo [N][ldt] ----

__global__ __launch_bounds__(256)
void prep_all(const float* __restrict__ enc_w, const float* __restrict__ s0_ws,
              const float* __restrict__ s0_wn, const float* __restrict__ s1_ws,
              const float* __restrict__ s1_wn, const float* __restrict__ rel_w,
              const float* __restrict__ cw1, const float* __restrict__ cw2,
              short* wt_enc_h, short* wt_enc_l, short* wt_s0_h, short* wt_s0_l,
              short* wt_st_h, short* wt_st_l, short* wt_rel_h, short* wt_rel_l,
              short* wt_c1_h, short* wt_c1_l, short* wt_c2_h, short* wt_c2_l) {
    int e = blockIdx.x * 256 + threadIdx.x;
    const float* W; short* hi; short* lo; int Nd, ldt, koff;
    if (e < 65536)       { W = enc_w; hi = wt_enc_h; lo = wt_enc_l; Nd = 128; ldt = 512; koff = 0; }
    else if (e < 98304)  { e -= 65536;  W = s0_ws; hi = wt_s0_h; lo = wt_s0_l; Nd = 256; ldt = 256; koff = 0; }
    else if (e < 131072) { e -= 98304;  W = s0_wn; hi = wt_s0_h; lo = wt_s0_l; Nd = 256; ldt = 256; koff = 128; }
    else if (e < 163840) { e -= 131072; W = s1_ws; hi = wt_st_h; lo = wt_st_l; Nd = 128; ldt = 256; koff = 0; }
    else if (e < 196608) { e -= 163840; W = s1_wn; hi = wt_st_h + 32768; lo = wt_st_l + 32768; Nd = 128; ldt = 256; koff = 0; }
    else if (e < 229376) { e -= 196608; W = rel_w; hi = wt_rel_h; lo = wt_rel_l; Nd = 128; ldt = 256; koff = 0; }
    else if (e < 237568) { e -= 229376; W = cw1; hi = wt_c1_h; lo = wt_c1_l; Nd = 64; ldt = 128; koff = 0; }
    else if (e < 239616) { e -= 237568; W = cw2; hi = wt_c2_h; lo = wt_c2_l; Nd = 32; ldt = 64; koff = 0; }
    else return;
    const int k = e / Nd, n = e - k * Nd;
    const float x = W[e];
    const unsigned short h = f2bf(x);
    const unsigned short l = f2bf(x - bf2f(h));
    const size_t o = (size_t)n * ldt + koff + k;
    hi[o] = (short)h;
    lo[o] = (short)l;
}

// ---------------- mean aggregation: 2-edge ILP per 16-lane group ------------

__global__ __launch_bounds__(256)
void agg_mean_bb(const short* __restrict__ featb,
                 const int* __restrict__ rowptr, const int* __restrict__ eidx,
                 short* __restrict__ outb, int n) {
    const int node = blockIdx.x * 4 + (threadIdx.x >> 6);
    if (node >= n) return;
    const int lane = threadIdx.x & 63;
    const int g = lane >> 4, j = lane & 15;
    const int beg = rowptr[node], end = rowptr[node + 1];
    float s[8];
    #pragma unroll
    for (int i = 0; i < 8; ++i) s[i] = 0.f;
    for (int e = beg + g; e < end; e += 8) {
        const int e1 = e + 4;
        const bool has2 = e1 < end;
        const int i0 = eidx[e];
        const int i1 = has2 ? eidx[e1] : i0;
        const uint4 v0 = *(const uint4*)(featb + (size_t)i0 * 128 + j * 8);
        const uint4 v1 = *(const uint4*)(featb + (size_t)i1 * 128 + j * 8);
        __builtin_amdgcn_sched_barrier(0);
        s[0] += __uint_as_float(v0.x << 16); s[1] += __uint_as_float(v0.x & 0xffff0000u);
        s[2] += __uint_as_float(v0.y << 16); s[3] += __uint_as_float(v0.y & 0xffff0000u);
        s[4] += __uint_as_float(v0.z << 16); s[5] += __uint_as_float(v0.z & 0xffff0000u);
        s[6] += __uint_as_float(v0.w << 16); s[7] += __uint_as_float(v0.w & 0xffff0000u);
        if (has2) {
            s[0] += __uint_as_float(v1.x << 16); s[1] += __uint_as_float(v1.x & 0xffff0000u);
            s[2] += __uint_as_float(v1.y << 16); s[3] += __uint_as_float(v1.y & 0xffff0000u);
            s[4] += __uint_as_float(v1.z << 16); s[5] += __uint_as_float(v1.z & 0xffff0000u);
            s[6] += __uint_as_float(v1.w << 16); s[7] += __uint_as_float(v1.w & 0xffff0000u);
        }
    }
    #pragma unroll
    for (int i = 0; i < 8; ++i) {
        s[i] += __shfl_xor(s[i], 32);
        s[i] += __shfl_xor(s[i], 16);
    }
    if (g == 0) {
        const float inv = 1.0f / fmaxf((float)(end - beg), 1.0f);
        uint4 o;
        o.x = packbf(s[0] * inv, s[1] * inv);
        o.y = packbf(s[2] * inv, s[3] * inv);
        o.z = packbf(s[4] * inv, s[5] * inv);
        o.w = packbf(s[6] * inv, s[7] * inv);
        *(uint4*)(outb + (size_t)node * 128 + j * 8) = o;
    }
}

// sage1 combine: h2 = relu(bn1(s1 + mean_neigh(t1) + b1)), bf16 out
__global__ __launch_bounds__(256)
void agg_combine_bb(const short* __restrict__ featb,
                    const int* __restrict__ rowptr, const int* __restrict__ eidx,
                    const float* __restrict__ s1,          // [n,128] fp32
                    const float* __restrict__ bias,
                    const float* __restrict__ bng, const float* __restrict__ bnb,
                    const float* __restrict__ bnm, const float* __restrict__ bnv,
                    short* __restrict__ outb, int n) {
    const int node = blockIdx.x * 4 + (threadIdx.x >> 6);
    if (node >= n) return;
    const int lane = threadIdx.x & 63;
    const int g = lane >> 4, j = lane & 15;
    const int beg = rowptr[node], end = rowptr[node + 1];
    float s[8];
    #pragma unroll
    for (int i = 0; i < 8; ++i) s[i] = 0.f;
    for (int e = beg + g; e < end; e += 8) {
        const int e1 = e + 4;
        const bool has2 = e1 < end;
        const int i0 = eidx[e];
        const int i1 = has2 ? eidx[e1] : i0;
        const uint4 v0 = *(const uint4*)(featb + (size_t)i0 * 128 + j * 8);
        const uint4 v1 = *(const uint4*)(featb + (size_t)i1 * 128 + j * 8);
        __builtin_amdgcn_sched_barrier(0);
        s[0] += __uint_as_float(v0.x << 16); s[1] += __uint_as_float(v0.x & 0xffff0000u);
        s[2] += __uint_as_float(v0.y << 16); s[3] += __uint_as_float(v0.y & 0xffff0000u);
        s[4] += __uint_as_float(v0.z << 16); s[5] += __uint_as_float(v0.z & 0xffff0000u);
        s[6] += __uint_as_float(v0.w << 16); s[7] += __uint_as_float(v0.w & 0xffff0000u);
        if (has2) {
            s[0] += __uint_as_float(v1.x << 16); s[1] += __uint_as_float(v1.x & 0xffff0000u);
            s[2] += __uint_as_float(v1.y << 16); s[3] += __uint_as_float(v1.y & 0xffff0000u);
            s[4] += __uint_as_float(v1.z << 16); s[5] += __uint_as_float(v1.z & 0xffff0000u);
            s[6] += __uint_as_float(v1.w << 16); s[7] += __uint_as_float(v1.w & 0xffff0000u);
        }
    }
    #pragma unroll
    for (int i = 0; i < 8; ++i) {
        s[i] += __shfl_xor(s[i], 32);
        s[i] += __shfl_xor(s[i], 16);
    }
    if (g == 0) {
        const float inv = 1.0f / fmaxf((float)(end - beg), 1.0f);
        const int c0 = j * 8;
        const float4 a0 = *(const float4*)(s1 + (size_t)node * 128 + c0);
        const float4 a1 = *(const float4*)(s1 + (size_t)node * 128 + c0 + 4);
        const float sf[8] = {a0.x, a0.y, a0.z, a0.w, a1.x, a1.y, a1.z, a1.w};
        float r[8];
        #pragma unroll
        for (int i = 0; i < 8; ++i) {
            const int c = c0 + i;
            float v = sf[i] + s[i] * inv + bias[c];
            v = (v - bnm[c]) * (bng[c] / sqrtf(bnv[c] + EPS)) + bnb[c];
            r[i] = fmaxf(v, 0.f);
        }
        uint4 o;
        o.x = packbf(r[0], r[1]); o.y = packbf(r[2], r[3]);
        o.z = packbf(r[4], r[5]); o.w = packbf(r[6], r[7]);
        *(uint4*)(outb + (size_t)node * 128 + j * 8) = o;
    }
}

// ---------------- all-LDS MFMA GEMM: bf16 A, split-bf16 W ------------------
// (unchanged from R11: 2m x 2n waves, BK=64, gload_lds A+B, counted vmcnt)
template<int NT, int K1, int K2>
__global__ __launch_bounds__(256)
void gemm_dp(const short* __restrict__ A1, int lda1,
             const short* __restrict__ A2, int lda2,
             const short* __restrict__ Wt_hi, const short* __restrict__ Wt_lo,
             const float* __restrict__ bias,
             const float* __restrict__ bng, const float* __restrict__ bnb,
             const float* __restrict__ bnm, const float* __restrict__ bnv,
             int relu,
             float* __restrict__ Cf, int fpN, int ldc,
             short* __restrict__ Cb, int bfcol0, int ldcb,
             int M) {
    constexpr int K   = K1 + K2;
    constexpr int NBK = K / 64;
    constexpr int NTW = NT / 2;
    static_assert(K % 64 == 0, "K multiple of 64");
    static_assert(NT % 2 == 0, "NT even");
    static_assert(K2 == 0 || K1 % 64 == 0, "concat boundary on BK");
    constexpr int ASZ = 128 * 64;                 // shorts (16KB)
    constexpr int BSZ = 2 * NT * 16 * 64;         // shorts (hi+lo planes)
    constexpr int BUF = ASZ + BSZ;
    __shared__ short lds[2 * BUF];

    const int tid  = threadIdx.x;
    const int lane = tid & 63;
    const int wv   = tid >> 6;
    const int wm   = wv >> 1;                     // 0..1 (row half)
    const int wn   = wv & 1;                      // 0..1 (col half)
    const int bm   = blockIdx.y * 128;
    const int col0 = blockIdx.x * (NT * 16);
    const int lrow = lane & 15;
    const int quad = lane >> 4;

    const int su = (tid & 7) ^ ((tid >> 3) & 7);
    const short* gsA1[4];
    const short* gsA2[4];
    #pragma unroll
    for (int jj = 0; jj < 4; ++jj) {
        const int rg = min(bm + jj * 32 + (tid >> 3), M - 1);
        gsA1[jj] = A1 + (size_t)rg * lda1 + su * 8;
        if constexpr (K2 > 0) gsA2[jj] = A2 + (size_t)rg * lda2 + su * 8;
        else gsA2[jj] = nullptr;
    }
    const short* gsB[NT];                         // B "rows": hi cols, then lo
    #pragma unroll
    for (int jj = 0; jj < NT; ++jj) {
        const int colIdx = jj * 32 + (tid >> 3);  // 0..2*NT*16-1
        const bool ishi = colIdx < NT * 16;
        const int cp = ishi ? colIdx : colIdx - NT * 16;
        gsB[jj] = (ishi ? Wt_hi : Wt_lo) + (size_t)(col0 + cp) * K + su * 8;
    }

    auto stage = [&](int b, int c) {
        const int k = c * 64;
        #pragma unroll
        for (int jj = 0; jj < 4; ++jj) {
            const short* p;
            if constexpr (K2 > 0)
                p = (k < K1) ? (gsA1[jj] + k) : (gsA2[jj] + (k - K1));
            else
                p = gsA1[jj] + k;
            gload_lds16(p, &lds[b * BUF + (jj * 256 + tid) * 8]);
        }
        #pragma unroll
        for (int jj = 0; jj < NT; ++jj)
            gload_lds16(gsB[jj] + k, &lds[b * BUF + ASZ + (jj * 256 + tid) * 8]);
    };

    int aoff[4][2];
    #pragma unroll
    for (int m = 0; m < 4; ++m)
        #pragma unroll
        for (int kk = 0; kk < 2; ++kk)
            aoff[m][kk] = (wm * 64 + m * 16 + lrow) * 64 +
                          (((kk * 4 + quad) ^ (lrow & 7)) * 8);
    int boff[NTW][2];
    #pragma unroll
    for (int nt = 0; nt < NTW; ++nt)
        #pragma unroll
        for (int kk = 0; kk < 2; ++kk)
            boff[nt][kk] = (wn * NTW * 16 + nt * 16 + lrow) * 64 +
                           (((kk * 4 + quad) ^ (lrow & 7)) * 8);

    f32x4 acc[4][NTW];
    #pragma unroll
    for (int m = 0; m < 4; ++m)
        #pragma unroll
        for (int nt = 0; nt < NTW; ++nt)
            acc[m][nt] = (f32x4){0.f, 0.f, 0.f, 0.f};

    stage(0, 0);

    for (int c = 0; c < NBK; ++c) {
        const int b = c & 1;
        if (c + 1 < NBK) {
            stage(b ^ 1, c + 1);
            if constexpr (NT == 4) asm volatile("s_waitcnt vmcnt(8)" ::: "memory");
            else                   asm volatile("s_waitcnt vmcnt(6)" ::: "memory");
        } else {
            asm volatile("s_waitcnt vmcnt(0)" ::: "memory");
        }
        __builtin_amdgcn_s_barrier();             // buf b fully staged

        const short* La = &lds[b * BUF];
        const short* Lb = &lds[b * BUF + ASZ];
        #pragma unroll
        for (int kk = 0; kk < 2; ++kk) {
            bf16x8 a[4];
            #pragma unroll
            for (int m = 0; m < 4; ++m)
                a[m] = *(const bf16x8*)(La + aoff[m][kk]);
            #pragma unroll
            for (int nt = 0; nt < NTW; ++nt) {
                const bf16x8 vbh = *(const bf16x8*)(Lb + boff[nt][kk]);
                const bf16x8 vbl = *(const bf16x8*)(Lb + boff[nt][kk] + NT * 16 * 64);
                #pragma unroll
                for (int m = 0; m < 4; ++m) {
                    acc[m][nt] = __builtin_amdgcn_mfma_f32_16x16x32_bf16(a[m], vbh, acc[m][nt], 0, 0, 0);
                    acc[m][nt] = __builtin_amdgcn_mfma_f32_16x16x32_bf16(a[m], vbl, acc[m][nt], 0, 0, 0);
                }
            }
        }
        asm volatile("" ::: "memory");
        __builtin_amdgcn_s_barrier();             // all waves done with buf b
    }

    // ---- epilogue via LDS: coalesced stores ----
    constexpr int EW = NT * 16 + 4;
    float* ep = (float*)lds;

    #pragma unroll
    for (int nt = 0; nt < NTW; ++nt) {
        const int lcol = wn * NTW * 16 + nt * 16 + lrow;
        const int gcol = col0 + lcol;
        const float bsc = bias ? bias[gcol] : 0.f;
        float gg = 1.f, bb = 0.f, mm = 0.f;
        if (bng) { gg = bng[gcol] / sqrtf(bnv[gcol] + EPS); bb = bnb[gcol]; mm = bnm[gcol]; }
        #pragma unroll
        for (int m = 0; m < 4; ++m) {
            #pragma unroll
            for (int r = 0; r < 4; ++r) {
                float x = acc[m][nt][r] + bsc;
                if (bng) x = (x - mm) * gg + bb;
                if (relu) x = fmaxf(x, 0.f);
                ep[(wm * 64 + m * 16 + quad * 4 + r) * EW + lcol] = x;
            }
        }
    }
    __syncthreads();

    if (col0 < fpN) {
        for (int g = tid; g < 128 * NT * 4; g += 256) {
            const int row = g / (NT * 4), u = g - row * (NT * 4);
            const int grow = bm + row;
            if (grow < M)
                *(float4*)(Cf + (size_t)grow * ldc + col0 + u * 4) =
                    *(const float4*)(ep + row * EW + u * 4);
        }
    } else {
        for (int g = tid; g < 128 * NT * 2; g += 256) {
            const int row = g / (NT * 2), u = g - row * (NT * 2);
            const int grow = bm + row;
            const float4 f0 = *(const float4*)(ep + row * EW + u * 8);
            const float4 f1 = *(const float4*)(ep + row * EW + u * 8 + 4);
            uint4 o;
            o.x = packbf(f0.x, f0.y); o.y = packbf(f0.z, f0.w);
            o.z = packbf(f1.x, f1.y); o.w = packbf(f1.z, f1.w);
            if (grow < M)
                *(uint4*)(Cb + (size_t)grow * ldcb + (col0 - bfcol0) + u * 8) = o;
        }
    }
}

// ---------------- fused enc GEMM: fp32 concat A -> bf16 staging -----------
// h0 = relu(concat(sf,mf) @ enc_w + enc_b). Same tile/LDS/compute as
// gemm_dp (NT=4, BK=64), but A is read fp32 from sf/mf and converted during
// staging: top of step c issues 8 float4 A(c+1) reg-loads + gload_lds
// B(c+1); compute(c) hides HBM latency; then f2bf + ds_write_b128 into the
// identical bf16 XOR-swizzled LDS layout; vmcnt(0) (B) + one barrier/step.
__global__ __launch_bounds__(256)
void gemm_enc(const float* __restrict__ A1f,           // sf [M,128]
              const float* __restrict__ A2f,           // mf [M,384]
              const short* __restrict__ Wt_hi, const short* __restrict__ Wt_lo,
              const float* __restrict__ bias,
              short* __restrict__ Cb, int ldcb, int M) {
    constexpr int NT = 4, NTW = 2, K = 512, NBK = 8;
    constexpr int ASZ = 128 * 64;                 // shorts (16KB)
    constexpr int BSZ = 2 * NT * 16 * 64;         // shorts (16KB)
    constexpr int BUF = ASZ + BSZ;
    __shared__ short lds[2 * BUF];                // 64 KB

    const int tid  = threadIdx.x;
    const int lane = tid & 63;
    const int wv   = tid >> 6;
    const int wm   = wv >> 1;
    const int wn   = wv & 1;
    const int bm   = blockIdx.y * 128;
    const int col0 = blockIdx.x * (NT * 16);
    const int lrow = lane & 15;
    const int quad = lane >> 4;

    // A staging: thread owns LDS bf16 units j*256+tid (j=0..3):
    //   row r = j*32 + (tid>>3), swizzled unit su covers k = su*8..su*8+7.
    const int su = (tid & 7) ^ ((tid >> 3) & 7);
    const float* gsA1[4];
    const float* gsA2[4];
    #pragma unroll
    for (int jj = 0; jj < 4; ++jj) {
        const int rg = min(bm + jj * 32 + (tid >> 3), M - 1);
        gsA1[jj] = A1f + (size_t)rg * 128 + su * 8;
        gsA2[jj] = A2f + (size_t)rg * 384 + su * 8;
    }
    const short* gsB[NT];
    #pragma unroll
    for (int jj = 0; jj < NT; ++jj) {
        const int colIdx = jj * 32 + (tid >> 3);
        const bool ishi = colIdx < NT * 16;
        const int cp = ishi ? colIdx : colIdx - NT * 16;
        gsB[jj] = (ishi ? Wt_hi : Wt_lo) + (size_t)(col0 + cp) * K + su * 8;
    }
    auto stageB = [&](int b, int c) {
        const int k = c * 64;
        #pragma unroll
        for (int jj = 0; jj < NT; ++jj)
            gload_lds16(gsB[jj] + k, &lds[b * BUF + ASZ + (jj * 256 + tid) * 8]);
    };

    int aoff[4][2], boff[NTW][2];
    #pragma unroll
    for (int m = 0; m < 4; ++m)
        #pragma unroll
        for (int kk = 0; kk < 2; ++kk)
            aoff[m][kk] = (wm * 64 + m * 16 + lrow) * 64 +
                          (((kk * 4 + quad) ^ (lrow & 7)) * 8);
    #pragma unroll
    for (int nt = 0; nt < NTW; ++nt)
        #pragma unroll
        for (int kk = 0; kk < 2; ++kk)
            boff[nt][kk] = (wn * NTW * 16 + nt * 16 + lrow) * 64 +
                           (((kk * 4 + quad) ^ (lrow & 7)) * 8);

    f32x4 acc[4][NTW];
    #pragma unroll
    for (int m = 0; m < 4; ++m)
        #pragma unroll
        for (int nt = 0; nt < NTW; ++nt)
            acc[m][nt] = (f32x4){0.f, 0.f, 0.f, 0.f};

    float4 awin[8];                               // [jj*2+h], one K-step window

    // ---- prologue: stage chunk 0 (k<128 -> sf) into buf 0 ----
    #pragma unroll
    for (int jj = 0; jj < 4; ++jj) {
        awin[jj * 2 + 0] = *(const float4*)(gsA1[jj]);
        awin[jj * 2 + 1] = *(const float4*)(gsA1[jj] + 4);
    }
    stageB(0, 0);
    #pragma unroll
    for (int jj = 0; jj < 4; ++jj) {
        const float4 w0 = awin[jj * 2 + 0], w1 = awin[jj * 2 + 1];
        uint4 o;
        o.x = packbf(w0.x, w0.y); o.y = packbf(w0.z, w0.w);
        o.z = packbf(w1.x, w1.y); o.w = packbf(w1.z, w1.w);
        *((uint4*)&lds[(jj * 256 + tid) * 8]) = o;
    }
    asm volatile("s_waitcnt vmcnt(0)" ::: "memory");   // B(0) landed
    __builtin_amdgcn_s_barrier();

    #pragma unroll
    for (int c = 0; c < NBK; ++c) {
        const int cur = c & 1, nxt = cur ^ 1;
        if (c + 1 < NBK) {
            const int k1 = (c + 1) * 64;          // compile-time
            #pragma unroll
            for (int jj = 0; jj < 4; ++jj) {
                const float* p = (k1 < 128) ? (gsA1[jj] + k1)
                                            : (gsA2[jj] + (k1 - 128));
                awin[jj * 2 + 0] = *(const float4*)p;
                awin[jj * 2 + 1] = *(const float4*)(p + 4);
            }
            stageB(nxt, c + 1);
            __builtin_amdgcn_sched_barrier(0);    // loads issue before compute
        }

        const short* La = &lds[cur * BUF];
        const short* Lb = &lds[cur * BUF + ASZ];
        #pragma unroll
        for (int kk = 0; kk < 2; ++kk) {
            bf16x8 a[4];
            #pragma unroll
            for (int m = 0; m < 4; ++m)
                a[m] = *(const bf16x8*)(La + aoff[m][kk]);
            #pragma unroll
            for (int nt = 0; nt < NTW; ++nt) {
                const bf16x8 vbh = *(const bf16x8*)(Lb + boff[nt][kk]);
                const bf16x8 vbl = *(const bf16x8*)(Lb + boff[nt][kk] + NT * 16 * 64);
                #pragma unroll
                for (int m = 0; m < 4; ++m) {
                    acc[m][nt] = __builtin_amdgcn_mfma_f32_16x16x32_bf16(a[m], vbh, acc[m][nt], 0, 0, 0);
                    acc[m][nt] = __builtin_amdgcn_mfma_f32_16x16x32_bf16(a[m], vbl, acc[m][nt], 0, 0, 0);
                }
            }
        }

        if (c + 1 < NBK) {
            // convert + ds_write A(c+1) into buf nxt (readers of nxt finished
            // at the previous barrier; safe anywhere in this iteration).
            #pragma unroll
            for (int jj = 0; jj < 4; ++jj) {
                const float4 w0 = awin[jj * 2 + 0], w1 = awin[jj * 2 + 1];
                uint4 o;
                o.x = packbf(w0.x, w0.y); o.y = packbf(w0.z, w0.w);
                o.z = packbf(w1.x, w1.y); o.w = packbf(w1.z, w1.w);
                *((uint4*)&lds[nxt * BUF + (jj * 256 + tid) * 8]) = o;
            }
            asm volatile("s_waitcnt vmcnt(0)" ::: "memory");  // B(c+1) landed
            __builtin_amdgcn_s_barrier();         // publish buf nxt
        }
    }
    __builtin_amdgcn_s_barrier();                 // all waves done computing

    // ---- epilogue (bf16 out, bias + relu) ----
    constexpr int EW = NT * 16 + 4;
    float* ep = (float*)lds;
    #pragma unroll
    for (int nt = 0; nt < NTW; ++nt) {
        const int lcol = wn * NTW * 16 + nt * 16 + lrow;
        const float bsc = bias[col0 + lcol];
        #pragma unroll
        for (int m = 0; m < 4; ++m)
            #pragma unroll
            for (int r = 0; r < 4; ++r)
                ep[(wm * 64 + m * 16 + quad * 4 + r) * EW + lcol] =
                    fmaxf(acc[m][nt][r] + bsc, 0.f);
    }
    __syncthreads();
    for (int g = tid; g < 128 * NT * 2; g += 256) {
        const int row = g / (NT * 2), u = g - row * (NT * 2);
        const int grow = bm + row;
        const float4 f0 = *(const float4*)(ep + row * EW + u * 8);
        const float4 f1 = *(const float4*)(ep + row * EW + u * 8 + 4);
        uint4 o;
        o.x = packbf(f0.x, f0.y); o.y = packbf(f0.z, f0.w);
        o.z = packbf(f1.x, f1.y); o.w = packbf(f1.z, f1.w);
        if (grow < M)
            *(uint4*)(Cb + (size_t)grow * ldcb + col0 + u * 8) = o;
    }
}

// ---------------- fused classifier: out = relu(rb@w1+b1)@w2+b2 -------------
__global__ __launch_bounds__(256)
void gemm_cls(const short* __restrict__ A1,            // rb [M,128]
              const short* __restrict__ W1h, const short* __restrict__ W1l,
              const float* __restrict__ cb1,
              const short* __restrict__ W2h, const short* __restrict__ W2l,
              const float* __restrict__ cb2,
              float* __restrict__ out, int M) {
    constexpr int NT = 4, NTW = 2, NBK = 2, K = 128;
    constexpr int ASZ = 128 * 64, BSZ = 2 * NT * 16 * 64, BUF = ASZ + BSZ;
    __shared__ short lds[2 * BUF];                // 64 KB

    const int tid  = threadIdx.x;
    const int lane = tid & 63;
    const int wv   = tid >> 6;
    const int wm   = wv >> 1;
    const int wn   = wv & 1;
    const int bm   = blockIdx.x * 128;
    const int lrow = lane & 15;
    const int quad = lane >> 4;

    const int su = (tid & 7) ^ ((tid >> 3) & 7);
    const short* gsA[4];
    #pragma unroll
    for (int jj = 0; jj < 4; ++jj) {
        const int rg = min(bm + jj * 32 + (tid >> 3), M - 1);
        gsA[jj] = A1 + (size_t)rg * 128 + su * 8;
    }
    const short* gsB[NT];
    #pragma unroll
    for (int jj = 0; jj < NT; ++jj) {
        const int colIdx = jj * 32 + (tid >> 3);
        const bool ishi = colIdx < NT * 16;
        const int cp = ishi ? colIdx : colIdx - NT * 16;
        gsB[jj] = (ishi ? W1h : W1l) + (size_t)cp * K + su * 8;
    }
    auto stage = [&](int b, int c) {
        const int k = c * 64;
        #pragma unroll
        for (int jj = 0; jj < 4; ++jj)
            gload_lds16(gsA[jj] + k, &lds[b * BUF + (jj * 256 + tid) * 8]);
        #pragma unroll
        for (int jj = 0; jj < NT; ++jj)
            gload_lds16(gsB[jj] + k, &lds[b * BUF + ASZ + (jj * 256 + tid) * 8]);
    };

    int aoff[4][2], boff[NTW][2];
    #pragma unroll
    for (int m = 0; m < 4; ++m)
        #pragma unroll
        for (int kk = 0; kk < 2; ++kk)
            aoff[m][kk] = (wm * 64 + m * 16 + lrow) * 64 +
                          (((kk * 4 + quad) ^ (lrow & 7)) * 8);
    #pragma unroll
    for (int nt = 0; nt < NTW; ++nt)
        #pragma unroll
        for (int kk = 0; kk < 2; ++kk)
            boff[nt][kk] = (wn * NTW * 16 + nt * 16 + lrow) * 64 +
                           (((kk * 4 + quad) ^ (lrow & 7)) * 8);

    f32x4 acc[4][NTW];
    #pragma unroll
    for (int m = 0; m < 4; ++m)
        #pragma unroll
        for (int nt = 0; nt < NTW; ++nt)
            acc[m][nt] = (f32x4){0.f, 0.f, 0.f, 0.f};

    stage(0, 0);
    for (int c = 0; c < NBK; ++c) {
        const int b = c & 1;
        if (c + 1 < NBK) {
            stage(b ^ 1, c + 1);
            asm volatile("s_waitcnt vmcnt(8)" ::: "memory");
        } else {
            asm volatile("s_waitcnt vmcnt(0)" ::: "memory");
        }
        __builtin_amdgcn_s_barrier();
        const short* La = &lds[b * BUF];
        const short* Lb = &lds[b * BUF + ASZ];
        #pragma unroll
        for (int kk = 0; kk < 2; ++kk) {
            bf16x8 a[4];
            #pragma unroll
            for (int m = 0; m < 4; ++m)
                a[m] = *(const bf16x8*)(La + aoff[m][kk]);
            #pragma unroll
            for (int nt = 0; nt < NTW; ++nt) {
                const bf16x8 vbh = *(const bf16x8*)(Lb + boff[nt][kk]);
                const bf16x8 vbl = *(const bf16x8*)(Lb + boff[nt][kk] + NT * 16 * 64);
                #pragma unroll
                for (int m = 0; m < 4; ++m) {
                    acc[m][nt] = __builtin_amdgcn_mfma_f32_16x16x32_bf16(a[m], vbh, acc[m][nt], 0, 0, 0);
                    acc[m][nt] = __builtin_amdgcn_mfma_f32_16x16x32_bf16(a[m], vbl, acc[m][nt], 0, 0, 0);
                }
            }
        }
        asm volatile("" ::: "memory");
        __builtin_amdgcn_s_barrier();
    }

    // ---- phase-1 epilogue -> ep (relu(o1)) ----
    constexpr int EW = 68;
    float* ep = (float*)lds;
    #pragma unroll
    for (int nt = 0; nt < NTW; ++nt) {
        const int lcol = wn * NTW * 16 + nt * 16 + lrow;
        const float bsc = cb1[lcol];
        #pragma unroll
        for (int m = 0; m < 4; ++m)
            #pragma unroll
            for (int r = 0; r < 4; ++r)
                ep[(wm * 64 + m * 16 + quad * 4 + r) * EW + lcol] =
                    fmaxf(acc[m][nt][r] + bsc, 0.f);
    }
    __syncthreads();

    // ---- phase 2: o1 (ep) @ w2 ----
    const short* pB2h = W2h + (size_t)(wn * 16 + lrow) * 64 + quad * 8;
    const short* pB2l = W2l + (size_t)(wn * 16 + lrow) * 64 + quad * 8;
    f32x4 acc2[4];
    #pragma unroll
    for (int m = 0; m < 4; ++m) acc2[m] = (f32x4){0.f, 0.f, 0.f, 0.f};
    #pragma unroll
    for (int kk = 0; kk < 2; ++kk) {
        const bf16x8 bh = *(const bf16x8*)(pB2h + kk * 32);
        const bf16x8 bl = *(const bf16x8*)(pB2l + kk * 32);
        #pragma unroll
        for (int m = 0; m < 4; ++m) {
            const float* pe = ep + (wm * 64 + m * 16 + lrow) * EW + kk * 32 + quad * 8;
            const float4 e0 = *(const float4*)pe;
            const float4 e1 = *(const float4*)(pe + 4);
            bf16x8 a;
            a[0] = (short)f2bf(e0.x); a[1] = (short)f2bf(e0.y);
            a[2] = (short)f2bf(e0.z); a[3] = (short)f2bf(e0.w);
            a[4] = (short)f2bf(e1.x); a[5] = (short)f2bf(e1.y);
            a[6] = (short)f2bf(e1.z); a[7] = (short)f2bf(e1.w);
            acc2[m] = __builtin_amdgcn_mfma_f32_16x16x32_bf16(a, bh, acc2[m], 0, 0, 0);
            acc2[m] = __builtin_amdgcn_mfma_f32_16x16x32_bf16(a, bl, acc2[m], 0, 0, 0);
        }
    }

    constexpr int EW2 = 36;
    float* ep2 = (float*)lds + 128 * EW;
    {
        const int lcol = wn * 16 + lrow;
        const float bsc = cb2[lcol];
        #pragma unroll
        for (int m = 0; m < 4; ++m)
            #pragma unroll
            for (int r = 0; r < 4; ++r)
                ep2[(wm * 64 + m * 16 + quad * 4 + r) * EW2 + lcol] =
                    acc2[m][r] + bsc;
    }
    __syncthreads();
    #pragma unroll
    for (int j = 0; j < 4; ++j) {
        const int g = tid + j * 256;
        const int row = g >> 3, u = g & 7;
        const int grow = bm + row;
        if (grow < M)
            *(float4*)(out + (size_t)grow * 32 + u * 4) =
                *(const float4*)(ep2 + row * EW2 + u * 4);
    }
}

// ---------------------------------------------------------------------------

extern "C" void kernel_launch(void* const* d_in, const int* in_sizes, int n_in,
                              void* d_out, int out_size, void* d_ws, size_t ws_size,
                              hipStream_t stream) {
    const float* sf    = (const float*)d_in[0];
    const float* mf    = (const float*)d_in[1];
    const int*   src   = (const int*)d_in[2];
    const int*   dst   = (const int*)d_in[3];
    const float* enc_w = (const float*)d_in[4];
    const float* enc_b = (const float*)d_in[5];
    const float* s0_ws = (const float*)d_in[6];
    const float* s0_wn = (const float*)d_in[7];
    const float* s0_b  = (const float*)d_in[8];
    const float* bn0_g = (const float*)d_in[9];
    const float* bn0_b = (const float*)d_in[10];
    const float* bn0_m = (const float*)d_in[11];
    const float* bn0_v = (const float*)d_in[12];
    const float* s1_ws = (const float*)d_in[13];
    const float* s1_wn = (const float*)d_in[14];
    const float* s1_b  = (const float*)d_in[15];
    const float* bn1_g = (const float*)d_in[16];
    const float* bn1_b = (const float*)d_in[17];
    const float* bn1_m = (const float*)d_in[18];
    const float* bn1_v = (const float*)d_in[19];
    const float* rel_w = (const float*)d_in[20];
    const float* rel_b = (const float*)d_in[21];
    const float* cw1   = (const float*)d_in[22];
    const float* cb1   = (const float*)d_in[23];
    const float* cw2   = (const float*)d_in[24];
    const float* cb2   = (const float*)d_in[25];
    float* out = (float*)d_out;

    const int nn = in_sizes[0] / 128;   // 100000
    const int ne = in_sizes[2];         // 800000
    const int nb = (nn + 1023) / 1024;  // scan blocks (98)

    // workspace layout (xb region retained only as backing for st/h1b)
    short* h0b   = (short*)d_ws;                       // [nn,128] bf16
    short* xb    = h0b + (size_t)nn * 128;             // region [nn,512]
    float* st    = (float*)xb;                         // s1 fp32 [nn,128]
    short* h1b   = (short*)(st + (size_t)nn * 128);    // [nn,256] bf16
    short* agg0b = xb + (size_t)nn * 512;              // [nn,128]
    short* t1b   = agg0b + (size_t)nn * 128;           // [nn,128]; reused as rb
    short* h2b   = t1b + (size_t)nn * 128;             // [nn,128]
    short* rb    = t1b;                                // [nn,128] (t1b dead)
    int* deg    = (int*)(h2b + (size_t)nn * 128);
    int* rowptr = deg + nn;
    int* cursor = rowptr + nn + 1;
    int* part   = cursor + nn;                         // [nb+1]
    int* eidx   = part + nb + 1;
    short* wts = (short*)(eidx + ne);
    short* wt_enc_h = wts;                 short* wt_enc_l = wt_enc_h + 65536;   // [128][512]
    short* wt_s0_h  = wt_enc_l + 65536;    short* wt_s0_l  = wt_s0_h  + 65536;   // [256][256]
    short* wt_st_h  = wt_s0_l  + 65536;    short* wt_st_l  = wt_st_h  + 65536;   // [256][256]
    short* wt_rel_h = wt_st_l  + 65536;    short* wt_rel_l = wt_rel_h + 32768;   // [128][256]
    short* wt_c1_h  = wt_rel_l + 32768;    short* wt_c1_l  = wt_c1_h  + 8192;    // [64][128]
    short* wt_c2_h  = wt_c1_l  + 8192;     short* wt_c2_l  = wt_c2_h  + 2048;    // [32][64]

    const dim3 blk(256);
    const int gM = (nn + 127) / 128;    // 782 row-blocks

    // --- CSR build (parallel scan) ---
    hipMemsetAsync(deg, 0, (size_t)nn * 4, stream);
    count_deg <<<dim3((ne + 255) / 256), blk, 0, stream>>>(dst, deg, ne);
    scan_block<<<dim3(nb), dim3(1024), 0, stream>>>(deg, rowptr, part, nn);
    scan_part <<<dim3(1),  dim3(1024), 0, stream>>>(part, nb);
    scan_add  <<<dim3((nn + 255) / 256), blk, 0, stream>>>(part, rowptr, cursor, nn, nb);
    fill_edges<<<dim3((ne + 255) / 256), blk, 0, stream>>>(src, dst, cursor, eidx, ne);

    // --- weight prep (fused, 1 launch) ---
    prep_all<<<dim3(936), blk, 0, stream>>>(
        enc_w, s0_ws, s0_wn, s1_ws, s1_wn, rel_w, cw1, cw2,
        wt_enc_h, wt_enc_l, wt_s0_h, wt_s0_l, wt_st_h, wt_st_l,
        wt_rel_h, wt_rel_l, wt_c1_h, wt_c1_l, wt_c2_h, wt_c2_l);

    // --- h0 = relu(concat(sf,mf) @ enc_w + enc_b) -> h0b bf16 (fused) ---
    gemm_enc<<<dim3(2, gM), blk, 0, stream>>>(
        sf, mf, wt_enc_h, wt_enc_l, enc_b, h0b, 128, nn);

    // --- agg0 = mean_neigh(h0b) -> agg0b bf16 ---
    agg_mean_bb<<<dim3((nn + 3) / 4), blk, 0, stream>>>(
        h0b, rowptr, eidx, agg0b, nn);

    // --- h1 = relu(bn0(h0@ws0 + agg0@wn0 + b0)) -> h1b bf16 ---
    gemm_dp<4, 128, 128><<<dim3(4, gM), blk, 0, stream>>>(
        h0b, 128, agg0b, 128, wt_s0_h, wt_s0_l, s0_b,
        bn0_g, bn0_b, bn0_m, bn0_v, 1,
        nullptr, 0, 0, h1b, 0, 256, nn);

    // --- [s1 | t1] = h1 @ [ws1 | wn1]; s1 fp32 -> st, t1 bf16 -> t1b ---
    gemm_dp<4, 256, 0><<<dim3(4, gM), blk, 0, stream>>>(
        h1b, 256, nullptr, 0, wt_st_h, wt_st_l, nullptr,
        nullptr, nullptr, nullptr, nullptr, 0,
        st, 128, 128, t1b, 128, 128, nn);

    // --- h2 = relu(bn1(s1 + mean_neigh(t1) + b1)) -> h2b bf16 ---
    agg_combine_bb<<<dim3((nn + 3) / 4), blk, 0, stream>>>(
        t1b, rowptr, eidx, st, s1_b,
        bn1_g, bn1_b, bn1_m, bn1_v, h2b, nn);

    // --- r = relu(h0@rel_w[:128] + h2@rel_w[128:] + rel_b) -> rb bf16 ---
    gemm_dp<4, 128, 128><<<dim3(2, gM), blk, 0, stream>>>(
        h0b, 128, h2b, 128, wt_rel_h, wt_rel_l, rel_b,
        nullptr, nullptr, nullptr, nullptr, 1,
        nullptr, 0, 0, rb, 0, 128, nn);

    // --- out = relu(rb@w1+b1)@w2+b2 (fused classifier) ---
    gemm_cls<<<dim3(gM), blk, 0, stream>>>(
        rb, wt_c1_h, wt_c1_l, cb1, wt_c2_h, wt_c2_l, cb2, out, nn);
}

// Round 7
// 659.404 us; speedup vs baseline: 1.6432x; 1.0028x over previous
//
#include <hip/hip_runtime.h>
#include <math.h>

// ---------------------------------------------------------------------------
// MultiModalGraphSAGE — R13.
// R12 post-mortem: gemm_enc at 2.13 TB/s HBM-counted = ~97% of the observed
// environmental ceiling (~2.2 TB/s across ALL kernels, 6 rounds) — enc done.
// R13: fuse the pure chain rel -> rb -> cls into ONE kernel (gemm_relcls):
// K=256 staged K-loop (NT=8, full 128 cols) -> r fp32 tile in LDS ->
// phase2 r@w1 (f2bf pack, bit-identical to the old rb round-trip) ->
// phase3 o1@w2 -> out. Removes one launch + 51MB rb write/read.
// Everything else unchanged from R12.
// ---------------------------------------------------------------------------

#define EPS 1e-5f

typedef __attribute__((ext_vector_type(8))) short bf16x8;
typedef __attribute__((ext_vector_type(4))) float f32x4;

__device__ inline unsigned short f2bf(float x) {
    unsigned u = __float_as_uint(x);
    u += 0x7fff + ((u >> 16) & 1);          // RNE to bf16
    return (unsigned short)(u >> 16);
}
__device__ inline float bf2f(unsigned short h) {
    return __uint_as_float(((unsigned)h) << 16);
}
__device__ inline unsigned packbf(float x, float y) {
    return (unsigned)f2bf(x) | ((unsigned)f2bf(y) << 16);
}

__device__ inline void gload_lds16(const void* g, void* l) {
    __builtin_amdgcn_global_load_lds(
        (__attribute__((address_space(1))) void*)g,
        (__attribute__((address_space(3))) void*)l, 16, 0, 0);
}

// ---------------- CSR build ----------------

__global__ void count_deg(const int* __restrict__ dst, int* __restrict__ deg, int e) {
    int i = blockIdx.x * 256 + threadIdx.x;
    if (i < e) atomicAdd(&deg[dst[i]], 1);
}

__global__ __launch_bounds__(1024)
void scan_block(const int* __restrict__ deg, int* __restrict__ rowptr,
                int* __restrict__ part, int n) {
    __shared__ int buf[1024];
    const int tid = threadIdx.x;
    const int i = blockIdx.x * 1024 + tid;
    const int v = (i < n) ? deg[i] : 0;
    buf[tid] = v;
    __syncthreads();
    #pragma unroll 1
    for (int off = 1; off < 1024; off <<= 1) {
        int t = (tid >= off) ? buf[tid - off] : 0;
        __syncthreads();
        buf[tid] += t;
        __syncthreads();
    }
    if (i < n) rowptr[i] = buf[tid] - v;          // local exclusive
    if (tid == 1023) part[blockIdx.x] = buf[1023];
}

__global__ __launch_bounds__(1024)
void scan_part(int* __restrict__ part, int nb) {
    __shared__ int buf[1024];
    const int tid = threadIdx.x;
    const int v = (tid < nb) ? part[tid] : 0;
    buf[tid] = v;
    __syncthreads();
    #pragma unroll 1
    for (int off = 1; off < 1024; off <<= 1) {
        int t = (tid >= off) ? buf[tid - off] : 0;
        __syncthreads();
        buf[tid] += t;
        __syncthreads();
    }
    if (tid < nb) part[tid] = buf[tid] - v;       // exclusive
    if (tid == 1023) part[nb] = buf[1023];        // grand total
}

__global__ void scan_add(const int* __restrict__ part, int* __restrict__ rowptr,
                         int* __restrict__ cursor, int n, int nb) {
    int i = blockIdx.x * 256 + threadIdx.x;
    if (i < n) {
        int v = rowptr[i] + part[i >> 10];
        rowptr[i] = v;
        cursor[i] = v;
    }
    if (i == 0) rowptr[n] = part[nb];
}

__global__ void fill_edges(const int* __restrict__ src, const int* __restrict__ dst,
                           int* __restrict__ cursor, int* __restrict__ eidx, int e) {
    int i = blockIdx.x * 256 + threadIdx.x;
    if (i < e) {
        int pos = atomicAdd(&cursor[dst[i]], 1);
        eidx[pos] = src[i];
    }
}

// ---------------- fused weight prep: all W[K][N] fp32 -> hi/lo [N][ldt] ----

__global__ __launch_bounds__(256)
void prep_all(const float* __restrict__ enc_w, const float* __restrict__ s0_ws,
              const float* __restrict__ s0_wn, const float* __restrict__ s1_ws,
              const float* __restrict__ s1_wn, const float* __restrict__ rel_w,
              const float* __restrict__ cw1, const float* __restrict__ cw2,
              short* wt_enc_h, short* wt_enc_l, short* wt_s0_h, short* wt_s0_l,
              short* wt_st_h, short* wt_st_l, short* wt_rel_h, short* wt_rel_l,
              short* wt_c1_h, short* wt_c1_l, short* wt_c2_h, short* wt_c2_l) {
    int e = blockIdx.x * 256 + threadIdx.x;
    const float* W; short* hi; short* lo; int Nd, ldt, koff;
    if (e < 65536)       { W = enc_w; hi = wt_enc_h; lo = wt_enc_l; Nd = 128; ldt = 512; koff = 0; }
    else if (e < 98304)  { e -= 65536;  W = s0_ws; hi = wt_s0_h; lo = wt_s0_l; Nd = 256; ldt = 256; koff = 0; }
    else if (e < 131072) { e -= 98304;  W = s0_wn; hi = wt_s0_h; lo = wt_s0_l; Nd = 256; ldt = 256; koff = 128; }
    else if (e < 163840) { e -= 131072; W = s1_ws; hi = wt_st_h; lo = wt_st_l; Nd = 128; ldt = 256; koff = 0; }
    else if (e < 196608) { e -= 163840; W = s1_wn; hi = wt_st_h + 32768; lo = wt_st_l + 32768; Nd = 128; ldt = 256; koff = 0; }
    else if (e < 229376) { e -= 196608; W = rel_w; hi = wt_rel_h; lo = wt_rel_l; Nd = 128; ldt = 256; koff = 0; }
    else if (e < 237568) { e -= 229376; W = cw1; hi = wt_c1_h; lo = wt_c1_l; Nd = 64; ldt = 128; koff = 0; }
    else if (e < 239616) { e -= 237568; W = cw2; hi = wt_c2_h; lo = wt_c2_l; Nd = 32; ldt = 64; koff = 0; }
    else return;
    const int k = e / Nd, n = e - k * Nd;
    const float x = W[e];
    const unsigned short h = f2bf(x);
    const unsigned short l = f2bf(x - bf2f(h));
    const size_t o = (size_t)n * ldt + koff + k;
    hi[o] = (short)h;
    lo[o] = (short)l;
}

// ---------------- mean aggregation: 2-edge ILP per 16-lane group ------------

__global__ __launch_bounds__(256)
void agg_mean_bb(const short* __restrict__ featb,
                 const int* __restrict__ rowptr, const int* __restrict__ eidx,
                 short* __restrict__ outb, int n) {
    const int node = blockIdx.x * 4 + (threadIdx.x >> 6);
    if (node >= n) return;
    const int lane = threadIdx.x & 63;
    const int g = lane >> 4, j = lane & 15;
    const int beg = rowptr[node], end = rowptr[node + 1];
    float s[8];
    #pragma unroll
    for (int i = 0; i < 8; ++i) s[i] = 0.f;
    for (int e = beg + g; e < end; e += 8) {
        const int e1 = e + 4;
        const bool has2 = e1 < end;
        const int i0 = eidx[e];
        const int i1 = has2 ? eidx[e1] : i0;
        const uint4 v0 = *(const uint4*)(featb + (size_t)i0 * 128 + j * 8);
        const uint4 v1 = *(const uint4*)(featb + (size_t)i1 * 128 + j * 8);
        __builtin_amdgcn_sched_barrier(0);
        s[0] += __uint_as_float(v0.x << 16); s[1] += __uint_as_float(v0.x & 0xffff0000u);
        s[2] += __uint_as_float(v0.y << 16); s[3] += __uint_as_float(v0.y & 0xffff0000u);
        s[4] += __uint_as_float(v0.z << 16); s[5] += __uint_as_float(v0.z & 0xffff0000u);
        s[6] += __uint_as_float(v0.w << 16); s[7] += __uint_as_float(v0.w & 0xffff0000u);
        if (has2) {
            s[0] += __uint_as_float(v1.x << 16); s[1] += __uint_as_float(v1.x & 0xffff0000u);
            s[2] += __uint_as_float(v1.y << 16); s[3] += __uint_as_float(v1.y & 0xffff0000u);
            s[4] += __uint_as_float(v1.z << 16); s[5] += __uint_as_float(v1.z & 0xffff0000u);
            s[6] += __uint_as_float(v1.w << 16); s[7] += __uint_as_float(v1.w & 0xffff0000u);
        }
    }
    #pragma unroll
    for (int i = 0; i < 8; ++i) {
        s[i] += __shfl_xor(s[i], 32);
        s[i] += __shfl_xor(s[i], 16);
    }
    if (g == 0) {
        const float inv = 1.0f / fmaxf((float)(end - beg), 1.0f);
        uint4 o;
        o.x = packbf(s[0] * inv, s[1] * inv);
        o.y = packbf(s[2] * inv, s[3] * inv);
        o.z = packbf(s[4] * inv, s[5] * inv);
        o.w = packbf(s[6] * inv, s[7] * inv);
        *(uint4*)(outb + (size_t)node * 128 + j * 8) = o;
    }
}

// sage1 combine: h2 = relu(bn1(s1 + mean_neigh(t1) + b1)), bf16 out
__global__ __launch_bounds__(256)
void agg_combine_bb(const short* __restrict__ featb,
                    const int* __restrict__ rowptr, const int* __restrict__ eidx,
                    const float* __restrict__ s1,          // [n,128] fp32
                    const float* __restrict__ bias,
                    const float* __restrict__ bng, const float* __restrict__ bnb,
                    const float* __restrict__ bnm, const float* __restrict__ bnv,
                    short* __restrict__ outb, int n) {
    const int node = blockIdx.x * 4 + (threadIdx.x >> 6);
    if (node >= n) return;
    const int lane = threadIdx.x & 63;
    const int g = lane >> 4, j = lane & 15;
    const int beg = rowptr[node], end = rowptr[node + 1];
    float s[8];
    #pragma unroll
    for (int i = 0; i < 8; ++i) s[i] = 0.f;
    for (int e = beg + g; e < end; e += 8) {
        const int e1 = e + 4;
        const bool has2 = e1 < end;
        const int i0 = eidx[e];
        const int i1 = has2 ? eidx[e1] : i0;
        const uint4 v0 = *(const uint4*)(featb + (size_t)i0 * 128 + j * 8);
        const uint4 v1 = *(const uint4*)(featb + (size_t)i1 * 128 + j * 8);
        __builtin_amdgcn_sched_barrier(0);
        s[0] += __uint_as_float(v0.x << 16); s[1] += __uint_as_float(v0.x & 0xffff0000u);
        s[2] += __uint_as_float(v0.y << 16); s[3] += __uint_as_float(v0.y & 0xffff0000u);
        s[4] += __uint_as_float(v0.z << 16); s[5] += __uint_as_float(v0.z & 0xffff0000u);
        s[6] += __uint_as_float(v0.w << 16); s[7] += __uint_as_float(v0.w & 0xffff0000u);
        if (has2) {
            s[0] += __uint_as_float(v1.x << 16); s[1] += __uint_as_float(v1.x & 0xffff0000u);
            s[2] += __uint_as_float(v1.y << 16); s[3] += __uint_as_float(v1.y & 0xffff0000u);
            s[4] += __uint_as_float(v1.z << 16); s[5] += __uint_as_float(v1.z & 0xffff0000u);
            s[6] += __uint_as_float(v1.w << 16); s[7] += __uint_as_float(v1.w & 0xffff0000u);
        }
    }
    #pragma unroll
    for (int i = 0; i < 8; ++i) {
        s[i] += __shfl_xor(s[i], 32);
        s[i] += __shfl_xor(s[i], 16);
    }
    if (g == 0) {
        const float inv = 1.0f / fmaxf((float)(end - beg), 1.0f);
        const int c0 = j * 8;
        const float4 a0 = *(const float4*)(s1 + (size_t)node * 128 + c0);
        const float4 a1 = *(const float4*)(s1 + (size_t)node * 128 + c0 + 4);
        const float sf[8] = {a0.x, a0.y, a0.z, a0.w, a1.x, a1.y, a1.z, a1.w};
        float r[8];
        #pragma unroll
        for (int i = 0; i < 8; ++i) {
            const int c = c0 + i;
            float v = sf[i] + s[i] * inv + bias[c];
            v = (v - bnm[c]) * (bng[c] / sqrtf(bnv[c] + EPS)) + bnb[c];
            r[i] = fmaxf(v, 0.f);
        }
        uint4 o;
        o.x = packbf(r[0], r[1]); o.y = packbf(r[2], r[3]);
        o.z = packbf(r[4], r[5]); o.w = packbf(r[6], r[7]);
        *(uint4*)(outb + (size_t)node * 128 + j * 8) = o;
    }
}

// ---------------- all-LDS MFMA GEMM: bf16 A, split-bf16 W ------------------
template<int NT, int K1, int K2>
__global__ __launch_bounds__(256)
void gemm_dp(const short* __restrict__ A1, int lda1,
             const short* __restrict__ A2, int lda2,
             const short* __restrict__ Wt_hi, const short* __restrict__ Wt_lo,
             const float* __restrict__ bias,
             const float* __restrict__ bng, const float* __restrict__ bnb,
             const float* __restrict__ bnm, const float* __restrict__ bnv,
             int relu,
             float* __restrict__ Cf, int fpN, int ldc,
             short* __restrict__ Cb, int bfcol0, int ldcb,
             int M) {
    constexpr int K   = K1 + K2;
    constexpr int NBK = K / 64;
    constexpr int NTW = NT / 2;
    static_assert(K % 64 == 0, "K multiple of 64");
    static_assert(NT % 2 == 0, "NT even");
    static_assert(K2 == 0 || K1 % 64 == 0, "concat boundary on BK");
    constexpr int ASZ = 128 * 64;                 // shorts (16KB)
    constexpr int BSZ = 2 * NT * 16 * 64;         // shorts (hi+lo planes)
    constexpr int BUF = ASZ + BSZ;
    __shared__ short lds[2 * BUF];

    const int tid  = threadIdx.x;
    const int lane = tid & 63;
    const int wv   = tid >> 6;
    const int wm   = wv >> 1;                     // 0..1 (row half)
    const int wn   = wv & 1;                      // 0..1 (col half)
    const int bm   = blockIdx.y * 128;
    const int col0 = blockIdx.x * (NT * 16);
    const int lrow = lane & 15;
    const int quad = lane >> 4;

    const int su = (tid & 7) ^ ((tid >> 3) & 7);
    const short* gsA1[4];
    const short* gsA2[4];
    #pragma unroll
    for (int jj = 0; jj < 4; ++jj) {
        const int rg = min(bm + jj * 32 + (tid >> 3), M - 1);
        gsA1[jj] = A1 + (size_t)rg * lda1 + su * 8;
        if constexpr (K2 > 0) gsA2[jj] = A2 + (size_t)rg * lda2 + su * 8;
        else gsA2[jj] = nullptr;
    }
    const short* gsB[NT];                         // B "rows": hi cols, then lo
    #pragma unroll
    for (int jj = 0; jj < NT; ++jj) {
        const int colIdx = jj * 32 + (tid >> 3);  // 0..2*NT*16-1
        const bool ishi = colIdx < NT * 16;
        const int cp = ishi ? colIdx : colIdx - NT * 16;
        gsB[jj] = (ishi ? Wt_hi : Wt_lo) + (size_t)(col0 + cp) * K + su * 8;
    }

    auto stage = [&](int b, int c) {
        const int k = c * 64;
        #pragma unroll
        for (int jj = 0; jj < 4; ++jj) {
            const short* p;
            if constexpr (K2 > 0)
                p = (k < K1) ? (gsA1[jj] + k) : (gsA2[jj] + (k - K1));
            else
                p = gsA1[jj] + k;
            gload_lds16(p, &lds[b * BUF + (jj * 256 + tid) * 8]);
        }
        #pragma unroll
        for (int jj = 0; jj < NT; ++jj)
            gload_lds16(gsB[jj] + k, &lds[b * BUF + ASZ + (jj * 256 + tid) * 8]);
    };

    int aoff[4][2];
    #pragma unroll
    for (int m = 0; m < 4; ++m)
        #pragma unroll
        for (int kk = 0; kk < 2; ++kk)
            aoff[m][kk] = (wm * 64 + m * 16 + lrow) * 64 +
                          (((kk * 4 + quad) ^ (lrow & 7)) * 8);
    int boff[NTW][2];
    #pragma unroll
    for (int nt = 0; nt < NTW; ++nt)
        #pragma unroll
        for (int kk = 0; kk < 2; ++kk)
            boff[nt][kk] = (wn * NTW * 16 + nt * 16 + lrow) * 64 +
                           (((kk * 4 + quad) ^ (lrow & 7)) * 8);

    f32x4 acc[4][NTW];
    #pragma unroll
    for (int m = 0; m < 4; ++m)
        #pragma unroll
        for (int nt = 0; nt < NTW; ++nt)
            acc[m][nt] = (f32x4){0.f, 0.f, 0.f, 0.f};

    stage(0, 0);

    for (int c = 0; c < NBK; ++c) {
        const int b = c & 1;
        if (c + 1 < NBK) {
            stage(b ^ 1, c + 1);
            if constexpr (NT == 4) asm volatile("s_waitcnt vmcnt(8)" ::: "memory");
            else                   asm volatile("s_waitcnt vmcnt(6)" ::: "memory");
        } else {
            asm volatile("s_waitcnt vmcnt(0)" ::: "memory");
        }
        __builtin_amdgcn_s_barrier();             // buf b fully staged

        const short* La = &lds[b * BUF];
        const short* Lb = &lds[b * BUF + ASZ];
        #pragma unroll
        for (int kk = 0; kk < 2; ++kk) {
            bf16x8 a[4];
            #pragma unroll
            for (int m = 0; m < 4; ++m)
                a[m] = *(const bf16x8*)(La + aoff[m][kk]);
            #pragma unroll
            for (int nt = 0; nt < NTW; ++nt) {
                const bf16x8 vbh = *(const bf16x8*)(Lb + boff[nt][kk]);
                const bf16x8 vbl = *(const bf16x8*)(Lb + boff[nt][kk] + NT * 16 * 64);
                #pragma unroll
                for (int m = 0; m < 4; ++m) {
                    acc[m][nt] = __builtin_amdgcn_mfma_f32_16x16x32_bf16(a[m], vbh, acc[m][nt], 0, 0, 0);
                    acc[m][nt] = __builtin_amdgcn_mfma_f32_16x16x32_bf16(a[m], vbl, acc[m][nt], 0, 0, 0);
                }
            }
        }
        asm volatile("" ::: "memory");
        __builtin_amdgcn_s_barrier();             // all waves done with buf b
    }

    // ---- epilogue via LDS: coalesced stores ----
    constexpr int EW = NT * 16 + 4;
    float* ep = (float*)lds;

    #pragma unroll
    for (int nt = 0; nt < NTW; ++nt) {
        const int lcol = wn * NTW * 16 + nt * 16 + lrow;
        const int gcol = col0 + lcol;
        const float bsc = bias ? bias[gcol] : 0.f;
        float gg = 1.f, bb = 0.f, mm = 0.f;
        if (bng) { gg = bng[gcol] / sqrtf(bnv[gcol] + EPS); bb = bnb[gcol]; mm = bnm[gcol]; }
        #pragma unroll
        for (int m = 0; m < 4; ++m) {
            #pragma unroll
            for (int r = 0; r < 4; ++r) {
                float x = acc[m][nt][r] + bsc;
                if (bng) x = (x - mm) * gg + bb;
                if (relu) x = fmaxf(x, 0.f);
                ep[(wm * 64 + m * 16 + quad * 4 + r) * EW + lcol] = x;
            }
        }
    }
    __syncthreads();

    if (col0 < fpN) {
        for (int g = tid; g < 128 * NT * 4; g += 256) {
            const int row = g / (NT * 4), u = g - row * (NT * 4);
            const int grow = bm + row;
            if (grow < M)
                *(float4*)(Cf + (size_t)grow * ldc + col0 + u * 4) =
                    *(const float4*)(ep + row * EW + u * 4);
        }
    } else {
        for (int g = tid; g < 128 * NT * 2; g += 256) {
            const int row = g / (NT * 2), u = g - row * (NT * 2);
            const int grow = bm + row;
            const float4 f0 = *(const float4*)(ep + row * EW + u * 8);
            const float4 f1 = *(const float4*)(ep + row * EW + u * 8 + 4);
            uint4 o;
            o.x = packbf(f0.x, f0.y); o.y = packbf(f0.z, f0.w);
            o.z = packbf(f1.x, f1.y); o.w = packbf(f1.z, f1.w);
            if (grow < M)
                *(uint4*)(Cb + (size_t)grow * ldcb + (col0 - bfcol0) + u * 8) = o;
        }
    }
}

// ---------------- fused enc GEMM: fp32 concat A -> bf16 staging -----------
__global__ __launch_bounds__(256)
void gemm_enc(const float* __restrict__ A1f,           // sf [M,128]
              const float* __restrict__ A2f,           // mf [M,384]
              const short* __restrict__ Wt_hi, const short* __restrict__ Wt_lo,
              const float* __restrict__ bias,
              short* __restrict__ Cb, int ldcb, int M) {
    constexpr int NT = 4, NTW = 2, K = 512, NBK = 8;
    constexpr int ASZ = 128 * 64;                 // shorts (16KB)
    constexpr int BSZ = 2 * NT * 16 * 64;         // shorts (16KB)
    constexpr int BUF = ASZ + BSZ;
    __shared__ short lds[2 * BUF];                // 64 KB

    const int tid  = threadIdx.x;
    const int lane = tid & 63;
    const int wv   = tid >> 6;
    const int wm   = wv >> 1;
    const int wn   = wv & 1;
    const int bm   = blockIdx.y * 128;
    const int col0 = blockIdx.x * (NT * 16);
    const int lrow = lane & 15;
    const int quad = lane >> 4;

    const int su = (tid & 7) ^ ((tid >> 3) & 7);
    const float* gsA1[4];
    const float* gsA2[4];
    #pragma unroll
    for (int jj = 0; jj < 4; ++jj) {
        const int rg = min(bm + jj * 32 + (tid >> 3), M - 1);
        gsA1[jj] = A1f + (size_t)rg * 128 + su * 8;
        gsA2[jj] = A2f + (size_t)rg * 384 + su * 8;
    }
    const short* gsB[NT];
    #pragma unroll
    for (int jj = 0; jj < NT; ++jj) {
        const int colIdx = jj * 32 + (tid >> 3);
        const bool ishi = colIdx < NT * 16;
        const int cp = ishi ? colIdx : colIdx - NT * 16;
        gsB[jj] = (ishi ? Wt_hi : Wt_lo) + (size_t)(col0 + cp) * K + su * 8;
    }
    auto stageB = [&](int b, int c) {
        const int k = c * 64;
        #pragma unroll
        for (int jj = 0; jj < NT; ++jj)
            gload_lds16(gsB[jj] + k, &lds[b * BUF + ASZ + (jj * 256 + tid) * 8]);
    };

    int aoff[4][2], boff[NTW][2];
    #pragma unroll
    for (int m = 0; m < 4; ++m)
        #pragma unroll
        for (int kk = 0; kk < 2; ++kk)
            aoff[m][kk] = (wm * 64 + m * 16 + lrow) * 64 +
                          (((kk * 4 + quad) ^ (lrow & 7)) * 8);
    #pragma unroll
    for (int nt = 0; nt < NTW; ++nt)
        #pragma unroll
        for (int kk = 0; kk < 2; ++kk)
            boff[nt][kk] = (wn * NTW * 16 + nt * 16 + lrow) * 64 +
                           (((kk * 4 + quad) ^ (lrow & 7)) * 8);

    f32x4 acc[4][NTW];
    #pragma unroll
    for (int m = 0; m < 4; ++m)
        #pragma unroll
        for (int nt = 0; nt < NTW; ++nt)
            acc[m][nt] = (f32x4){0.f, 0.f, 0.f, 0.f};

    float4 awin[8];

    #pragma unroll
    for (int jj = 0; jj < 4; ++jj) {
        awin[jj * 2 + 0] = *(const float4*)(gsA1[jj]);
        awin[jj * 2 + 1] = *(const float4*)(gsA1[jj] + 4);
    }
    stageB(0, 0);
    #pragma unroll
    for (int jj = 0; jj < 4; ++jj) {
        const float4 w0 = awin[jj * 2 + 0], w1 = awin[jj * 2 + 1];
        uint4 o;
        o.x = packbf(w0.x, w0.y); o.y = packbf(w0.z, w0.w);
        o.z = packbf(w1.x, w1.y); o.w = packbf(w1.z, w1.w);
        *((uint4*)&lds[(jj * 256 + tid) * 8]) = o;
    }
    asm volatile("s_waitcnt vmcnt(0)" ::: "memory");
    __builtin_amdgcn_s_barrier();

    #pragma unroll
    for (int c = 0; c < NBK; ++c) {
        const int cur = c & 1, nxt = cur ^ 1;
        if (c + 1 < NBK) {
            const int k1 = (c + 1) * 64;
            #pragma unroll
            for (int jj = 0; jj < 4; ++jj) {
                const float* p = (k1 < 128) ? (gsA1[jj] + k1)
                                            : (gsA2[jj] + (k1 - 128));
                awin[jj * 2 + 0] = *(const float4*)p;
                awin[jj * 2 + 1] = *(const float4*)(p + 4);
            }
            stageB(nxt, c + 1);
            __builtin_amdgcn_sched_barrier(0);
        }

        const short* La = &lds[cur * BUF];
        const short* Lb = &lds[cur * BUF + ASZ];
        #pragma unroll
        for (int kk = 0; kk < 2; ++kk) {
            bf16x8 a[4];
            #pragma unroll
            for (int m = 0; m < 4; ++m)
                a[m] = *(const bf16x8*)(La + aoff[m][kk]);
            #pragma unroll
            for (int nt = 0; nt < NTW; ++nt) {
                const bf16x8 vbh = *(const bf16x8*)(Lb + boff[nt][kk]);
                const bf16x8 vbl = *(const bf16x8*)(Lb + boff[nt][kk] + NT * 16 * 64);
                #pragma unroll
                for (int m = 0; m < 4; ++m) {
                    acc[m][nt] = __builtin_amdgcn_mfma_f32_16x16x32_bf16(a[m], vbh, acc[m][nt], 0, 0, 0);
                    acc[m][nt] = __builtin_amdgcn_mfma_f32_16x16x32_bf16(a[m], vbl, acc[m][nt], 0, 0, 0);
                }
            }
        }

        if (c + 1 < NBK) {
            #pragma unroll
            for (int jj = 0; jj < 4; ++jj) {
                const float4 w0 = awin[jj * 2 + 0], w1 = awin[jj * 2 + 1];
                uint4 o;
                o.x = packbf(w0.x, w0.y); o.y = packbf(w0.z, w0.w);
                o.z = packbf(w1.x, w1.y); o.w = packbf(w1.z, w1.w);
                *((uint4*)&lds[nxt * BUF + (jj * 256 + tid) * 8]) = o;
            }
            asm volatile("s_waitcnt vmcnt(0)" ::: "memory");
            __builtin_amdgcn_s_barrier();
        }
    }
    __builtin_amdgcn_s_barrier();

    constexpr int EW = NT * 16 + 4;
    float* ep = (float*)lds;
    #pragma unroll
    for (int nt = 0; nt < NTW; ++nt) {
        const int lcol = wn * NTW * 16 + nt * 16 + lrow;
        const float bsc = bias[col0 + lcol];
        #pragma unroll
        for (int m = 0; m < 4; ++m)
            #pragma unroll
            for (int r = 0; r < 4; ++r)
                ep[(wm * 64 + m * 16 + quad * 4 + r) * EW + lcol] =
                    fmaxf(acc[m][nt][r] + bsc, 0.f);
    }
    __syncthreads();
    for (int g = tid; g < 128 * NT * 2; g += 256) {
        const int row = g / (NT * 2), u = g - row * (NT * 2);
        const int grow = bm + row;
        const float4 f0 = *(const float4*)(ep + row * EW + u * 8);
        const float4 f1 = *(const float4*)(ep + row * EW + u * 8 + 4);
        uint4 o;
        o.x = packbf(f0.x, f0.y); o.y = packbf(f0.z, f0.w);
        o.z = packbf(f1.x, f1.y); o.w = packbf(f1.z, f1.w);
        if (grow < M)
            *(uint4*)(Cb + (size_t)grow * ldcb + col0 + u * 8) = o;
    }
}

// ---------------- fused rel + classifier -----------------------------------
// out = relu( relu(h0|h2 @ rel_w + rel_b) @ w1 + b1 ) @ w2 + b2.
// One block per 128 rows. Phase 1: K=256 staged K-loop, NT=8 (all 128 cols),
// 2m x 2n waves (wave = 64 rows x 64 cols) -> r fp32 [128][132] in LDS.
// Phase 2: r -> f2bf (bit-identical to the old rb round-trip) @ w1 (K=128)
// -> ep2 relu(o1). Phase 3: o1 @ w2 (K=64) -> ep3 -> coalesced out stores.
__global__ __launch_bounds__(256)
void gemm_relcls(const short* __restrict__ A1,         // h0b [M,128]
                 const short* __restrict__ A2,         // h2b [M,128]
                 const short* __restrict__ Wh, const short* __restrict__ Wl,
                 const float* __restrict__ rel_b,
                 const short* __restrict__ W1h, const short* __restrict__ W1l,
                 const float* __restrict__ cb1,
                 const short* __restrict__ W2h, const short* __restrict__ W2l,
                 const float* __restrict__ cb2,
                 float* __restrict__ out, int M) {
    constexpr int NT = 8, NTW = 4, NBK = 4, K = 256;
    constexpr int ASZ = 128 * 64;                 // 16 KB
    constexpr int BSZ = 2 * NT * 16 * 64;         // 32 KB
    constexpr int BUF = ASZ + BSZ;                // 24576 shorts
    __shared__ short lds[2 * BUF];                // 96 KB

    const int tid  = threadIdx.x;
    const int lane = tid & 63;
    const int wv   = tid >> 6;
    const int wm   = wv >> 1;
    const int wn   = wv & 1;
    const int bm   = blockIdx.x * 128;
    const int lrow = lane & 15;
    const int quad = lane >> 4;

    const int su = (tid & 7) ^ ((tid >> 3) & 7);
    const short* gsA1[4];
    const short* gsA2[4];
    #pragma unroll
    for (int jj = 0; jj < 4; ++jj) {
        const int rg = min(bm + jj * 32 + (tid >> 3), M - 1);
        gsA1[jj] = A1 + (size_t)rg * 128 + su * 8;
        gsA2[jj] = A2 + (size_t)rg * 128 + su * 8;
    }
    const short* gsB[NT];
    #pragma unroll
    for (int jj = 0; jj < NT; ++jj) {
        const int colIdx = jj * 32 + (tid >> 3);  // 0..255
        const bool ishi = colIdx < 128;
        const int cp = ishi ? colIdx : colIdx - 128;
        gsB[jj] = (ishi ? Wh : Wl) + (size_t)cp * K + su * 8;
    }
    auto stage = [&](int b, int c) {
        const int k = c * 64;
        #pragma unroll
        for (int jj = 0; jj < 4; ++jj) {
            const short* p = (k < 128) ? (gsA1[jj] + k) : (gsA2[jj] + (k - 128));
            gload_lds16(p, &lds[b * BUF + (jj * 256 + tid) * 8]);
        }
        #pragma unroll
        for (int jj = 0; jj < NT; ++jj)
            gload_lds16(gsB[jj] + k, &lds[b * BUF + ASZ + (jj * 256 + tid) * 8]);
    };

    int aoff[4][2], boff[NTW][2];
    #pragma unroll
    for (int m = 0; m < 4; ++m)
        #pragma unroll
        for (int kk = 0; kk < 2; ++kk)
            aoff[m][kk] = (wm * 64 + m * 16 + lrow) * 64 +
                          (((kk * 4 + quad) ^ (lrow & 7)) * 8);
    #pragma unroll
    for (int nt = 0; nt < NTW; ++nt)
        #pragma unroll
        for (int kk = 0; kk < 2; ++kk)
            boff[nt][kk] = (wn * 64 + nt * 16 + lrow) * 64 +
                           (((kk * 4 + quad) ^ (lrow & 7)) * 8);

    f32x4 acc[4][NTW];
    #pragma unroll
    for (int m = 0; m < 4; ++m)
        #pragma unroll
        for (int nt = 0; nt < NTW; ++nt)
            acc[m][nt] = (f32x4){0.f, 0.f, 0.f, 0.f};

    stage(0, 0);
    for (int c = 0; c < NBK; ++c) {
        const int b = c & 1;
        if (c + 1 < NBK) {
            stage(b ^ 1, c + 1);
            asm volatile("s_waitcnt vmcnt(12)" ::: "memory");
        } else {
            asm volatile("s_waitcnt vmcnt(0)" ::: "memory");
        }
        __builtin_amdgcn_s_barrier();

        const short* La = &lds[b * BUF];
        const short* Lb = &lds[b * BUF + ASZ];
        #pragma unroll
        for (int kk = 0; kk < 2; ++kk) {
            bf16x8 a[4];
            #pragma unroll
            for (int m = 0; m < 4; ++m)
                a[m] = *(const bf16x8*)(La + aoff[m][kk]);
            #pragma unroll
            for (int nt = 0; nt < NTW; ++nt) {
                const bf16x8 vbh = *(const bf16x8*)(Lb + boff[nt][kk]);
                const bf16x8 vbl = *(const bf16x8*)(Lb + boff[nt][kk] + 128 * 64);
                #pragma unroll
                for (int m = 0; m < 4; ++m) {
                    acc[m][nt] = __builtin_amdgcn_mfma_f32_16x16x32_bf16(a[m], vbh, acc[m][nt], 0, 0, 0);
                    acc[m][nt] = __builtin_amdgcn_mfma_f32_16x16x32_bf16(a[m], vbl, acc[m][nt], 0, 0, 0);
                }
            }
        }
        asm volatile("" ::: "memory");
        __builtin_amdgcn_s_barrier();
    }

    // ---- phase-1 epilogue: r = relu(acc + rel_b) -> rtile fp32 [128][132] --
    constexpr int EW1 = 132;                      // 132 mod 32 = 4 -> 2-way ok
    float* rt = (float*)lds;                      // 67.6 KB of 96 KB
    #pragma unroll
    for (int nt = 0; nt < NTW; ++nt) {
        const int lcol = wn * 64 + nt * 16 + lrow;
        const float bsc = rel_b[lcol];
        #pragma unroll
        for (int m = 0; m < 4; ++m)
            #pragma unroll
            for (int r = 0; r < 4; ++r)
                rt[(wm * 64 + m * 16 + quad * 4 + r) * EW1 + lcol] =
                    fmaxf(acc[m][nt][r] + bsc, 0.f);
    }
    __syncthreads();

    // ---- phase 2: o1 = relu(r @ w1 + b1), K=128, 64 cols ----
    f32x4 acc2[4][2];
    #pragma unroll
    for (int m = 0; m < 4; ++m)
        #pragma unroll
        for (int nt = 0; nt < 2; ++nt)
            acc2[m][nt] = (f32x4){0.f, 0.f, 0.f, 0.f};
    #pragma unroll
    for (int kk = 0; kk < 4; ++kk) {
        bf16x8 b2h[2], b2l[2];
        #pragma unroll
        for (int nt = 0; nt < 2; ++nt) {
            const size_t cw = (size_t)(wn * 32 + nt * 16 + lrow) * 128 + kk * 32 + quad * 8;
            b2h[nt] = *(const bf16x8*)(W1h + cw);
            b2l[nt] = *(const bf16x8*)(W1l + cw);
        }
        #pragma unroll
        for (int m = 0; m < 4; ++m) {
            const float* pe = rt + (wm * 64 + m * 16 + lrow) * EW1 + kk * 32 + quad * 8;
            const float4 e0 = *(const float4*)pe;
            const float4 e1 = *(const float4*)(pe + 4);
            bf16x8 a;
            a[0] = (short)f2bf(e0.x); a[1] = (short)f2bf(e0.y);
            a[2] = (short)f2bf(e0.z); a[3] = (short)f2bf(e0.w);
            a[4] = (short)f2bf(e1.x); a[5] = (short)f2bf(e1.y);
            a[6] = (short)f2bf(e1.z); a[7] = (short)f2bf(e1.w);
            #pragma unroll
            for (int nt = 0; nt < 2; ++nt) {
                acc2[m][nt] = __builtin_amdgcn_mfma_f32_16x16x32_bf16(a, b2h[nt], acc2[m][nt], 0, 0, 0);
                acc2[m][nt] = __builtin_amdgcn_mfma_f32_16x16x32_bf16(a, b2l[nt], acc2[m][nt], 0, 0, 0);
            }
        }
    }
    __syncthreads();                              // all rtile reads done

    constexpr int EW2 = 68;
    float* ep2 = (float*)lds;                     // overwrites rtile
    #pragma unroll
    for (int nt = 0; nt < 2; ++nt) {
        const int lcol = wn * 32 + nt * 16 + lrow;
        const float bsc = cb1[lcol];
        #pragma unroll
        for (int m = 0; m < 4; ++m)
            #pragma unroll
            for (int r = 0; r < 4; ++r)
                ep2[(wm * 64 + m * 16 + quad * 4 + r) * EW2 + lcol] =
                    fmaxf(acc2[m][nt][r] + bsc, 0.f);
    }
    __syncthreads();

    // ---- phase 3: out = o1 @ w2 + b2, K=64, 32 cols ----
    const short* pB3h = W2h + (size_t)(wn * 16 + lrow) * 64 + quad * 8;
    const short* pB3l = W2l + (size_t)(wn * 16 + lrow) * 64 + quad * 8;
    f32x4 acc3[4];
    #pragma unroll
    for (int m = 0; m < 4; ++m) acc3[m] = (f32x4){0.f, 0.f, 0.f, 0.f};
    #pragma unroll
    for (int kk = 0; kk < 2; ++kk) {
        const bf16x8 bh = *(const bf16x8*)(pB3h + kk * 32);
        const bf16x8 bl = *(const bf16x8*)(pB3l + kk * 32);
        #pragma unroll
        for (int m = 0; m < 4; ++m) {
            const float* pe = ep2 + (wm * 64 + m * 16 + lrow) * EW2 + kk * 32 + quad * 8;
            const float4 e0 = *(const float4*)pe;
            const float4 e1 = *(const float4*)(pe + 4);
            bf16x8 a;
            a[0] = (short)f2bf(e0.x); a[1] = (short)f2bf(e0.y);
            a[2] = (short)f2bf(e0.z); a[3] = (short)f2bf(e0.w);
            a[4] = (short)f2bf(e1.x); a[5] = (short)f2bf(e1.y);
            a[6] = (short)f2bf(e1.z); a[7] = (short)f2bf(e1.w);
            acc3[m] = __builtin_amdgcn_mfma_f32_16x16x32_bf16(a, bh, acc3[m], 0, 0, 0);
            acc3[m] = __builtin_amdgcn_mfma_f32_16x16x32_bf16(a, bl, acc3[m], 0, 0, 0);
        }
    }

    constexpr int EW3 = 36;
    float* ep3 = (float*)lds + 128 * EW2;         // 34.8 + 18.4 = 53.2 KB ok
    {
        const int lcol = wn * 16 + lrow;
        const float bsc = cb2[lcol];
        #pragma unroll
        for (int m = 0; m < 4; ++m)
            #pragma unroll
            for (int r = 0; r < 4; ++r)
                ep3[(wm * 64 + m * 16 + quad * 4 + r) * EW3 + lcol] =
                    acc3[m][r] + bsc;
    }
    __syncthreads();
    #pragma unroll
    for (int j = 0; j < 4; ++j) {
        const int g = tid + j * 256;              // 16B units, 8 per row
        const int row = g >> 3, u = g & 7;
        const int grow = bm + row;
        if (grow < M)
            *(float4*)(out + (size_t)grow * 32 + u * 4) =
                *(const float4*)(ep3 + row * EW3 + u * 4);
    }
}

// ---------------------------------------------------------------------------

extern "C" void kernel_launch(void* const* d_in, const int* in_sizes, int n_in,
                              void* d_out, int out_size, void* d_ws, size_t ws_size,
                              hipStream_t stream) {
    const float* sf    = (const float*)d_in[0];
    const float* mf    = (const float*)d_in[1];
    const int*   src   = (const int*)d_in[2];
    const int*   dst   = (const int*)d_in[3];
    const float* enc_w = (const float*)d_in[4];
    const float* enc_b = (const float*)d_in[5];
    const float* s0_ws = (const float*)d_in[6];
    const float* s0_wn = (const float*)d_in[7];
    const float* s0_b  = (const float*)d_in[8];
    const float* bn0_g = (const float*)d_in[9];
    const float* bn0_b = (const float*)d_in[10];
    const float* bn0_m = (const float*)d_in[11];
    const float* bn0_v = (const float*)d_in[12];
    const float* s1_ws = (const float*)d_in[13];
    const float* s1_wn = (const float*)d_in[14];
    const float* s1_b  = (const float*)d_in[15];
    const float* bn1_g = (const float*)d_in[16];
    const float* bn1_b = (const float*)d_in[17];
    const float* bn1_m = (const float*)d_in[18];
    const float* bn1_v = (const float*)d_in[19];
    const float* rel_w = (const float*)d_in[20];
    const float* rel_b = (const float*)d_in[21];
    const float* cw1   = (const float*)d_in[22];
    const float* cb1   = (const float*)d_in[23];
    const float* cw2   = (const float*)d_in[24];
    const float* cb2   = (const float*)d_in[25];
    float* out = (float*)d_out;

    const int nn = in_sizes[0] / 128;   // 100000
    const int ne = in_sizes[2];         // 800000
    const int nb = (nn + 1023) / 1024;  // scan blocks (98)

    short* h0b   = (short*)d_ws;                       // [nn,128] bf16
    short* xb    = h0b + (size_t)nn * 128;             // region [nn,512]
    float* st    = (float*)xb;                         // s1 fp32 [nn,128]
    short* h1b   = (short*)(st + (size_t)nn * 128);    // [nn,256] bf16
    short* agg0b = xb + (size_t)nn * 512;              // [nn,128]
    short* t1b   = agg0b + (size_t)nn * 128;           // [nn,128]
    short* h2b   = t1b + (size_t)nn * 128;             // [nn,128]
    int* deg    = (int*)(h2b + (size_t)nn * 128);
    int* rowptr = deg + nn;
    int* cursor = rowptr + nn + 1;
    int* part   = cursor + nn;                         // [nb+1]
    int* eidx   = part + nb + 1;
    short* wts = (short*)(eidx + ne);
    short* wt_enc_h = wts;                 short* wt_enc_l = wt_enc_h + 65536;   // [128][512]
    short* wt_s0_h  = wt_enc_l + 65536;    short* wt_s0_l  = wt_s0_h  + 65536;   // [256][256]
    short* wt_st_h  = wt_s0_l  + 65536;    short* wt_st_l  = wt_st_h  + 65536;   // [256][256]
    short* wt_rel_h = wt_st_l  + 65536;    short* wt_rel_l = wt_rel_h + 32768;   // [128][256]
    short* wt_c1_h  = wt_rel_l + 32768;    short* wt_c1_l  = wt_c1_h  + 8192;    // [64][128]
    short* wt_c2_h  = wt_c1_l  + 8192;     short* wt_c2_l  = wt_c2_h  + 2048;    // [32][64]

    const dim3 blk(256);
    const int gM = (nn + 127) / 128;    // 782 row-blocks

    // --- CSR build (parallel scan) ---
    hipMemsetAsync(deg, 0, (size_t)nn * 4, stream);
    count_deg <<<dim3((ne + 255) / 256), blk, 0, stream>>>(dst, deg, ne);
    scan_block<<<dim3(nb), dim3(1024), 0, stream>>>(deg, rowptr, part, nn);
    scan_part <<<dim3(1),  dim3(1024), 0, stream>>>(part, nb);
    scan_add  <<<dim3((nn + 255) / 256), blk, 0, stream>>>(part, rowptr, cursor, nn, nb);
    fill_edges<<<dim3((ne + 255) / 256), blk, 0, stream>>>(src, dst, cursor, eidx, ne);

    // --- weight prep (fused, 1 launch) ---
    prep_all<<<dim3(936), blk, 0, stream>>>(
        enc_w, s0_ws, s0_wn, s1_ws, s1_wn, rel_w, cw1, cw2,
        wt_enc_h, wt_enc_l, wt_s0_h, wt_s0_l, wt_st_h, wt_st_l,
        wt_rel_h, wt_rel_l, wt_c1_h, wt_c1_l, wt_c2_h, wt_c2_l);

    // --- h0 = relu(concat(sf,mf) @ enc_w + enc_b) -> h0b bf16 (fused) ---
    gemm_enc<<<dim3(2, gM), blk, 0, stream>>>(
        sf, mf, wt_enc_h, wt_enc_l, enc_b, h0b, 128, nn);

    // --- agg0 = mean_neigh(h0b) -> agg0b bf16 ---
    agg_mean_bb<<<dim3((nn + 3) / 4), blk, 0, stream>>>(
        h0b, rowptr, eidx, agg0b, nn);

    // --- h1 = relu(bn0(h0@ws0 + agg0@wn0 + b0)) -> h1b bf16 ---
    gemm_dp<4, 128, 128><<<dim3(4, gM), blk, 0, stream>>>(
        h0b, 128, agg0b, 128, wt_s0_h, wt_s0_l, s0_b,
        bn0_g, bn0_b, bn0_m, bn0_v, 1,
        nullptr, 0, 0, h1b, 0, 256, nn);

    // --- [s1 | t1] = h1 @ [ws1 | wn1]; s1 fp32 -> st, t1 bf16 -> t1b ---
    gemm_dp<4, 256, 0><<<dim3(4, gM), blk, 0, stream>>>(
        h1b, 256, nullptr, 0, wt_st_h, wt_st_l, nullptr,
        nullptr, nullptr, nullptr, nullptr, 0,
        st, 128, 128, t1b, 128, 128, nn);

    // --- h2 = relu(bn1(s1 + mean_neigh(t1) + b1)) -> h2b bf16 ---
    agg_combine_bb<<<dim3((nn + 3) / 4), blk, 0, stream>>>(
        t1b, rowptr, eidx, st, s1_b,
        bn1_g, bn1_b, bn1_m, bn1_v, h2b, nn);

    // --- out = fused rel + cls1 + cls2 ---
    gemm_relcls<<<dim3(gM), blk, 0, stream>>>(
        h0b, h2b, wt_rel_h, wt_rel_l, rel_b,
        wt_c1_h, wt_c1_l, cb1, wt_c2_h, wt_c2_l, cb2, out, nn);
}